// Round 4
// baseline (383.358 us; speedup 1.0000x reference)
//
#include <hip/hip_runtime.h>

typedef __bf16 bf16;
typedef __attribute__((ext_vector_type(8))) __bf16 bf16x8;
typedef __attribute__((ext_vector_type(4))) float f32x4;

#define B_SZ 4
#define SEQ 2048
#define DM 1024
#define DIN 2048
#define NH 256
#define DSTATE 16
#define CONVD 2080
#define DPROJ 4384
#define NPAD1 4608
#define MROWS 8192
#define NC 64
#define LC 32
#define UROWB 8768  // u row stride in bytes (4384 * 2)

__device__ __forceinline__ void gload_lds16(const void* g, void* l) {
  __builtin_amdgcn_global_load_lds(
      (__attribute__((address_space(1))) void*)g,
      (__attribute__((address_space(3))) void*)l, 16, 0, 0);
}

template <int N>
__device__ __forceinline__ void vm_wait() {
  asm volatile("s_waitcnt vmcnt(%0)" ::"n"(N) : "memory");
}
__device__ __forceinline__ void bar() { asm volatile("s_barrier" ::: "memory"); }

// ---------------- transpose (f32 [K][N] -> bf16 [Npad][K], zero-pad rows >= N)
__global__ void transpose_cvt(const float* __restrict__ W, bf16* __restrict__ WT,
                              int K, int N, int Npad) {
  __shared__ float tile[32][33];
  int k0 = blockIdx.x * 32, n0 = blockIdx.y * 32;
  int tx = threadIdx.x, ty = threadIdx.y;  // (32, 8)
#pragma unroll
  for (int j = 0; j < 4; j++) {
    int k = k0 + ty + 8 * j, n = n0 + tx;
    tile[ty + 8 * j][tx] = (k < K && n < N) ? W[(size_t)k * N + n] : 0.f;
  }
  __syncthreads();
#pragma unroll
  for (int j = 0; j < 4; j++) {
    int n = n0 + ty + 8 * j, k = k0 + tx;
    if (n < Npad && k < K) WT[(size_t)n * K + k] = (bf16)tile[tx][ty + 8 * j];
  }
}

// ---------------- layernorm (f32 in) -> xn bf16
__global__ __launch_bounds__(256) void ln_kernel(const float* __restrict__ x,
                                                 const float* __restrict__ lw,
                                                 const float* __restrict__ lb,
                                                 bf16* __restrict__ xn) {
  int row = blockIdx.x;
  int t = threadIdx.x;
  f32x4 v4 = ((const f32x4*)(x + (size_t)row * DM))[t];
  float v0 = v4[0], v1 = v4[1], v2 = v4[2], v3 = v4[3];
  float s = v0 + v1 + v2 + v3;
  float s2 = v0 * v0 + v1 * v1 + v2 * v2 + v3 * v3;
#pragma unroll
  for (int off = 32; off > 0; off >>= 1) {
    s += __shfl_down(s, off);
    s2 += __shfl_down(s2, off);
  }
  __shared__ float ps[8];
  int wave = t >> 6, lane = t & 63;
  if (lane == 0) { ps[wave] = s; ps[4 + wave] = s2; }
  __syncthreads();
  s = ps[0] + ps[1] + ps[2] + ps[3];
  s2 = ps[4] + ps[5] + ps[6] + ps[7];
  float mean = s * (1.f / DM);
  float var = s2 * (1.f / DM) - mean * mean;
  float rstd = rsqrtf(var + 1e-5f);
  f32x4 wv = ((const f32x4*)lw)[t];
  f32x4 bv = ((const f32x4*)lb)[t];
  bf16 o[4];
  o[0] = (bf16)((v0 - mean) * rstd * wv[0] + bv[0]);
  o[1] = (bf16)((v1 - mean) * rstd * wv[1] + bv[1]);
  o[2] = (bf16)((v2 - mean) * rstd * wv[2] + bv[2]);
  o[3] = (bf16)((v3 - mean) * rstd * wv[3] + bv[3]);
  bf16* dst = xn + (size_t)row * DM + t * 4;
  dst[0] = o[0]; dst[1] = o[1]; dst[2] = o[2]; dst[3] = o[3];
}

// ---------------- GEMM1: deep-pipelined 256x256, BK=64, 8 waves, counted vmcnt.
// A[8192][1024] bf16, BT[4608][1024] bf16 -> C bf16 [8192][4384] (col<4384 guard).
// LDS half-slots: A[par][mq] at (par*2+mq)*16384; B[par][nq] at 65536+(par*2+nq)*16384.
// XOR swizzle: global 16B-slot s at LDS slot s^(lrow&7); read back with same XOR.
#define PHASE(MQ, NQ, P, STAGE_STMT)                                                       \
  {                                                                                        \
    const char* sa_ = lds + ((P) * 2 + MQ) * 16384;                                        \
    const char* sb_ = lds + 65536 + ((P) * 2 + NQ) * 16384;                                \
    bf16x8 a_[4][2], b_[2][2];                                                             \
    _Pragma("unroll") for (int mi = 0; mi < 4; mi++) {                                     \
      int lrow = wm * 64 + mi * 16 + lr16;                                                 \
      a_[mi][0] = *(const bf16x8*)(sa_ + lrow * 128 + ts0 * 16);                           \
      a_[mi][1] = *(const bf16x8*)(sa_ + lrow * 128 + ts1 * 16);                           \
    }                                                                                      \
    _Pragma("unroll") for (int ni = 0; ni < 2; ni++) {                                     \
      int lrow = wn * 32 + ni * 16 + lr16;                                                 \
      b_[ni][0] = *(const bf16x8*)(sb_ + lrow * 128 + ts0 * 16);                           \
      b_[ni][1] = *(const bf16x8*)(sb_ + lrow * 128 + ts1 * 16);                           \
    }                                                                                      \
    STAGE_STMT;                                                                            \
    __builtin_amdgcn_s_setprio(1);                                                         \
    _Pragma("unroll") for (int mi = 0; mi < 4; mi++)                                       \
      _Pragma("unroll") for (int ni = 0; ni < 2; ni++) {                                   \
        acc[MQ * 4 + mi][NQ * 2 + ni] = __builtin_amdgcn_mfma_f32_16x16x32_bf16(           \
            a_[mi][0], b_[ni][0], acc[MQ * 4 + mi][NQ * 2 + ni], 0, 0, 0);                 \
        acc[MQ * 4 + mi][NQ * 2 + ni] = __builtin_amdgcn_mfma_f32_16x16x32_bf16(           \
            a_[mi][1], b_[ni][1], acc[MQ * 4 + mi][NQ * 2 + ni], 0, 0, 0);                 \
      }                                                                                    \
    __builtin_amdgcn_s_setprio(0);                                                         \
  }

__global__ __launch_bounds__(512, 2) void gemm1_8p(const bf16* __restrict__ A,
                                                   const bf16* __restrict__ BT,
                                                   bf16* __restrict__ C) {
  __shared__ char lds[131072];
  int bid = blockIdx.x;                       // 576 = 32 m-tiles * 18 n-tiles
  int swz = (bid & 7) * 72 + (bid >> 3);      // bijective XCD swizzle (576 % 8 == 0)
  int bm = swz / 18, bn = swz - (swz / 18) * 18;
  int m0 = bm * 256, n0 = bn * 256;
  int t = threadIdx.x, lane = t & 63, wave = t >> 6;
  int wm = wave >> 2, wn = wave & 3;
  int lr16 = lane & 15, kq = lane >> 4;
  int ts0 = kq ^ (lr16 & 7);
  int ts1 = (4 + kq) ^ (lr16 & 7);
  // staging: chunks c0,c1; lane covers global 16B-slot sw, LDS lands linearly
  int sw = (lane & 7) ^ ((lane >> 3) & 7);
  int l8 = lane >> 3;
  int c0 = 2 * wave, c1 = 2 * wave + 1;
  int lr0 = c0 * 8 + l8, lr1 = c1 * 8 + l8;
  const char* Ab = (const char*)A;
  const char* Bb = (const char*)BT;
  int grA0 = m0 + (lr0 >> 6) * 128 + (lr0 & 63);
  int grA1 = m0 + (lr1 >> 6) * 128 + (lr1 & 63);
  int gcB0 = n0 + (lr0 >> 5) * 64 + (lr0 & 31);
  int gcB1 = n0 + (lr1 >> 5) * 64 + (lr1 & 31);

  auto stA = [&](int kt, int p, int mq) {
    char* slot = lds + (p * 2 + mq) * 16384;
    size_t ko = (size_t)kt * 128 + sw * 16;
    gload_lds16(Ab + (size_t)(grA0 + mq * 64) * 2048 + ko, slot + c0 * 1024);
    gload_lds16(Ab + (size_t)(grA1 + mq * 64) * 2048 + ko, slot + c1 * 1024);
  };
  auto stB = [&](int kt, int p, int nq) {
    char* slot = lds + 65536 + (p * 2 + nq) * 16384;
    size_t ko = (size_t)kt * 128 + sw * 16;
    gload_lds16(Bb + (size_t)(gcB0 + nq * 32) * 2048 + ko, slot + c0 * 1024);
    gload_lds16(Bb + (size_t)(gcB1 + nq * 32) * 2048 + ko, slot + c1 * 1024);
  };

  f32x4 acc[8][4] = {};
  // prologue: exactly this order (queue = A0(0),B0(0),A1(0),B1(0),A0(1),B0(1))
  stA(0, 0, 0); stB(0, 0, 0); stA(0, 0, 1); stB(0, 0, 1); stA(1, 1, 0); stB(1, 1, 0);
#pragma unroll 1
  for (int kt = 0; kt < 16; kt++) {
    int p = kt & 1;
    if (kt < 15) vm_wait<8>(); else vm_wait<4>();
    bar();
    PHASE(0, 0, p, { if (kt + 1 < 16) stA(kt + 1, p ^ 1, 1); });
    if (kt < 15) vm_wait<6>(); else vm_wait<0>();
    bar();
    PHASE(0, 1, p, { if (kt + 1 < 16) stB(kt + 1, p ^ 1, 1); });
    bar();
    PHASE(1, 0, p, { if (kt + 2 < 16) stA(kt + 2, p, 0); });
    bar();
    PHASE(1, 1, p, { if (kt + 2 < 16) stB(kt + 2, p, 0); });
  }
#pragma unroll
  for (int mq = 0; mq < 2; mq++)
#pragma unroll
    for (int mi = 0; mi < 4; mi++)
#pragma unroll
      for (int nq = 0; nq < 2; nq++)
#pragma unroll
        for (int ni = 0; ni < 2; ni++) {
          int row = m0 + wm * 128 + mq * 64 + mi * 16 + kq * 4;
          int col = n0 + wn * 64 + nq * 32 + ni * 16 + lr16;
          f32x4 v = acc[mq * 4 + mi][nq * 2 + ni];
          if (col < 4384) {
#pragma unroll
            for (int r = 0; r < 4; r++)
              C[(size_t)(row + r) * DPROJ + col] = (bf16)v[r];
          }
        }
}

// ---------------- GEMM2 (old structure): A[M][K] bf16 @ BT[N][K] bf16 -> f32 C = Xres + acc
__global__ __launch_bounds__(256) void gemm2_kernel(const bf16* __restrict__ A,
                                                    const bf16* __restrict__ BT,
                                                    int K, int ldc,
                                                    float* __restrict__ C,
                                                    const float* __restrict__ Xres) {
  __shared__ bf16 As[128 * 32];
  __shared__ bf16 Bs[128 * 32];
  int m0 = blockIdx.y * 128, n0 = blockIdx.x * 128;
  int t = threadIdx.x;
  int lane = t & 63, wave = t >> 6;
  int wm = wave >> 1, wn = wave & 1;
  int lr = lane & 15, kq = lane >> 4;
  f32x4 acc[4][4] = {};
  const char* Ab = (const char*)A;
  const char* Bb = (const char*)BT;
  size_t strideA = (size_t)K * 2;
  int r0 = t >> 2;
  int kb0 = (t & 3) * 16;
  int nk = K / 32;
  for (int kt = 0; kt < nk; ++kt) {
    size_t koff = (size_t)kt * 64;
    gload_lds16(Ab + (size_t)(m0 + r0) * strideA + koff + kb0, (char*)As + wave * 1024);
    gload_lds16(Ab + (size_t)(m0 + 64 + r0) * strideA + koff + kb0, (char*)As + 4096 + wave * 1024);
    gload_lds16(Bb + (size_t)(n0 + r0) * strideA + koff + kb0, (char*)Bs + wave * 1024);
    gload_lds16(Bb + (size_t)(n0 + 64 + r0) * strideA + koff + kb0, (char*)Bs + 4096 + wave * 1024);
    __syncthreads();
    bf16x8 af[4], bfr[4];
#pragma unroll
    for (int i = 0; i < 4; i++) af[i] = *(const bf16x8*)&As[(wm * 64 + i * 16 + lr) * 32 + kq * 8];
#pragma unroll
    for (int j = 0; j < 4; j++) bfr[j] = *(const bf16x8*)&Bs[(wn * 64 + j * 16 + lr) * 32 + kq * 8];
#pragma unroll
    for (int i = 0; i < 4; i++)
#pragma unroll
      for (int j = 0; j < 4; j++)
        acc[i][j] = __builtin_amdgcn_mfma_f32_16x16x32_bf16(af[i], bfr[j], acc[i][j], 0, 0, 0);
    __syncthreads();
  }
#pragma unroll
  for (int i = 0; i < 4; i++) {
    int row = m0 + wm * 64 + i * 16 + kq * 4;
#pragma unroll
    for (int j = 0; j < 4; j++) {
      int col = n0 + wn * 64 + j * 16 + lr;
#pragma unroll
      for (int r = 0; r < 4; r++) {
        size_t o = (size_t)(row + r) * ldc + col;
        C[o] = Xres[o] + acc[i][j][r];
      }
    }
  }
}

// ---------------- conv: t-chunked, u read once; silu; softplus(dt)
__global__ __launch_bounds__(256) void conv_prep2(const bf16* __restrict__ u,
                                                  const float* __restrict__ cw,
                                                  const float* __restrict__ cb,
                                                  const float* __restrict__ dt_bias,
                                                  bf16* __restrict__ xs,
                                                  float* __restrict__ BC,
                                                  float* __restrict__ dtf) {
  int c = blockIdx.x * 256 + threadIdx.x;  // channel 0..2335
  int tc = blockIdx.y;                     // 16 chunks of 128
  int b = blockIdx.z;
  if (c >= CONVD + NH) return;
  int t0 = tc * 128;
  size_t rb = (size_t)b * SEQ + t0;
  if (c < CONVD) {
    float w0 = cw[c], w1 = cw[CONVD + c], w2 = cw[2 * CONVD + c], w3 = cw[3 * CONVD + c];
    float bb = cb[c];
    const bf16* ucol = u + (size_t)b * SEQ * DPROJ + DIN + c;
    float um3 = 0.f, um2 = 0.f, um1 = 0.f;
    if (tc > 0) {
      um3 = (float)ucol[(size_t)(t0 - 3) * DPROJ];
      um2 = (float)ucol[(size_t)(t0 - 2) * DPROJ];
      um1 = (float)ucol[(size_t)(t0 - 1) * DPROJ];
    }
    for (int i = 0; i < 128; i++) {
      float uc = (float)ucol[(size_t)(t0 + i) * DPROJ];
      float acc = bb + w0 * um3 + w1 * um2 + w2 * um1 + w3 * uc;
      um3 = um2; um2 = um1; um1 = uc;
      float sv = acc / (1.f + __expf(-acc));
      size_t row = rb + i;
      if (c < DIN) xs[row * DIN + c] = (bf16)sv;
      else BC[row * 32 + (c - DIN)] = sv;
    }
  } else {
    int h = c - CONVD;
    float db = dt_bias[h];
    for (int i = 0; i < 128; i++) {
      size_t row = rb + i;
      float xv = (float)u[row * DPROJ + (DPROJ - NH) + h] + db;
      dtf[row * NH + h] = (xv > 20.f) ? xv : log1pf(__expf(xv));
    }
  }
}

// ---------------- chunked scan, phase 1: local scan from zero -> (S, P) in u's dead tail
__global__ __launch_bounds__(64) void scan_p1(const bf16* __restrict__ xs,
                                              const float* __restrict__ BC,
                                              const float* __restrict__ dtf,
                                              const float* __restrict__ A_log,
                                              bf16* __restrict__ uscr) {
  int c = blockIdx.x & 63, hg = (blockIdx.x >> 6) & 31, b = blockIdx.x >> 11;
  int lane = threadIdx.x, hh = lane >> 3;
  int h = hg * 8 + hh;
  float A = -__expf(A_log[h]);
  float st[16];
#pragma unroll
  for (int n = 0; n < 16; n++) st[n] = 0.f;
  float pcum = 1.f;
  size_t rb = (size_t)b * SEQ + (size_t)c * LC;
  for (int t = 0; t < LC; t++) {
    size_t row = rb + t;
    const float* bcrow = BC + row * 32;
    float dtv = dtf[row * NH + h];
    float x = (float)xs[row * DIN + hg * 64 + lane];
    float dA = __expf(dtv * A);
    pcum *= dA;
    float w = dtv * x;
#pragma unroll
    for (int n = 0; n < 16; n++) st[n] = st[n] * dA + w * bcrow[n];
  }
  char* slot = (char*)uscr + (size_t)blockIdx.x * UROWB + 4096;
  float* S = (float*)slot;
#pragma unroll
  for (int n = 0; n < 16; n++) S[lane * 16 + n] = st[n];
  if ((lane & 7) == 0) ((float*)(slot + 4096))[hh] = pcum;
}

// ---------------- phase 2: sequential combine over chunks (prefetched); S <- incoming H
__global__ __launch_bounds__(64) void scan_p2(bf16* __restrict__ uscr) {
  int bh = blockIdx.x;  // 0..127 = b*32+hg
  int lane = threadIdx.x, hh = lane >> 3;
  float H[16];
#pragma unroll
  for (int n = 0; n < 16; n++) H[n] = 0.f;
  char* base = (char*)uscr + (size_t)bh * NC * UROWB + 4096;
  float sN[16], PN;
  {
    float* S = (float*)base;
#pragma unroll
    for (int n = 0; n < 16; n++) sN[n] = S[lane * 16 + n];
    PN = ((const float*)(base + 4096))[hh];
  }
  for (int c = 0; c < NC; c++) {
    float sC[16], PC = PN;
#pragma unroll
    for (int n = 0; n < 16; n++) sC[n] = sN[n];
    if (c + 1 < NC) {
      char* slot = base + (size_t)(c + 1) * UROWB;
      float* S = (float*)slot;
#pragma unroll
      for (int n = 0; n < 16; n++) sN[n] = S[lane * 16 + n];
      PN = ((const float*)(slot + 4096))[hh];
    }
    float* S0 = (float*)(base + (size_t)c * UROWB);
#pragma unroll
    for (int n = 0; n < 16; n++) {
      float hn = H[n];
      S0[lane * 16 + n] = hn;
      H[n] = PC * hn + sC[n];
    }
  }
}

// ---------------- phase 3: re-scan each chunk from true incoming state, emit y
__global__ __launch_bounds__(64) void scan_p3(const bf16* __restrict__ xs,
                                              const float* __restrict__ BC,
                                              const float* __restrict__ dtf,
                                              const float* __restrict__ A_log,
                                              const float* __restrict__ Dp,
                                              const bf16* __restrict__ uscr,
                                              bf16* __restrict__ y) {
  int c = blockIdx.x & 63, hg = (blockIdx.x >> 6) & 31, b = blockIdx.x >> 11;
  int lane = threadIdx.x, hh = lane >> 3;
  int h = hg * 8 + hh;
  float A = -__expf(A_log[h]);
  float D = Dp[h];
  const char* slot = (const char*)uscr + (size_t)blockIdx.x * UROWB + 4096;
  float st[16];
#pragma unroll
  for (int n = 0; n < 16; n++) st[n] = ((const float*)slot)[lane * 16 + n];
  size_t rb = (size_t)b * SEQ + (size_t)c * LC;
  for (int t = 0; t < LC; t++) {
    size_t row = rb + t;
    const float* bcrow = BC + row * 32;
    float dtv = dtf[row * NH + h];
    float x = (float)xs[row * DIN + hg * 64 + lane];
    float dA = __expf(dtv * A);
    float w = dtv * x;
    float yv = 0.f;
#pragma unroll
    for (int n = 0; n < 16; n++) {
      st[n] = st[n] * dA + w * bcrow[n];
      yv += st[n] * bcrow[16 + n];
    }
    y[row * DIN + hg * 64 + lane] = (bf16)(yv + D * x);
  }
}

// ---------------- gating + rmsnorm -> g bf16
__global__ __launch_bounds__(256) void gate_rms(const bf16* __restrict__ u,
                                                const bf16* __restrict__ y,
                                                const float* __restrict__ rms_w,
                                                bf16* __restrict__ g) {
  int row = blockIdx.x;
  int t = threadIdx.x;
  bf16x8 zv = ((const bf16x8*)(u + (size_t)row * DPROJ))[t];
  bf16x8 yv = ((const bf16x8*)(y + (size_t)row * DIN))[t];
  float gv[8];
  float s2 = 0.f;
#pragma unroll
  for (int i = 0; i < 8; i++) {
    float z = (float)zv[i];
    float yy = (float)yv[i];
    float gg = yy * z / (1.f + __expf(-z));
    gv[i] = gg;
    s2 += gg * gg;
  }
#pragma unroll
  for (int off = 32; off > 0; off >>= 1) s2 += __shfl_down(s2, off);
  __shared__ float ps[4];
  int wave = t >> 6, lane = t & 63;
  if (lane == 0) ps[wave] = s2;
  __syncthreads();
  s2 = ps[0] + ps[1] + ps[2] + ps[3];
  float scale = rsqrtf(s2 * (1.f / DIN) + 1e-5f);
  f32x4 w0 = ((const f32x4*)rms_w)[2 * t];
  f32x4 w1 = ((const f32x4*)rms_w)[2 * t + 1];
  bf16x8 og;
#pragma unroll
  for (int i = 0; i < 4; i++) og[i] = (bf16)(gv[i] * scale * w0[i]);
#pragma unroll
  for (int i = 0; i < 4; i++) og[4 + i] = (bf16)(gv[4 + i] * scale * w1[i]);
  ((bf16x8*)(g + (size_t)row * DIN))[t] = og;
}

extern "C" void kernel_launch(void* const* d_in, const int* in_sizes, int n_in,
                              void* d_out, int out_size, void* d_ws, size_t ws_size,
                              hipStream_t stream) {
  const float* x = (const float*)d_in[0];
  const float* lnw = (const float*)d_in[1];
  const float* lnb = (const float*)d_in[2];
  const float* Win = (const float*)d_in[3];
  const float* cw = (const float*)d_in[4];
  const float* cb = (const float*)d_in[5];
  const float* Alog = (const float*)d_in[6];
  const float* Dpv = (const float*)d_in[7];
  const float* dtb = (const float*)d_in[8];
  const float* rmsw = (const float*)d_in[9];
  const float* Wout = (const float*)d_in[10];
  float* out = (float*)d_out;

  char* ws = (char*)d_ws;
  bf16* u = (bf16*)(ws + 0);                     // [8192][4384] bf16
  bf16* xnb = (bf16*)(ws + 71827456);            // [8192][1024] bf16 (dead after GEMM1)
  bf16* WinT = (bf16*)(ws + 88604672);           // [4608][1024] bf16 (dead after GEMM1)
  bf16* yb = (bf16*)(ws + 71827456);             // [8192][2048] bf16 (reuses xnb+WinT)
  bf16* xsb = (bf16*)(ws + 105381888);           // [8192][2048] bf16 (dead after scan)
  bf16* gb = (bf16*)(ws + 105381888);            // reuses xsb
  float* BC = (float*)(ws + 138936320);          // [8192][32] f32
  float* dtf = (float*)(ws + 139984896);         // [8192][256] f32
  bf16* WoutT = (bf16*)(ws + 148373504);         // [1024][2048] bf16

  transpose_cvt<<<dim3(32, 144), dim3(32, 8), 0, stream>>>(Win, WinT, 1024, DPROJ, NPAD1);
  transpose_cvt<<<dim3(64, 32), dim3(32, 8), 0, stream>>>(Wout, WoutT, DIN, DM, DM);
  ln_kernel<<<MROWS, 256, 0, stream>>>(x, lnw, lnb, xnb);
  gemm1_8p<<<576, 512, 0, stream>>>(xnb, WinT, u);
  conv_prep2<<<dim3(10, 16, 4), 256, 0, stream>>>(u, cw, cb, dtb, xsb, BC, dtf);
  scan_p1<<<MROWS, 64, 0, stream>>>(xsb, BC, dtf, Alog, u);
  scan_p2<<<128, 64, 0, stream>>>(u);
  scan_p3<<<MROWS, 64, 0, stream>>>(xsb, BC, dtf, Alog, Dpv, u, yb);
  gate_rms<<<MROWS, 256, 0, stream>>>(u, yb, rmsw, gb);
  gemm2_kernel<<<dim3(DM / 128, MROWS / 128), 256, 0, stream>>>(gb, WoutT, DIN, DM, out, x);
}

// Round 5
// 324.417 us; speedup vs baseline: 1.1817x; 1.1817x over previous
//
#include <hip/hip_runtime.h>

typedef __bf16 bf16;
typedef __attribute__((ext_vector_type(8))) __bf16 bf16x8;
typedef __attribute__((ext_vector_type(4))) float f32x4;

#define B_SZ 4
#define SEQ 2048
#define DM 1024
#define DIN 2048
#define NH 256
#define DSTATE 16
#define CONVD 2080
#define DPROJ 4384
#define NPAD1 4608
#define MROWS 8192
#define NC 64
#define LC 32
#define UROWB 8768  // u row stride in bytes (4384 * 2)

__device__ __forceinline__ void gload_lds16(const void* g, void* l) {
  __builtin_amdgcn_global_load_lds(
      (__attribute__((address_space(1))) void*)g,
      (__attribute__((address_space(3))) void*)l, 16, 0, 0);
}

template <int N>
__device__ __forceinline__ void vm_wait() {
  asm volatile("s_waitcnt vmcnt(%0)" ::"n"(N) : "memory");
}
__device__ __forceinline__ void bar() { asm volatile("s_barrier" ::: "memory"); }

// ---------------- transpose (f32 [K][N] -> bf16 [Npad][K], zero-pad rows >= N)
__global__ void transpose_cvt(const float* __restrict__ W, bf16* __restrict__ WT,
                              int K, int N, int Npad) {
  __shared__ float tile[32][33];
  int k0 = blockIdx.x * 32, n0 = blockIdx.y * 32;
  int tx = threadIdx.x, ty = threadIdx.y;  // (32, 8)
#pragma unroll
  for (int j = 0; j < 4; j++) {
    int k = k0 + ty + 8 * j, n = n0 + tx;
    tile[ty + 8 * j][tx] = (k < K && n < N) ? W[(size_t)k * N + n] : 0.f;
  }
  __syncthreads();
#pragma unroll
  for (int j = 0; j < 4; j++) {
    int n = n0 + ty + 8 * j, k = k0 + tx;
    if (n < Npad && k < K) WT[(size_t)n * K + k] = (bf16)tile[tx][ty + 8 * j];
  }
}

// ---------------- layernorm (f32 in) -> xn bf16
__global__ __launch_bounds__(256) void ln_kernel(const float* __restrict__ x,
                                                 const float* __restrict__ lw,
                                                 const float* __restrict__ lb,
                                                 bf16* __restrict__ xn) {
  int row = blockIdx.x;
  int t = threadIdx.x;
  f32x4 v4 = ((const f32x4*)(x + (size_t)row * DM))[t];
  float v0 = v4[0], v1 = v4[1], v2 = v4[2], v3 = v4[3];
  float s = v0 + v1 + v2 + v3;
  float s2 = v0 * v0 + v1 * v1 + v2 * v2 + v3 * v3;
#pragma unroll
  for (int off = 32; off > 0; off >>= 1) {
    s += __shfl_down(s, off);
    s2 += __shfl_down(s2, off);
  }
  __shared__ float ps[8];
  int wave = t >> 6, lane = t & 63;
  if (lane == 0) { ps[wave] = s; ps[4 + wave] = s2; }
  __syncthreads();
  s = ps[0] + ps[1] + ps[2] + ps[3];
  s2 = ps[4] + ps[5] + ps[6] + ps[7];
  float mean = s * (1.f / DM);
  float var = s2 * (1.f / DM) - mean * mean;
  float rstd = rsqrtf(var + 1e-5f);
  f32x4 wv = ((const f32x4*)lw)[t];
  f32x4 bv = ((const f32x4*)lb)[t];
  bf16 o[4];
  o[0] = (bf16)((v0 - mean) * rstd * wv[0] + bv[0]);
  o[1] = (bf16)((v1 - mean) * rstd * wv[1] + bv[1]);
  o[2] = (bf16)((v2 - mean) * rstd * wv[2] + bv[2]);
  o[3] = (bf16)((v3 - mean) * rstd * wv[3] + bv[3]);
  bf16* dst = xn + (size_t)row * DM + t * 4;
  dst[0] = o[0]; dst[1] = o[1]; dst[2] = o[2]; dst[3] = o[3];
}

// ---------------- GEMM1: deep-pipelined 256x256, BK=64, 8 waves, counted vmcnt.
#define PHASE(MQ, NQ, P, STAGE_STMT)                                                       \
  {                                                                                        \
    const char* sa_ = lds + ((P) * 2 + MQ) * 16384;                                        \
    const char* sb_ = lds + 65536 + ((P) * 2 + NQ) * 16384;                                \
    bf16x8 a_[4][2], b_[2][2];                                                             \
    _Pragma("unroll") for (int mi = 0; mi < 4; mi++) {                                     \
      int lrow = wm * 64 + mi * 16 + lr16;                                                 \
      a_[mi][0] = *(const bf16x8*)(sa_ + lrow * 128 + ts0 * 16);                           \
      a_[mi][1] = *(const bf16x8*)(sa_ + lrow * 128 + ts1 * 16);                           \
    }                                                                                      \
    _Pragma("unroll") for (int ni = 0; ni < 2; ni++) {                                     \
      int lrow = wn * 32 + ni * 16 + lr16;                                                 \
      b_[ni][0] = *(const bf16x8*)(sb_ + lrow * 128 + ts0 * 16);                           \
      b_[ni][1] = *(const bf16x8*)(sb_ + lrow * 128 + ts1 * 16);                           \
    }                                                                                      \
    STAGE_STMT;                                                                            \
    __builtin_amdgcn_s_setprio(1);                                                         \
    _Pragma("unroll") for (int mi = 0; mi < 4; mi++)                                       \
      _Pragma("unroll") for (int ni = 0; ni < 2; ni++) {                                   \
        acc[MQ * 4 + mi][NQ * 2 + ni] = __builtin_amdgcn_mfma_f32_16x16x32_bf16(           \
            a_[mi][0], b_[ni][0], acc[MQ * 4 + mi][NQ * 2 + ni], 0, 0, 0);                 \
        acc[MQ * 4 + mi][NQ * 2 + ni] = __builtin_amdgcn_mfma_f32_16x16x32_bf16(           \
            a_[mi][1], b_[ni][1], acc[MQ * 4 + mi][NQ * 2 + ni], 0, 0, 0);                 \
      }                                                                                    \
    __builtin_amdgcn_s_setprio(0);                                                         \
  }

__global__ __launch_bounds__(512, 2) void gemm1_8p(const bf16* __restrict__ A,
                                                   const bf16* __restrict__ BT,
                                                   bf16* __restrict__ C) {
  __shared__ char lds[131072];
  int bid = blockIdx.x;                       // 576 = 32 m-tiles * 18 n-tiles
  int swz = (bid & 7) * 72 + (bid >> 3);      // bijective XCD swizzle (576 % 8 == 0)
  int bm = swz / 18, bn = swz - (swz / 18) * 18;
  int m0 = bm * 256, n0 = bn * 256;
  int t = threadIdx.x, lane = t & 63, wave = t >> 6;
  int wm = wave >> 2, wn = wave & 3;
  int lr16 = lane & 15, kq = lane >> 4;
  int ts0 = kq ^ (lr16 & 7);
  int ts1 = (4 + kq) ^ (lr16 & 7);
  int sw = (lane & 7) ^ ((lane >> 3) & 7);
  int l8 = lane >> 3;
  int c0 = 2 * wave, c1 = 2 * wave + 1;
  int lr0 = c0 * 8 + l8, lr1 = c1 * 8 + l8;
  const char* Ab = (const char*)A;
  const char* Bb = (const char*)BT;
  int grA0 = m0 + (lr0 >> 6) * 128 + (lr0 & 63);
  int grA1 = m0 + (lr1 >> 6) * 128 + (lr1 & 63);
  int gcB0 = n0 + (lr0 >> 5) * 64 + (lr0 & 31);
  int gcB1 = n0 + (lr1 >> 5) * 64 + (lr1 & 31);

  auto stA = [&](int kt, int p, int mq) {
    char* slot = lds + (p * 2 + mq) * 16384;
    size_t ko = (size_t)kt * 128 + sw * 16;
    gload_lds16(Ab + (size_t)(grA0 + mq * 64) * 2048 + ko, slot + c0 * 1024);
    gload_lds16(Ab + (size_t)(grA1 + mq * 64) * 2048 + ko, slot + c1 * 1024);
  };
  auto stB = [&](int kt, int p, int nq) {
    char* slot = lds + 65536 + (p * 2 + nq) * 16384;
    size_t ko = (size_t)kt * 128 + sw * 16;
    gload_lds16(Bb + (size_t)(gcB0 + nq * 32) * 2048 + ko, slot + c0 * 1024);
    gload_lds16(Bb + (size_t)(gcB1 + nq * 32) * 2048 + ko, slot + c1 * 1024);
  };

  f32x4 acc[8][4] = {};
  stA(0, 0, 0); stB(0, 0, 0); stA(0, 0, 1); stB(0, 0, 1); stA(1, 1, 0); stB(1, 1, 0);
#pragma unroll 1
  for (int kt = 0; kt < 16; kt++) {
    int p = kt & 1;
    if (kt < 15) vm_wait<8>(); else vm_wait<4>();
    bar();
    PHASE(0, 0, p, { if (kt + 1 < 16) stA(kt + 1, p ^ 1, 1); });
    if (kt < 15) vm_wait<6>(); else vm_wait<0>();
    bar();
    PHASE(0, 1, p, { if (kt + 1 < 16) stB(kt + 1, p ^ 1, 1); });
    bar();
    PHASE(1, 0, p, { if (kt + 2 < 16) stA(kt + 2, p, 0); });
    bar();
    PHASE(1, 1, p, { if (kt + 2 < 16) stB(kt + 2, p, 0); });
  }
#pragma unroll
  for (int mq = 0; mq < 2; mq++)
#pragma unroll
    for (int mi = 0; mi < 4; mi++)
#pragma unroll
      for (int nq = 0; nq < 2; nq++)
#pragma unroll
        for (int ni = 0; ni < 2; ni++) {
          int row = m0 + wm * 128 + mq * 64 + mi * 16 + kq * 4;
          int col = n0 + wn * 64 + nq * 32 + ni * 16 + lr16;
          f32x4 v = acc[mq * 4 + mi][nq * 2 + ni];
          if (col < 4384) {
#pragma unroll
            for (int r = 0; r < 4; r++)
              C[(size_t)(row + r) * DPROJ + col] = (bf16)v[r];
          }
        }
}

// ---------------- GEMM2: A[M][K] bf16 @ BT[N][K] bf16 -> f32 C = Xres + acc
__global__ __launch_bounds__(256) void gemm2_kernel(const bf16* __restrict__ A,
                                                    const bf16* __restrict__ BT,
                                                    int K, int ldc,
                                                    float* __restrict__ C,
                                                    const float* __restrict__ Xres) {
  __shared__ bf16 As[128 * 32];
  __shared__ bf16 Bs[128 * 32];
  int m0 = blockIdx.y * 128, n0 = blockIdx.x * 128;
  int t = threadIdx.x;
  int lane = t & 63, wave = t >> 6;
  int wm = wave >> 1, wn = wave & 1;
  int lr = lane & 15, kq = lane >> 4;
  f32x4 acc[4][4] = {};
  const char* Ab = (const char*)A;
  const char* Bb = (const char*)BT;
  size_t strideA = (size_t)K * 2;
  int r0 = t >> 2;
  int kb0 = (t & 3) * 16;
  int nk = K / 32;
  for (int kt = 0; kt < nk; ++kt) {
    size_t koff = (size_t)kt * 64;
    gload_lds16(Ab + (size_t)(m0 + r0) * strideA + koff + kb0, (char*)As + wave * 1024);
    gload_lds16(Ab + (size_t)(m0 + 64 + r0) * strideA + koff + kb0, (char*)As + 4096 + wave * 1024);
    gload_lds16(Bb + (size_t)(n0 + r0) * strideA + koff + kb0, (char*)Bs + wave * 1024);
    gload_lds16(Bb + (size_t)(n0 + 64 + r0) * strideA + koff + kb0, (char*)Bs + 4096 + wave * 1024);
    __syncthreads();
    bf16x8 af[4], bfr[4];
#pragma unroll
    for (int i = 0; i < 4; i++) af[i] = *(const bf16x8*)&As[(wm * 64 + i * 16 + lr) * 32 + kq * 8];
#pragma unroll
    for (int j = 0; j < 4; j++) bfr[j] = *(const bf16x8*)&Bs[(wn * 64 + j * 16 + lr) * 32 + kq * 8];
#pragma unroll
    for (int i = 0; i < 4; i++)
#pragma unroll
      for (int j = 0; j < 4; j++)
        acc[i][j] = __builtin_amdgcn_mfma_f32_16x16x32_bf16(af[i], bfr[j], acc[i][j], 0, 0, 0);
    __syncthreads();
  }
#pragma unroll
  for (int i = 0; i < 4; i++) {
    int row = m0 + wm * 64 + i * 16 + kq * 4;
#pragma unroll
    for (int j = 0; j < 4; j++) {
      int col = n0 + wn * 64 + j * 16 + lr;
#pragma unroll
      for (int r = 0; r < 4; r++) {
        size_t o = (size_t)(row + r) * ldc + col;
        C[o] = Xres[o] + acc[i][j][r];
      }
    }
  }
}

// ---------------- conv: one thread per 8-channel vector per row; 4 coalesced bf16x8
// tap loads (L2 catches tap overlap); silu; softplus(dt) folded in.
__global__ __launch_bounds__(256) void conv_prep3(const bf16* __restrict__ u,
                                                  const float* __restrict__ cw,
                                                  const float* __restrict__ cb,
                                                  const float* __restrict__ dt_bias,
                                                  bf16* __restrict__ xs,
                                                  float* __restrict__ BC,
                                                  float* __restrict__ dtf) {
  const int JPR = 292;  // 260 conv vec8 + 32 dt vec8
  int idx = blockIdx.x * 256 + threadIdx.x;
  if (idx >= MROWS * JPR) return;
  int row = idx / JPR;
  int j = idx - row * JPR;
  int t = row & (SEQ - 1);
  if (j < 260) {
    int c0 = j * 8;
    float acc[8];
#pragma unroll
    for (int i = 0; i < 8; i++) acc[i] = cb[c0 + i];
    const bf16* ub = u + (size_t)row * DPROJ + DIN + c0;
#pragma unroll
    for (int tap = 0; tap < 4; tap++) {
      int tt = t - 3 + tap;
      if (tt >= 0) {
        bf16x8 uv = *(const bf16x8*)(ub + (ptrdiff_t)(tap - 3) * DPROJ);
        const float* wv = cw + tap * CONVD + c0;
#pragma unroll
        for (int i = 0; i < 8; i++) acc[i] += wv[i] * (float)uv[i];
      }
    }
    if (c0 < DIN) {
      bf16x8 o;
#pragma unroll
      for (int i = 0; i < 8; i++) {
        float sv = acc[i] / (1.f + __expf(-acc[i]));
        o[i] = (bf16)sv;
      }
      *(bf16x8*)(xs + (size_t)row * DIN + c0) = o;
    } else {
      float* bc = BC + (size_t)row * 32 + (c0 - DIN);
#pragma unroll
      for (int i = 0; i < 8; i++) bc[i] = acc[i] / (1.f + __expf(-acc[i]));
    }
  } else {
    int h0 = (j - 260) * 8;
    bf16x8 uv = *(const bf16x8*)(u + (size_t)row * DPROJ + (DPROJ - NH) + h0);
    float* dst = dtf + (size_t)row * NH + h0;
#pragma unroll
    for (int i = 0; i < 8; i++) {
      float xv = (float)uv[i] + dt_bias[h0 + i];
      dst[i] = (xv > 20.f) ? xv : log1pf(__expf(xv));
    }
  }
}

// ---------------- chunked scan, phase 1: local scan from zero -> (S, P) in u's dead tail
__global__ __launch_bounds__(64) void scan_p1(const bf16* __restrict__ xs,
                                              const float* __restrict__ BC,
                                              const float* __restrict__ dtf,
                                              const float* __restrict__ A_log,
                                              bf16* __restrict__ uscr) {
  int c = blockIdx.x & 63, hg = (blockIdx.x >> 6) & 31, b = blockIdx.x >> 11;
  int lane = threadIdx.x, hh = lane >> 3;
  int h = hg * 8 + hh;
  float A = -__expf(A_log[h]);
  float st[16];
#pragma unroll
  for (int n = 0; n < 16; n++) st[n] = 0.f;
  float pcum = 1.f;
  size_t rb = (size_t)b * SEQ + (size_t)c * LC;
  for (int t = 0; t < LC; t++) {
    size_t row = rb + t;
    const float* bcrow = BC + row * 32;
    float dtv = dtf[row * NH + h];
    float x = (float)xs[row * DIN + hg * 64 + lane];
    float dA = __expf(dtv * A);
    pcum *= dA;
    float w = dtv * x;
#pragma unroll
    for (int n = 0; n < 16; n++) st[n] = st[n] * dA + w * bcrow[n];
  }
  char* slot = (char*)uscr + (size_t)blockIdx.x * UROWB + 4096;
  float* S = (float*)slot;
#pragma unroll
  for (int n = 0; n < 16; n++) S[lane * 16 + n] = st[n];
  if ((lane & 7) == 0) ((float*)(slot + 4096))[hh] = pcum;
}

// ---------------- phase 2: sequential combine over chunks (prefetched); S <- incoming H
__global__ __launch_bounds__(64) void scan_p2(bf16* __restrict__ uscr) {
  int bh = blockIdx.x;  // 0..127 = b*32+hg
  int lane = threadIdx.x, hh = lane >> 3;
  float H[16];
#pragma unroll
  for (int n = 0; n < 16; n++) H[n] = 0.f;
  char* base = (char*)uscr + (size_t)bh * NC * UROWB + 4096;
  float sN[16], PN;
  {
    float* S = (float*)base;
#pragma unroll
    for (int n = 0; n < 16; n++) sN[n] = S[lane * 16 + n];
    PN = ((const float*)(base + 4096))[hh];
  }
  for (int c = 0; c < NC; c++) {
    float sC[16], PC = PN;
#pragma unroll
    for (int n = 0; n < 16; n++) sC[n] = sN[n];
    if (c + 1 < NC) {
      char* slot = base + (size_t)(c + 1) * UROWB;
      float* S = (float*)slot;
#pragma unroll
      for (int n = 0; n < 16; n++) sN[n] = S[lane * 16 + n];
      PN = ((const float*)(slot + 4096))[hh];
    }
    float* S0 = (float*)(base + (size_t)c * UROWB);
#pragma unroll
    for (int n = 0; n < 16; n++) {
      float hn = H[n];
      S0[lane * 16 + n] = hn;
      H[n] = PC * hn + sC[n];
    }
  }
}

// ---------------- phase 3: re-scan each chunk from true incoming state, emit y
__global__ __launch_bounds__(64) void scan_p3(const bf16* __restrict__ xs,
                                              const float* __restrict__ BC,
                                              const float* __restrict__ dtf,
                                              const float* __restrict__ A_log,
                                              const float* __restrict__ Dp,
                                              const bf16* __restrict__ uscr,
                                              bf16* __restrict__ y) {
  int c = blockIdx.x & 63, hg = (blockIdx.x >> 6) & 31, b = blockIdx.x >> 11;
  int lane = threadIdx.x, hh = lane >> 3;
  int h = hg * 8 + hh;
  float A = -__expf(A_log[h]);
  float D = Dp[h];
  const char* slot = (const char*)uscr + (size_t)blockIdx.x * UROWB + 4096;
  float st[16];
#pragma unroll
  for (int n = 0; n < 16; n++) st[n] = ((const float*)slot)[lane * 16 + n];
  size_t rb = (size_t)b * SEQ + (size_t)c * LC;
  for (int t = 0; t < LC; t++) {
    size_t row = rb + t;
    const float* bcrow = BC + row * 32;
    float dtv = dtf[row * NH + h];
    float x = (float)xs[row * DIN + hg * 64 + lane];
    float dA = __expf(dtv * A);
    float w = dtv * x;
    float yv = 0.f;
#pragma unroll
    for (int n = 0; n < 16; n++) {
      st[n] = st[n] * dA + w * bcrow[n];
      yv += st[n] * bcrow[16 + n];
    }
    y[row * DIN + hg * 64 + lane] = (bf16)(yv + D * x);
  }
}

// ---------------- gating + rmsnorm -> g bf16
__global__ __launch_bounds__(256) void gate_rms(const bf16* __restrict__ u,
                                                const bf16* __restrict__ y,
                                                const float* __restrict__ rms_w,
                                                bf16* __restrict__ g) {
  int row = blockIdx.x;
  int t = threadIdx.x;
  bf16x8 zv = ((const bf16x8*)(u + (size_t)row * DPROJ))[t];
  bf16x8 yv = ((const bf16x8*)(y + (size_t)row * DIN))[t];
  float gv[8];
  float s2 = 0.f;
#pragma unroll
  for (int i = 0; i < 8; i++) {
    float z = (float)zv[i];
    float yy = (float)yv[i];
    float gg = yy * z / (1.f + __expf(-z));
    gv[i] = gg;
    s2 += gg * gg;
  }
#pragma unroll
  for (int off = 32; off > 0; off >>= 1) s2 += __shfl_down(s2, off);
  __shared__ float ps[4];
  int wave = t >> 6, lane = t & 63;
  if (lane == 0) ps[wave] = s2;
  __syncthreads();
  s2 = ps[0] + ps[1] + ps[2] + ps[3];
  float scale = rsqrtf(s2 * (1.f / DIN) + 1e-5f);
  f32x4 w0 = ((const f32x4*)rms_w)[2 * t];
  f32x4 w1 = ((const f32x4*)rms_w)[2 * t + 1];
  bf16x8 og;
#pragma unroll
  for (int i = 0; i < 4; i++) og[i] = (bf16)(gv[i] * scale * w0[i]);
#pragma unroll
  for (int i = 0; i < 4; i++) og[4 + i] = (bf16)(gv[4 + i] * scale * w1[i]);
  ((bf16x8*)(g + (size_t)row * DIN))[t] = og;
}

extern "C" void kernel_launch(void* const* d_in, const int* in_sizes, int n_in,
                              void* d_out, int out_size, void* d_ws, size_t ws_size,
                              hipStream_t stream) {
  const float* x = (const float*)d_in[0];
  const float* lnw = (const float*)d_in[1];
  const float* lnb = (const float*)d_in[2];
  const float* Win = (const float*)d_in[3];
  const float* cw = (const float*)d_in[4];
  const float* cb = (const float*)d_in[5];
  const float* Alog = (const float*)d_in[6];
  const float* Dpv = (const float*)d_in[7];
  const float* dtb = (const float*)d_in[8];
  const float* rmsw = (const float*)d_in[9];
  const float* Wout = (const float*)d_in[10];
  float* out = (float*)d_out;

  char* ws = (char*)d_ws;
  bf16* u = (bf16*)(ws + 0);                     // [8192][4384] bf16
  bf16* xnb = (bf16*)(ws + 71827456);            // [8192][1024] bf16 (dead after GEMM1)
  bf16* WinT = (bf16*)(ws + 88604672);           // [4608][1024] bf16 (dead after GEMM1)
  bf16* yb = (bf16*)(ws + 71827456);             // [8192][2048] bf16 (reuses xnb+WinT)
  bf16* xsb = (bf16*)(ws + 105381888);           // [8192][2048] bf16 (dead after scan)
  bf16* gb = (bf16*)(ws + 105381888);            // reuses xsb
  float* BC = (float*)(ws + 138936320);          // [8192][32] f32
  float* dtf = (float*)(ws + 139984896);         // [8192][256] f32
  bf16* WoutT = (bf16*)(ws + 148373504);         // [1024][2048] bf16

  transpose_cvt<<<dim3(32, 144), dim3(32, 8), 0, stream>>>(Win, WinT, 1024, DPROJ, NPAD1);
  transpose_cvt<<<dim3(64, 32), dim3(32, 8), 0, stream>>>(Wout, WoutT, DIN, DM, DM);
  ln_kernel<<<MROWS, 256, 0, stream>>>(x, lnw, lnb, xnb);
  gemm1_8p<<<576, 512, 0, stream>>>(xnb, WinT, u);
  conv_prep3<<<(MROWS * 292) / 256, 256, 0, stream>>>(u, cw, cb, dtb, xsb, BC, dtf);
  scan_p1<<<MROWS, 64, 0, stream>>>(xsb, BC, dtf, Alog, u);
  scan_p2<<<128, 64, 0, stream>>>(u);
  scan_p3<<<MROWS, 64, 0, stream>>>(xsb, BC, dtf, Alog, Dpv, u, yb);
  gate_rms<<<MROWS, 256, 0, stream>>>(u, yb, rmsw, gb);
  gemm2_kernel<<<dim3(DM / 128, MROWS / 128), 256, 0, stream>>>(gb, WoutT, DIN, DM, out, x);
}

// Round 6
// 321.527 us; speedup vs baseline: 1.1923x; 1.0090x over previous
//
#include <hip/hip_runtime.h>

typedef __bf16 bf16;
typedef __attribute__((ext_vector_type(8))) __bf16 bf16x8;
typedef __attribute__((ext_vector_type(4))) float f32x4;

#define B_SZ 4
#define SEQ 2048
#define DM 1024
#define DIN 2048
#define NH 256
#define DSTATE 16
#define CONVD 2080
#define DPROJ 4384
#define NPAD1 4608
#define MROWS 8192
#define NC 64
#define LC 32
#define UROWB 8768  // u row stride in bytes (4384 * 2)

__device__ __forceinline__ void gload_lds16(const void* g, void* l) {
  __builtin_amdgcn_global_load_lds(
      (__attribute__((address_space(1))) void*)g,
      (__attribute__((address_space(3))) void*)l, 16, 0, 0);
}

template <int N>
__device__ __forceinline__ void vm_wait() {
  asm volatile("s_waitcnt vmcnt(%0)" ::"n"(N) : "memory");
}
__device__ __forceinline__ void bar() { asm volatile("s_barrier" ::: "memory"); }
__device__ __forceinline__ void lgkm0() {
  asm volatile("s_waitcnt lgkmcnt(0)" ::: "memory");
}

// ---------------- transpose (f32 [K][N] -> bf16 [Npad][K], zero-pad rows >= N)
__global__ void transpose_cvt(const float* __restrict__ W, bf16* __restrict__ WT,
                              int K, int N, int Npad) {
  __shared__ float tile[32][33];
  int k0 = blockIdx.x * 32, n0 = blockIdx.y * 32;
  int tx = threadIdx.x, ty = threadIdx.y;  // (32, 8)
#pragma unroll
  for (int j = 0; j < 4; j++) {
    int k = k0 + ty + 8 * j, n = n0 + tx;
    tile[ty + 8 * j][tx] = (k < K && n < N) ? W[(size_t)k * N + n] : 0.f;
  }
  __syncthreads();
#pragma unroll
  for (int j = 0; j < 4; j++) {
    int n = n0 + ty + 8 * j, k = k0 + tx;
    if (n < Npad && k < K) WT[(size_t)n * K + k] = (bf16)tile[tx][ty + 8 * j];
  }
}

// ---------------- layernorm (f32 in) -> xn bf16
__global__ __launch_bounds__(256) void ln_kernel(const float* __restrict__ x,
                                                 const float* __restrict__ lw,
                                                 const float* __restrict__ lb,
                                                 bf16* __restrict__ xn) {
  int row = blockIdx.x;
  int t = threadIdx.x;
  f32x4 v4 = ((const f32x4*)(x + (size_t)row * DM))[t];
  float v0 = v4[0], v1 = v4[1], v2 = v4[2], v3 = v4[3];
  float s = v0 + v1 + v2 + v3;
  float s2 = v0 * v0 + v1 * v1 + v2 * v2 + v3 * v3;
#pragma unroll
  for (int off = 32; off > 0; off >>= 1) {
    s += __shfl_down(s, off);
    s2 += __shfl_down(s2, off);
  }
  __shared__ float ps[8];
  int wave = t >> 6, lane = t & 63;
  if (lane == 0) { ps[wave] = s; ps[4 + wave] = s2; }
  __syncthreads();
  s = ps[0] + ps[1] + ps[2] + ps[3];
  s2 = ps[4] + ps[5] + ps[6] + ps[7];
  float mean = s * (1.f / DM);
  float var = s2 * (1.f / DM) - mean * mean;
  float rstd = rsqrtf(var + 1e-5f);
  f32x4 wv = ((const f32x4*)lw)[t];
  f32x4 bv = ((const f32x4*)lb)[t];
  bf16 o[4];
  o[0] = (bf16)((v0 - mean) * rstd * wv[0] + bv[0]);
  o[1] = (bf16)((v1 - mean) * rstd * wv[1] + bv[1]);
  o[2] = (bf16)((v2 - mean) * rstd * wv[2] + bv[2]);
  o[3] = (bf16)((v3 - mean) * rstd * wv[3] + bv[3]);
  bf16* dst = xn + (size_t)row * DM + t * 4;
  dst[0] = o[0]; dst[1] = o[1]; dst[2] = o[2]; dst[3] = o[3];
}

// ---------------- GEMM1: 256x256, BK=64, 8 waves, dual-barrier phases, counted vmcnt
#define G1_PHASE(MQ, NQ, P, STAGE, VMW)                                                    \
  {                                                                                        \
    const char* sa_ = lds + ((P) * 2 + (MQ)) * 16384;                                      \
    const char* sb_ = lds + 65536 + ((P) * 2 + (NQ)) * 16384;                              \
    bf16x8 a_[4][2], b_[2][2];                                                             \
    _Pragma("unroll") for (int mi = 0; mi < 4; mi++) {                                     \
      int lrow = wm * 64 + mi * 16 + lr16;                                                 \
      a_[mi][0] = *(const bf16x8*)(sa_ + lrow * 128 + ts0 * 16);                           \
      a_[mi][1] = *(const bf16x8*)(sa_ + lrow * 128 + ts1 * 16);                           \
    }                                                                                      \
    _Pragma("unroll") for (int ni = 0; ni < 2; ni++) {                                     \
      int lrow = wn * 32 + ni * 16 + lr16;                                                 \
      b_[ni][0] = *(const bf16x8*)(sb_ + lrow * 128 + ts0 * 16);                           \
      b_[ni][1] = *(const bf16x8*)(sb_ + lrow * 128 + ts1 * 16);                           \
    }                                                                                      \
    STAGE;                                                                                 \
    VMW;                                                                                   \
    bar();                                                                                 \
    lgkm0();                                                                               \
    __builtin_amdgcn_s_setprio(1);                                                         \
    _Pragma("unroll") for (int mi = 0; mi < 4; mi++)                                       \
      _Pragma("unroll") for (int ni = 0; ni < 2; ni++) {                                   \
        acc[(MQ) * 4 + mi][(NQ) * 2 + ni] = __builtin_amdgcn_mfma_f32_16x16x32_bf16(       \
            a_[mi][0], b_[ni][0], acc[(MQ) * 4 + mi][(NQ) * 2 + ni], 0, 0, 0);             \
        acc[(MQ) * 4 + mi][(NQ) * 2 + ni] = __builtin_amdgcn_mfma_f32_16x16x32_bf16(       \
            a_[mi][1], b_[ni][1], acc[(MQ) * 4 + mi][(NQ) * 2 + ni], 0, 0, 0);             \
      }                                                                                    \
    __builtin_amdgcn_s_setprio(0);                                                         \
    bar();                                                                                 \
  }

__global__ __launch_bounds__(512, 2) void gemm1_8p(const bf16* __restrict__ A,
                                                   const bf16* __restrict__ BT,
                                                   bf16* __restrict__ C) {
  __shared__ char lds[131072];
  int bid = blockIdx.x;                       // 576 = 32 m-tiles * 18 n-tiles
  int swz = (bid & 7) * 72 + (bid >> 3);      // bijective XCD swizzle (576 % 8 == 0)
  int bm = swz / 18, bn = swz - (swz / 18) * 18;
  int m0 = bm * 256, n0 = bn * 256;
  int t = threadIdx.x, lane = t & 63, wave = t >> 6;
  int wm = wave >> 2, wn = wave & 3;
  int lr16 = lane & 15, kq = lane >> 4;
  int ts0 = kq ^ (lr16 & 7);
  int ts1 = (4 + kq) ^ (lr16 & 7);
  int sw = (lane & 7) ^ ((lane >> 3) & 7);
  int l8 = lane >> 3;
  int c0 = 2 * wave, c1 = 2 * wave + 1;
  int lr0 = c0 * 8 + l8, lr1 = c1 * 8 + l8;
  const char* Ab = (const char*)A;
  const char* Bb = (const char*)BT;
  int grA0 = m0 + (lr0 >> 6) * 128 + (lr0 & 63);
  int grA1 = m0 + (lr1 >> 6) * 128 + (lr1 & 63);
  int gcB0 = n0 + (lr0 >> 5) * 64 + (lr0 & 31);
  int gcB1 = n0 + (lr1 >> 5) * 64 + (lr1 & 31);

  auto stA = [&](int kt, int p, int mq) {
    char* slot = lds + (p * 2 + mq) * 16384;
    size_t ko = (size_t)kt * 128 + sw * 16;
    gload_lds16(Ab + (size_t)(grA0 + mq * 64) * 2048 + ko, slot + c0 * 1024);
    gload_lds16(Ab + (size_t)(grA1 + mq * 64) * 2048 + ko, slot + c1 * 1024);
  };
  auto stB = [&](int kt, int p, int nq) {
    char* slot = lds + 65536 + (p * 2 + nq) * 16384;
    size_t ko = (size_t)kt * 128 + sw * 16;
    gload_lds16(Bb + (size_t)(gcB0 + nq * 32) * 2048 + ko, slot + c0 * 1024);
    gload_lds16(Bb + (size_t)(gcB1 + nq * 32) * 2048 + ko, slot + c1 * 1024);
  };

  f32x4 acc[8][4] = {};
  // prologue queue: A00,B00,A01,B01 (kt0) + A10,B10 (kt1) = 12 instr
  stA(0, 0, 0); stB(0, 0, 0); stA(0, 0, 1); stB(0, 0, 1); stA(1, 1, 0); stB(1, 1, 0);
  vm_wait<8>();
  bar();
#pragma unroll 1
  for (int kt = 0; kt < 16; kt++) {
    int p = kt & 1;
    G1_PHASE(0, 0, p, { if (kt + 1 < 16) stA(kt + 1, p ^ 1, 1); },
             { if (kt < 15) vm_wait<6>(); else vm_wait<0>(); });
    G1_PHASE(0, 1, p, { if (kt + 1 < 16) stB(kt + 1, p ^ 1, 1); }, {});
    G1_PHASE(1, 0, p, { if (kt + 2 < 16) stA(kt + 2, p, 0); }, {});
    G1_PHASE(1, 1, p, { if (kt + 2 < 16) stB(kt + 2, p, 0); },
             { if (kt < 14) vm_wait<8>(); else if (kt == 14) vm_wait<4>(); });
  }
#pragma unroll
  for (int mq = 0; mq < 2; mq++)
#pragma unroll
    for (int mi = 0; mi < 4; mi++)
#pragma unroll
      for (int nq = 0; nq < 2; nq++)
#pragma unroll
        for (int ni = 0; ni < 2; ni++) {
          int row = m0 + wm * 128 + mq * 64 + mi * 16 + kq * 4;
          int col = n0 + wn * 64 + nq * 32 + ni * 16 + lr16;
          f32x4 v = acc[mq * 4 + mi][nq * 2 + ni];
          if (col < 4384) {
#pragma unroll
            for (int r = 0; r < 4; r++)
              C[(size_t)(row + r) * DPROJ + col] = (bf16)v[r];
          }
        }
}

// ---------------- GEMM2: 256x128, BK=64, 8 waves, grid 256 (=1/CU), same skeleton.
// LDS: A[p][mq] 4x16KB at 0; B[p] 2x16KB at 65536. 96 KiB.
#define G2_PHASE(MQ, P, STAGE, VMW)                                                        \
  {                                                                                        \
    const char* sa_ = lds + ((P) * 2 + (MQ)) * 16384;                                      \
    const char* sb_ = lds + 65536 + (P) * 16384;                                           \
    bf16x8 a_[4][2], b_[2][2];                                                             \
    _Pragma("unroll") for (int mi = 0; mi < 4; mi++) {                                     \
      int lrow = wm * 64 + mi * 16 + lr16;                                                 \
      a_[mi][0] = *(const bf16x8*)(sa_ + lrow * 128 + ts0 * 16);                           \
      a_[mi][1] = *(const bf16x8*)(sa_ + lrow * 128 + ts1 * 16);                           \
    }                                                                                      \
    _Pragma("unroll") for (int ni = 0; ni < 2; ni++) {                                     \
      int lrow = wn * 32 + ni * 16 + lr16;                                                 \
      b_[ni][0] = *(const bf16x8*)(sb_ + lrow * 128 + ts0 * 16);                           \
      b_[ni][1] = *(const bf16x8*)(sb_ + lrow * 128 + ts1 * 16);                           \
    }                                                                                      \
    STAGE;                                                                                 \
    VMW;                                                                                   \
    bar();                                                                                 \
    lgkm0();                                                                               \
    __builtin_amdgcn_s_setprio(1);                                                         \
    _Pragma("unroll") for (int mi = 0; mi < 4; mi++)                                       \
      _Pragma("unroll") for (int ni = 0; ni < 2; ni++) {                                   \
        acc[(MQ) * 4 + mi][ni] = __builtin_amdgcn_mfma_f32_16x16x32_bf16(                  \
            a_[mi][0], b_[ni][0], acc[(MQ) * 4 + mi][ni], 0, 0, 0);                        \
        acc[(MQ) * 4 + mi][ni] = __builtin_amdgcn_mfma_f32_16x16x32_bf16(                  \
            a_[mi][1], b_[ni][1], acc[(MQ) * 4 + mi][ni], 0, 0, 0);                        \
      }                                                                                    \
    __builtin_amdgcn_s_setprio(0);                                                         \
    bar();                                                                                 \
  }

__global__ __launch_bounds__(512, 2) void gemm2_8p(const bf16* __restrict__ A,
                                                   const bf16* __restrict__ BT,
                                                   float* __restrict__ C,
                                                   const float* __restrict__ Xres) {
  __shared__ char lds[98304];
  int bid = blockIdx.x;                  // 256 = 32 m * 8 n
  int swz = (bid & 7) * 32 + (bid >> 3); // bijective (256 % 8 == 0)
  int bm = swz >> 3, bn = swz & 7;
  int m0 = bm * 256, n0 = bn * 128;
  int t = threadIdx.x, lane = t & 63, wave = t >> 6;
  int wm = wave >> 2, wn = wave & 3;
  int lr16 = lane & 15, kq = lane >> 4;
  int ts0 = kq ^ (lr16 & 7);
  int ts1 = (4 + kq) ^ (lr16 & 7);
  int sw = (lane & 7) ^ ((lane >> 3) & 7);
  int l8 = lane >> 3;
  int c0 = 2 * wave, c1 = 2 * wave + 1;
  int lr0 = c0 * 8 + l8, lr1 = c1 * 8 + l8;
  const char* Ab = (const char*)A;
  const char* Bb = (const char*)BT;
  int grA0 = m0 + (lr0 >> 6) * 128 + (lr0 & 63);
  int grA1 = m0 + (lr1 >> 6) * 128 + (lr1 & 63);
  int gcB0 = n0 + lr0, gcB1 = n0 + lr1;  // lr in [0,128)

  auto stA = [&](int kt, int p, int mq) {
    char* slot = lds + (p * 2 + mq) * 16384;
    size_t ko = (size_t)kt * 128 + sw * 16;
    gload_lds16(Ab + (size_t)(grA0 + mq * 64) * 4096 + ko, slot + c0 * 1024);
    gload_lds16(Ab + (size_t)(grA1 + mq * 64) * 4096 + ko, slot + c1 * 1024);
  };
  auto stB = [&](int kt, int p) {
    char* slot = lds + 65536 + p * 16384;
    size_t ko = (size_t)kt * 128 + sw * 16;
    gload_lds16(Bb + (size_t)gcB0 * 4096 + ko, slot + c0 * 1024);
    gload_lds16(Bb + (size_t)gcB1 * 4096 + ko, slot + c1 * 1024);
  };

  f32x4 acc[8][2] = {};
  // prologue queue: A0@0, B@0, A1@0, A0@1 = 8 instr
  stA(0, 0, 0); stB(0, 0); stA(0, 0, 1); stA(1, 1, 0);
  vm_wait<4>();
  bar();
#pragma unroll 1
  for (int kt = 0; kt < 32; kt++) {
    int p = kt & 1;
    // ph1 reads A[p][0], B[p]; issues B@kt+1, A1@kt+1
    G2_PHASE(0, p, { if (kt + 1 < 32) { stB(kt + 1, p ^ 1); stA(kt + 1, p ^ 1, 1); } },
             { if (kt < 31) vm_wait<6>(); else vm_wait<0>(); });
    // ph2 reads A[p][1], B[p]; issues A0@kt+2
    G2_PHASE(1, p, { if (kt + 2 < 32) stA(kt + 2, p, 0); },
             { if (kt < 30) vm_wait<4>(); else if (kt == 30) vm_wait<2>(); });
  }
#pragma unroll
  for (int mq = 0; mq < 2; mq++)
#pragma unroll
    for (int mi = 0; mi < 4; mi++)
#pragma unroll
      for (int ni = 0; ni < 2; ni++) {
        int row = m0 + wm * 128 + mq * 64 + mi * 16 + kq * 4;
        int col = n0 + wn * 32 + ni * 16 + lr16;
        f32x4 v = acc[mq * 4 + mi][ni];
#pragma unroll
        for (int r = 0; r < 4; r++) {
          size_t o = (size_t)(row + r) * DM + col;
          C[o] = Xres[o] + v[r];
        }
      }
}

// ---------------- conv: one thread per 8-channel vector per row
__global__ __launch_bounds__(256) void conv_prep3(const bf16* __restrict__ u,
                                                  const float* __restrict__ cw,
                                                  const float* __restrict__ cb,
                                                  const float* __restrict__ dt_bias,
                                                  bf16* __restrict__ xs,
                                                  float* __restrict__ BC,
                                                  float* __restrict__ dtf) {
  const int JPR = 292;  // 260 conv vec8 + 32 dt vec8
  int idx = blockIdx.x * 256 + threadIdx.x;
  if (idx >= MROWS * JPR) return;
  int row = idx / JPR;
  int j = idx - row * JPR;
  int t = row & (SEQ - 1);
  if (j < 260) {
    int c0 = j * 8;
    float acc[8];
#pragma unroll
    for (int i = 0; i < 8; i++) acc[i] = cb[c0 + i];
    const bf16* ub = u + (size_t)row * DPROJ + DIN + c0;
#pragma unroll
    for (int tap = 0; tap < 4; tap++) {
      int tt = t - 3 + tap;
      if (tt >= 0) {
        bf16x8 uv = *(const bf16x8*)(ub + (ptrdiff_t)(tap - 3) * DPROJ);
        const float* wv = cw + tap * CONVD + c0;
#pragma unroll
        for (int i = 0; i < 8; i++) acc[i] += wv[i] * (float)uv[i];
      }
    }
    if (c0 < DIN) {
      bf16x8 o;
#pragma unroll
      for (int i = 0; i < 8; i++) {
        float sv = acc[i] / (1.f + __expf(-acc[i]));
        o[i] = (bf16)sv;
      }
      *(bf16x8*)(xs + (size_t)row * DIN + c0) = o;
    } else {
      float* bc = BC + (size_t)row * 32 + (c0 - DIN);
#pragma unroll
      for (int i = 0; i < 8; i++) bc[i] = acc[i] / (1.f + __expf(-acc[i]));
    }
  } else {
    int h0 = (j - 260) * 8;
    bf16x8 uv = *(const bf16x8*)(u + (size_t)row * DPROJ + (DPROJ - NH) + h0);
    float* dst = dtf + (size_t)row * NH + h0;
#pragma unroll
    for (int i = 0; i < 8; i++) {
      float xv = (float)uv[i] + dt_bias[h0 + i];
      dst[i] = (xv > 20.f) ? xv : log1pf(__expf(xv));
    }
  }
}

// ---------------- chunked scan, phase 1: local scan from zero -> (S, P) in u's dead tail
__global__ __launch_bounds__(64) void scan_p1(const bf16* __restrict__ xs,
                                              const float* __restrict__ BC,
                                              const float* __restrict__ dtf,
                                              const float* __restrict__ A_log,
                                              bf16* __restrict__ uscr) {
  int c = blockIdx.x & 63, hg = (blockIdx.x >> 6) & 31, b = blockIdx.x >> 11;
  int lane = threadIdx.x, hh = lane >> 3;
  int h = hg * 8 + hh;
  float A = -__expf(A_log[h]);
  float st[16];
#pragma unroll
  for (int n = 0; n < 16; n++) st[n] = 0.f;
  float pcum = 1.f;
  size_t rb = (size_t)b * SEQ + (size_t)c * LC;
  for (int t = 0; t < LC; t++) {
    size_t row = rb + t;
    const float* bcrow = BC + row * 32;
    float dtv = dtf[row * NH + h];
    float x = (float)xs[row * DIN + hg * 64 + lane];
    float dA = __expf(dtv * A);
    pcum *= dA;
    float w = dtv * x;
#pragma unroll
    for (int n = 0; n < 16; n++) st[n] = st[n] * dA + w * bcrow[n];
  }
  char* slot = (char*)uscr + (size_t)blockIdx.x * UROWB + 4096;
  float* S = (float*)slot;
#pragma unroll
  for (int n = 0; n < 16; n++) S[lane * 16 + n] = st[n];
  if ((lane & 7) == 0) ((float*)(slot + 4096))[hh] = pcum;
}

// ---------------- phase 2: sequential combine over chunks (prefetched); S <- incoming H
__global__ __launch_bounds__(64) void scan_p2(bf16* __restrict__ uscr) {
  int bh = blockIdx.x;  // 0..127 = b*32+hg
  int lane = threadIdx.x, hh = lane >> 3;
  float H[16];
#pragma unroll
  for (int n = 0; n < 16; n++) H[n] = 0.f;
  char* base = (char*)uscr + (size_t)bh * NC * UROWB + 4096;
  float sN[16], PN;
  {
    float* S = (float*)base;
#pragma unroll
    for (int n = 0; n < 16; n++) sN[n] = S[lane * 16 + n];
    PN = ((const float*)(base + 4096))[hh];
  }
  for (int c = 0; c < NC; c++) {
    float sC[16], PC = PN;
#pragma unroll
    for (int n = 0; n < 16; n++) sC[n] = sN[n];
    if (c + 1 < NC) {
      char* slot = base + (size_t)(c + 1) * UROWB;
      float* S = (float*)slot;
#pragma unroll
      for (int n = 0; n < 16; n++) sN[n] = S[lane * 16 + n];
      PN = ((const float*)(slot + 4096))[hh];
    }
    float* S0 = (float*)(base + (size_t)c * UROWB);
#pragma unroll
    for (int n = 0; n < 16; n++) {
      float hn = H[n];
      S0[lane * 16 + n] = hn;
      H[n] = PC * hn + sC[n];
    }
  }
}

// ---------------- phase 3: re-scan each chunk from true incoming state, emit y
__global__ __launch_bounds__(64) void scan_p3(const bf16* __restrict__ xs,
                                              const float* __restrict__ BC,
                                              const float* __restrict__ dtf,
                                              const float* __restrict__ A_log,
                                              const float* __restrict__ Dp,
                                              const bf16* __restrict__ uscr,
                                              bf16* __restrict__ y) {
  int c = blockIdx.x & 63, hg = (blockIdx.x >> 6) & 31, b = blockIdx.x >> 11;
  int lane = threadIdx.x, hh = lane >> 3;
  int h = hg * 8 + hh;
  float A = -__expf(A_log[h]);
  float D = Dp[h];
  const char* slot = (const char*)uscr + (size_t)blockIdx.x * UROWB + 4096;
  float st[16];
#pragma unroll
  for (int n = 0; n < 16; n++) st[n] = ((const float*)slot)[lane * 16 + n];
  size_t rb = (size_t)b * SEQ + (size_t)c * LC;
  for (int t = 0; t < LC; t++) {
    size_t row = rb + t;
    const float* bcrow = BC + row * 32;
    float dtv = dtf[row * NH + h];
    float x = (float)xs[row * DIN + hg * 64 + lane];
    float dA = __expf(dtv * A);
    float w = dtv * x;
    float yv = 0.f;
#pragma unroll
    for (int n = 0; n < 16; n++) {
      st[n] = st[n] * dA + w * bcrow[n];
      yv += st[n] * bcrow[16 + n];
    }
    y[row * DIN + hg * 64 + lane] = (bf16)(yv + D * x);
  }
}

// ---------------- gating + rmsnorm -> g bf16
__global__ __launch_bounds__(256) void gate_rms(const bf16* __restrict__ u,
                                                const bf16* __restrict__ y,
                                                const float* __restrict__ rms_w,
                                                bf16* __restrict__ g) {
  int row = blockIdx.x;
  int t = threadIdx.x;
  bf16x8 zv = ((const bf16x8*)(u + (size_t)row * DPROJ))[t];
  bf16x8 yv = ((const bf16x8*)(y + (size_t)row * DIN))[t];
  float gv[8];
  float s2 = 0.f;
#pragma unroll
  for (int i = 0; i < 8; i++) {
    float z = (float)zv[i];
    float yy = (float)yv[i];
    float gg = yy * z / (1.f + __expf(-z));
    gv[i] = gg;
    s2 += gg * gg;
  }
#pragma unroll
  for (int off = 32; off > 0; off >>= 1) s2 += __shfl_down(s2, off);
  __shared__ float ps[4];
  int wave = t >> 6, lane = t & 63;
  if (lane == 0) ps[wave] = s2;
  __syncthreads();
  s2 = ps[0] + ps[1] + ps[2] + ps[3];
  float scale = rsqrtf(s2 * (1.f / DIN) + 1e-5f);
  f32x4 w0 = ((const f32x4*)rms_w)[2 * t];
  f32x4 w1 = ((const f32x4*)rms_w)[2 * t + 1];
  bf16x8 og;
#pragma unroll
  for (int i = 0; i < 4; i++) og[i] = (bf16)(gv[i] * scale * w0[i]);
#pragma unroll
  for (int i = 0; i < 4; i++) og[4 + i] = (bf16)(gv[4 + i] * scale * w1[i]);
  ((bf16x8*)(g + (size_t)row * DIN))[t] = og;
}

extern "C" void kernel_launch(void* const* d_in, const int* in_sizes, int n_in,
                              void* d_out, int out_size, void* d_ws, size_t ws_size,
                              hipStream_t stream) {
  const float* x = (const float*)d_in[0];
  const float* lnw = (const float*)d_in[1];
  const float* lnb = (const float*)d_in[2];
  const float* Win = (const float*)d_in[3];
  const float* cw = (const float*)d_in[4];
  const float* cb = (const float*)d_in[5];
  const float* Alog = (const float*)d_in[6];
  const float* Dpv = (const float*)d_in[7];
  const float* dtb = (const float*)d_in[8];
  const float* rmsw = (const float*)d_in[9];
  const float* Wout = (const float*)d_in[10];
  float* out = (float*)d_out;

  char* ws = (char*)d_ws;
  bf16* u = (bf16*)(ws + 0);                     // [8192][4384] bf16
  bf16* xnb = (bf16*)(ws + 71827456);            // [8192][1024] bf16 (dead after GEMM1)
  bf16* WinT = (bf16*)(ws + 88604672);           // [4608][1024] bf16 (dead after GEMM1)
  bf16* yb = (bf16*)(ws + 71827456);             // [8192][2048] bf16 (reuses xnb+WinT)
  bf16* xsb = (bf16*)(ws + 105381888);           // [8192][2048] bf16 (dead after scan)
  bf16* gb = (bf16*)(ws + 105381888);            // reuses xsb
  float* BC = (float*)(ws + 138936320);          // [8192][32] f32
  float* dtf = (float*)(ws + 139984896);         // [8192][256] f32
  bf16* WoutT = (bf16*)(ws + 148373504);         // [1024][2048] bf16

  transpose_cvt<<<dim3(32, 144), dim3(32, 8), 0, stream>>>(Win, WinT, 1024, DPROJ, NPAD1);
  transpose_cvt<<<dim3(64, 32), dim3(32, 8), 0, stream>>>(Wout, WoutT, DIN, DM, DM);
  ln_kernel<<<MROWS, 256, 0, stream>>>(x, lnw, lnb, xnb);
  gemm1_8p<<<576, 512, 0, stream>>>(xnb, WinT, u);
  conv_prep3<<<(MROWS * 292) / 256, 256, 0, stream>>>(u, cw, cb, dtb, xsb, BC, dtf);
  scan_p1<<<MROWS, 64, 0, stream>>>(xsb, BC, dtf, Alog, u);
  scan_p2<<<128, 64, 0, stream>>>(u);
  scan_p3<<<MROWS, 64, 0, stream>>>(xsb, BC, dtf, Alog, Dpv, u, yb);
  gate_rms<<<MROWS, 256, 0, stream>>>(u, yb, rmsw, gb);
  gemm2_8p<<<256, 512, 0, stream>>>(gb, WoutT, out, x);
}

// Round 7
// 311.560 us; speedup vs baseline: 1.2304x; 1.0320x over previous
//
#include <hip/hip_runtime.h>

typedef __bf16 bf16;
typedef __attribute__((ext_vector_type(8))) __bf16 bf16x8;
typedef __attribute__((ext_vector_type(4))) float f32x4;

#define B_SZ 4
#define SEQ 2048
#define DM 1024
#define DIN 2048
#define NH 256
#define DSTATE 16
#define CONVD 2080
#define DPROJ 4384
#define NPAD1 4608
#define MROWS 8192
#define NC 64
#define LC 32
#define UROWB 8768  // u row stride in bytes (4384 * 2)

__device__ __forceinline__ void gload_lds16(const void* g, void* l) {
  __builtin_amdgcn_global_load_lds(
      (__attribute__((address_space(1))) void*)g,
      (__attribute__((address_space(3))) void*)l, 16, 0, 0);
}

template <int N>
__device__ __forceinline__ void vm_wait() {
  asm volatile("s_waitcnt vmcnt(%0)" ::"n"(N) : "memory");
}
__device__ __forceinline__ void bar() { asm volatile("s_barrier" ::: "memory"); }
__device__ __forceinline__ void lgkm0() {
  asm volatile("s_waitcnt lgkmcnt(0)" ::: "memory");
}

// ---------------- transpose (f32 [K][N] -> bf16 [Npad][K], zero-pad rows >= N)
__global__ void transpose_cvt(const float* __restrict__ W, bf16* __restrict__ WT,
                              int K, int N, int Npad) {
  __shared__ float tile[32][33];
  int k0 = blockIdx.x * 32, n0 = blockIdx.y * 32;
  int tx = threadIdx.x, ty = threadIdx.y;  // (32, 8)
#pragma unroll
  for (int j = 0; j < 4; j++) {
    int k = k0 + ty + 8 * j, n = n0 + tx;
    tile[ty + 8 * j][tx] = (k < K && n < N) ? W[(size_t)k * N + n] : 0.f;
  }
  __syncthreads();
#pragma unroll
  for (int j = 0; j < 4; j++) {
    int n = n0 + ty + 8 * j, k = k0 + tx;
    if (n < Npad && k < K) WT[(size_t)n * K + k] = (bf16)tile[tx][ty + 8 * j];
  }
}

// ---------------- layernorm (f32 in) -> xn bf16
__global__ __launch_bounds__(256) void ln_kernel(const float* __restrict__ x,
                                                 const float* __restrict__ lw,
                                                 const float* __restrict__ lb,
                                                 bf16* __restrict__ xn) {
  int row = blockIdx.x;
  int t = threadIdx.x;
  f32x4 v4 = ((const f32x4*)(x + (size_t)row * DM))[t];
  float v0 = v4[0], v1 = v4[1], v2 = v4[2], v3 = v4[3];
  float s = v0 + v1 + v2 + v3;
  float s2 = v0 * v0 + v1 * v1 + v2 * v2 + v3 * v3;
#pragma unroll
  for (int off = 32; off > 0; off >>= 1) {
    s += __shfl_down(s, off);
    s2 += __shfl_down(s2, off);
  }
  __shared__ float ps[8];
  int wave = t >> 6, lane = t & 63;
  if (lane == 0) { ps[wave] = s; ps[4 + wave] = s2; }
  __syncthreads();
  s = ps[0] + ps[1] + ps[2] + ps[3];
  s2 = ps[4] + ps[5] + ps[6] + ps[7];
  float mean = s * (1.f / DM);
  float var = s2 * (1.f / DM) - mean * mean;
  float rstd = rsqrtf(var + 1e-5f);
  f32x4 wv = ((const f32x4*)lw)[t];
  f32x4 bv = ((const f32x4*)lb)[t];
  bf16 o[4];
  o[0] = (bf16)((v0 - mean) * rstd * wv[0] + bv[0]);
  o[1] = (bf16)((v1 - mean) * rstd * wv[1] + bv[1]);
  o[2] = (bf16)((v2 - mean) * rstd * wv[2] + bv[2]);
  o[3] = (bf16)((v3 - mean) * rstd * wv[3] + bv[3]);
  bf16* dst = xn + (size_t)row * DM + t * 4;
  dst[0] = o[0]; dst[1] = o[1]; dst[2] = o[2]; dst[3] = o[3];
}

// ---------------- GEMM1: 256x256, BK=64, 8 waves, minimal-LDS 2-phase schedule.
// LDS: A half-slots [p][h] 4x16KB at 0..65536; B slots [p] 2x32KB at 65536. 128 KiB.
// ph0: read A-half0 (8 b128) + ALL B (16 b128, persists in regs); 32 MFMA.
// ph1: read A-half1 (8 b128); 32 MFMA.  24 ds_reads/K-tile = minimal.
__global__ __launch_bounds__(512, 2) void gemm1_8p(const bf16* __restrict__ A,
                                                   const bf16* __restrict__ BT,
                                                   bf16* __restrict__ C) {
  __shared__ char lds[131072];
  int bid = blockIdx.x;                       // 576 = 32 m-tiles * 18 n-tiles
  int swz = (bid & 7) * 72 + (bid >> 3);      // bijective XCD swizzle (576 % 8 == 0)
  int bm = swz / 18, bn = swz - (swz / 18) * 18;
  int m0 = bm * 256, n0 = bn * 256;
  int t = threadIdx.x, lane = t & 63, wave = t >> 6;
  int wm = wave >> 2, wn = wave & 3;
  int lr16 = lane & 15, kq = lane >> 4;
  int ts0 = kq ^ (lr16 & 7);
  int ts1 = (4 + kq) ^ (lr16 & 7);
  int sw = (lane & 7) ^ (lane >> 3);
  int l8 = lane >> 3;
  const char* Ab = (const char*)A;
  const char* Bb = (const char*)BT;

  // A half-slot staging: 2 gloads/wave; slot h holds rows {wm*128+h*64+[0,64)} as local [wm*64+q]
  auto stA = [&](int kt, int p, int h) {
    char* slot = lds + (p * 2 + h) * 16384;
    size_t ko = (size_t)kt * 128 + sw * 16;
#pragma unroll
    for (int g = 0; g < 2; g++) {
      int c = wave * 2 + g;
      int L = c * 8 + l8;
      int grow = m0 + ((L >> 6) << 7) + h * 64 + (L & 63);
      gload_lds16(Ab + (size_t)grow * 2048 + ko, slot + c * 1024);
    }
  };
  // B slot staging: 4 gloads/wave; 256 n-rows linear
  auto stB = [&](int kt, int p) {
    char* slot = lds + 65536 + p * 32768;
    size_t ko = (size_t)kt * 128 + sw * 16;
#pragma unroll
    for (int g = 0; g < 4; g++) {
      int c = wave * 4 + g;
      gload_lds16(Bb + (size_t)(n0 + c * 8 + l8) * 2048 + ko, slot + c * 1024);
    }
  };

  f32x4 acc[8][4] = {};
  bf16x8 b_[4][2];
  // prologue queue (oldest->newest): A(0,0)2, B(0)4, A(0,1)2 [drained], A(1,0)2, B(1)4 [in flight]
  stA(0, 0, 0); stB(0, 0); stA(0, 0, 1); stA(1, 1, 0); stB(1, 1);
  vm_wait<6>();
  bar();
#pragma unroll 1
  for (int kt = 0; kt < 16; kt++) {
    int p = kt & 1;
    // ---- ph0: A-half0 + B reads, MFMA mq=0
    {
      const char* sa_ = lds + (p * 2 + 0) * 16384;
      const char* sb_ = lds + 65536 + p * 32768;
      bf16x8 a_[4][2];
#pragma unroll
      for (int mi = 0; mi < 4; mi++) {
        int lrow = wm * 64 + mi * 16 + lr16;
        a_[mi][0] = *(const bf16x8*)(sa_ + lrow * 128 + ts0 * 16);
        a_[mi][1] = *(const bf16x8*)(sa_ + lrow * 128 + ts1 * 16);
      }
#pragma unroll
      for (int ni = 0; ni < 4; ni++) {
        int lrow = wn * 64 + ni * 16 + lr16;
        b_[ni][0] = *(const bf16x8*)(sb_ + lrow * 128 + ts0 * 16);
        b_[ni][1] = *(const bf16x8*)(sb_ + lrow * 128 + ts1 * 16);
      }
      if (kt < 15) stA(kt + 1, p ^ 1, 1);
      if (kt < 15) vm_wait<8>(); else vm_wait<0>();
      bar();
      lgkm0();
      __builtin_amdgcn_s_setprio(1);
#pragma unroll
      for (int mi = 0; mi < 4; mi++)
#pragma unroll
        for (int ni = 0; ni < 4; ni++) {
          acc[mi][ni] = __builtin_amdgcn_mfma_f32_16x16x32_bf16(a_[mi][0], b_[ni][0], acc[mi][ni], 0, 0, 0);
          acc[mi][ni] = __builtin_amdgcn_mfma_f32_16x16x32_bf16(a_[mi][1], b_[ni][1], acc[mi][ni], 0, 0, 0);
        }
      __builtin_amdgcn_s_setprio(0);
      bar();
    }
    // ---- ph1: A-half1 reads (B persists in regs), MFMA mq=1
    {
      const char* sa_ = lds + (p * 2 + 1) * 16384;
      bf16x8 a_[4][2];
#pragma unroll
      for (int mi = 0; mi < 4; mi++) {
        int lrow = wm * 64 + mi * 16 + lr16;
        a_[mi][0] = *(const bf16x8*)(sa_ + lrow * 128 + ts0 * 16);
        a_[mi][1] = *(const bf16x8*)(sa_ + lrow * 128 + ts1 * 16);
      }
      if (kt < 14) { stA(kt + 2, p, 0); stB(kt + 2, p); }
      if (kt < 14) vm_wait<8>(); else if (kt == 14) vm_wait<2>();
      bar();
      lgkm0();
      __builtin_amdgcn_s_setprio(1);
#pragma unroll
      for (int mi = 0; mi < 4; mi++)
#pragma unroll
        for (int ni = 0; ni < 4; ni++) {
          acc[4 + mi][ni] = __builtin_amdgcn_mfma_f32_16x16x32_bf16(a_[mi][0], b_[ni][0], acc[4 + mi][ni], 0, 0, 0);
          acc[4 + mi][ni] = __builtin_amdgcn_mfma_f32_16x16x32_bf16(a_[mi][1], b_[ni][1], acc[4 + mi][ni], 0, 0, 0);
        }
      __builtin_amdgcn_s_setprio(0);
      bar();
    }
  }
#pragma unroll
  for (int mq = 0; mq < 2; mq++)
#pragma unroll
    for (int mi = 0; mi < 4; mi++)
#pragma unroll
      for (int ni = 0; ni < 4; ni++) {
        int row = m0 + wm * 128 + mq * 64 + mi * 16 + kq * 4;
        int col = n0 + wn * 64 + ni * 16 + lr16;
        f32x4 v = acc[mq * 4 + mi][ni];
        if (col < 4384) {
#pragma unroll
          for (int r = 0; r < 4; r++)
            C[(size_t)(row + r) * DPROJ + col] = (bf16)v[r];
        }
      }
}

// ---------------- GEMM2: 256x128, BK=64, 8 waves, grid 256 (=1/CU), dual-barrier skeleton.
#define G2_PHASE(MQ, P, STAGE, VMW)                                                        \
  {                                                                                        \
    const char* sa_ = lds + ((P) * 2 + (MQ)) * 16384;                                      \
    const char* sb_ = lds + 65536 + (P) * 16384;                                           \
    bf16x8 a_[4][2], b_[2][2];                                                             \
    _Pragma("unroll") for (int mi = 0; mi < 4; mi++) {                                     \
      int lrow = wm * 64 + mi * 16 + lr16;                                                 \
      a_[mi][0] = *(const bf16x8*)(sa_ + lrow * 128 + ts0 * 16);                           \
      a_[mi][1] = *(const bf16x8*)(sa_ + lrow * 128 + ts1 * 16);                           \
    }                                                                                      \
    _Pragma("unroll") for (int ni = 0; ni < 2; ni++) {                                     \
      int lrow = wn * 32 + ni * 16 + lr16;                                                 \
      b_[ni][0] = *(const bf16x8*)(sb_ + lrow * 128 + ts0 * 16);                           \
      b_[ni][1] = *(const bf16x8*)(sb_ + lrow * 128 + ts1 * 16);                           \
    }                                                                                      \
    STAGE;                                                                                 \
    VMW;                                                                                   \
    bar();                                                                                 \
    lgkm0();                                                                               \
    __builtin_amdgcn_s_setprio(1);                                                         \
    _Pragma("unroll") for (int mi = 0; mi < 4; mi++)                                       \
      _Pragma("unroll") for (int ni = 0; ni < 2; ni++) {                                   \
        acc[(MQ) * 4 + mi][ni] = __builtin_amdgcn_mfma_f32_16x16x32_bf16(                  \
            a_[mi][0], b_[ni][0], acc[(MQ) * 4 + mi][ni], 0, 0, 0);                        \
        acc[(MQ) * 4 + mi][ni] = __builtin_amdgcn_mfma_f32_16x16x32_bf16(                  \
            a_[mi][1], b_[ni][1], acc[(MQ) * 4 + mi][ni], 0, 0, 0);                        \
      }                                                                                    \
    __builtin_amdgcn_s_setprio(0);                                                         \
    bar();                                                                                 \
  }

__global__ __launch_bounds__(512, 2) void gemm2_8p(const bf16* __restrict__ A,
                                                   const bf16* __restrict__ BT,
                                                   float* __restrict__ C,
                                                   const float* __restrict__ Xres) {
  __shared__ char lds[98304];
  int bid = blockIdx.x;                  // 256 = 32 m * 8 n
  int swz = (bid & 7) * 32 + (bid >> 3); // bijective (256 % 8 == 0)
  int bm = swz >> 3, bn = swz & 7;
  int m0 = bm * 256, n0 = bn * 128;
  int t = threadIdx.x, lane = t & 63, wave = t >> 6;
  int wm = wave >> 2, wn = wave & 3;
  int lr16 = lane & 15, kq = lane >> 4;
  int ts0 = kq ^ (lr16 & 7);
  int ts1 = (4 + kq) ^ (lr16 & 7);
  int sw = (lane & 7) ^ ((lane >> 3) & 7);
  int l8 = lane >> 3;
  int c0 = 2 * wave, c1 = 2 * wave + 1;
  int lr0 = c0 * 8 + l8, lr1 = c1 * 8 + l8;
  const char* Ab = (const char*)A;
  const char* Bb = (const char*)BT;
  int grA0 = m0 + (lr0 >> 6) * 128 + (lr0 & 63);
  int grA1 = m0 + (lr1 >> 6) * 128 + (lr1 & 63);
  int gcB0 = n0 + lr0, gcB1 = n0 + lr1;  // lr in [0,128)

  auto stA = [&](int kt, int p, int mq) {
    char* slot = lds + (p * 2 + mq) * 16384;
    size_t ko = (size_t)kt * 128 + sw * 16;
    gload_lds16(Ab + (size_t)(grA0 + mq * 64) * 4096 + ko, slot + c0 * 1024);
    gload_lds16(Ab + (size_t)(grA1 + mq * 64) * 4096 + ko, slot + c1 * 1024);
  };
  auto stB = [&](int kt, int p) {
    char* slot = lds + 65536 + p * 16384;
    size_t ko = (size_t)kt * 128 + sw * 16;
    gload_lds16(Bb + (size_t)gcB0 * 4096 + ko, slot + c0 * 1024);
    gload_lds16(Bb + (size_t)gcB1 * 4096 + ko, slot + c1 * 1024);
  };

  f32x4 acc[8][2] = {};
  stA(0, 0, 0); stB(0, 0); stA(0, 0, 1); stA(1, 1, 0);
  vm_wait<4>();
  bar();
#pragma unroll 1
  for (int kt = 0; kt < 32; kt++) {
    int p = kt & 1;
    G2_PHASE(0, p, { if (kt + 1 < 32) { stB(kt + 1, p ^ 1); stA(kt + 1, p ^ 1, 1); } },
             { if (kt < 31) vm_wait<6>(); else vm_wait<0>(); });
    G2_PHASE(1, p, { if (kt + 2 < 32) stA(kt + 2, p, 0); },
             { if (kt < 30) vm_wait<4>(); else if (kt == 30) vm_wait<2>(); });
  }
#pragma unroll
  for (int mq = 0; mq < 2; mq++)
#pragma unroll
    for (int mi = 0; mi < 4; mi++)
#pragma unroll
      for (int ni = 0; ni < 2; ni++) {
        int row = m0 + wm * 128 + mq * 64 + mi * 16 + kq * 4;
        int col = n0 + wn * 32 + ni * 16 + lr16;
        f32x4 v = acc[mq * 4 + mi][ni];
#pragma unroll
        for (int r = 0; r < 4; r++) {
          size_t o = (size_t)(row + r) * DM + col;
          C[o] = Xres[o] + v[r];
        }
      }
}

// ---------------- conv: one thread per 8-channel vector per row
__global__ __launch_bounds__(256) void conv_prep3(const bf16* __restrict__ u,
                                                  const float* __restrict__ cw,
                                                  const float* __restrict__ cb,
                                                  const float* __restrict__ dt_bias,
                                                  bf16* __restrict__ xs,
                                                  float* __restrict__ BC,
                                                  float* __restrict__ dtf) {
  const int JPR = 292;  // 260 conv vec8 + 32 dt vec8
  int idx = blockIdx.x * 256 + threadIdx.x;
  if (idx >= MROWS * JPR) return;
  int row = idx / JPR;
  int j = idx - row * JPR;
  int t = row & (SEQ - 1);
  if (j < 260) {
    int c0 = j * 8;
    float acc[8];
#pragma unroll
    for (int i = 0; i < 8; i++) acc[i] = cb[c0 + i];
    const bf16* ub = u + (size_t)row * DPROJ + DIN + c0;
#pragma unroll
    for (int tap = 0; tap < 4; tap++) {
      int tt = t - 3 + tap;
      if (tt >= 0) {
        bf16x8 uv = *(const bf16x8*)(ub + (ptrdiff_t)(tap - 3) * DPROJ);
        const float* wv = cw + tap * CONVD + c0;
#pragma unroll
        for (int i = 0; i < 8; i++) acc[i] += wv[i] * (float)uv[i];
      }
    }
    if (c0 < DIN) {
      bf16x8 o;
#pragma unroll
      for (int i = 0; i < 8; i++) {
        float sv = acc[i] / (1.f + __expf(-acc[i]));
        o[i] = (bf16)sv;
      }
      *(bf16x8*)(xs + (size_t)row * DIN + c0) = o;
    } else {
      float* bc = BC + (size_t)row * 32 + (c0 - DIN);
#pragma unroll
      for (int i = 0; i < 8; i++) bc[i] = acc[i] / (1.f + __expf(-acc[i]));
    }
  } else {
    int h0 = (j - 260) * 8;
    bf16x8 uv = *(const bf16x8*)(u + (size_t)row * DPROJ + (DPROJ - NH) + h0);
    float* dst = dtf + (size_t)row * NH + h0;
#pragma unroll
    for (int i = 0; i < 8; i++) {
      float xv = (float)uv[i] + dt_bias[h0 + i];
      dst[i] = (xv > 20.f) ? xv : log1pf(__expf(xv));
    }
  }
}

// ---------------- chunked scan, phase 1: local scan from zero -> (S, P) in u's dead tail
__global__ __launch_bounds__(64) void scan_p1(const bf16* __restrict__ xs,
                                              const float* __restrict__ BC,
                                              const float* __restrict__ dtf,
                                              const float* __restrict__ A_log,
                                              bf16* __restrict__ uscr) {
  int c = blockIdx.x & 63, hg = (blockIdx.x >> 6) & 31, b = blockIdx.x >> 11;
  int lane = threadIdx.x, hh = lane >> 3;
  int h = hg * 8 + hh;
  float A = -__expf(A_log[h]);
  float st[16];
#pragma unroll
  for (int n = 0; n < 16; n++) st[n] = 0.f;
  float pcum = 1.f;
  size_t rb = (size_t)b * SEQ + (size_t)c * LC;
  for (int t = 0; t < LC; t++) {
    size_t row = rb + t;
    const float* bcrow = BC + row * 32;
    float dtv = dtf[row * NH + h];
    float x = (float)xs[row * DIN + hg * 64 + lane];
    float dA = __expf(dtv * A);
    pcum *= dA;
    float w = dtv * x;
#pragma unroll
    for (int n = 0; n < 16; n++) st[n] = st[n] * dA + w * bcrow[n];
  }
  char* slot = (char*)uscr + (size_t)blockIdx.x * UROWB + 4096;
  float* S = (float*)slot;
#pragma unroll
  for (int n = 0; n < 16; n++) S[lane * 16 + n] = st[n];
  if ((lane & 7) == 0) ((float*)(slot + 4096))[hh] = pcum;
}

// ---------------- phase 2: sequential combine over chunks (prefetched); S <- incoming H
__global__ __launch_bounds__(64) void scan_p2(bf16* __restrict__ uscr) {
  int bh = blockIdx.x;  // 0..127 = b*32+hg
  int lane = threadIdx.x, hh = lane >> 3;
  float H[16];
#pragma unroll
  for (int n = 0; n < 16; n++) H[n] = 0.f;
  char* base = (char*)uscr + (size_t)bh * NC * UROWB + 4096;
  float sN[16], PN;
  {
    float* S = (float*)base;
#pragma unroll
    for (int n = 0; n < 16; n++) sN[n] = S[lane * 16 + n];
    PN = ((const float*)(base + 4096))[hh];
  }
  for (int c = 0; c < NC; c++) {
    float sC[16], PC = PN;
#pragma unroll
    for (int n = 0; n < 16; n++) sC[n] = sN[n];
    if (c + 1 < NC) {
      char* slot = base + (size_t)(c + 1) * UROWB;
      float* S = (float*)slot;
#pragma unroll
      for (int n = 0; n < 16; n++) sN[n] = S[lane * 16 + n];
      PN = ((const float*)(slot + 4096))[hh];
    }
    float* S0 = (float*)(base + (size_t)c * UROWB);
#pragma unroll
    for (int n = 0; n < 16; n++) {
      float hn = H[n];
      S0[lane * 16 + n] = hn;
      H[n] = PC * hn + sC[n];
    }
  }
}

// ---------------- phase 3: re-scan each chunk from true incoming state, emit y
__global__ __launch_bounds__(64) void scan_p3(const bf16* __restrict__ xs,
                                              const float* __restrict__ BC,
                                              const float* __restrict__ dtf,
                                              const float* __restrict__ A_log,
                                              const float* __restrict__ Dp,
                                              const bf16* __restrict__ uscr,
                                              bf16* __restrict__ y) {
  int c = blockIdx.x & 63, hg = (blockIdx.x >> 6) & 31, b = blockIdx.x >> 11;
  int lane = threadIdx.x, hh = lane >> 3;
  int h = hg * 8 + hh;
  float A = -__expf(A_log[h]);
  float D = Dp[h];
  const char* slot = (const char*)uscr + (size_t)blockIdx.x * UROWB + 4096;
  float st[16];
#pragma unroll
  for (int n = 0; n < 16; n++) st[n] = ((const float*)slot)[lane * 16 + n];
  size_t rb = (size_t)b * SEQ + (size_t)c * LC;
  for (int t = 0; t < LC; t++) {
    size_t row = rb + t;
    const float* bcrow = BC + row * 32;
    float dtv = dtf[row * NH + h];
    float x = (float)xs[row * DIN + hg * 64 + lane];
    float dA = __expf(dtv * A);
    float w = dtv * x;
    float yv = 0.f;
#pragma unroll
    for (int n = 0; n < 16; n++) {
      st[n] = st[n] * dA + w * bcrow[n];
      yv += st[n] * bcrow[16 + n];
    }
    y[row * DIN + hg * 64 + lane] = (bf16)(yv + D * x);
  }
}

// ---------------- gating + rmsnorm -> g bf16
__global__ __launch_bounds__(256) void gate_rms(const bf16* __restrict__ u,
                                                const bf16* __restrict__ y,
                                                const float* __restrict__ rms_w,
                                                bf16* __restrict__ g) {
  int row = blockIdx.x;
  int t = threadIdx.x;
  bf16x8 zv = ((const bf16x8*)(u + (size_t)row * DPROJ))[t];
  bf16x8 yv = ((const bf16x8*)(y + (size_t)row * DIN))[t];
  float gv[8];
  float s2 = 0.f;
#pragma unroll
  for (int i = 0; i < 8; i++) {
    float z = (float)zv[i];
    float yy = (float)yv[i];
    float gg = yy * z / (1.f + __expf(-z));
    gv[i] = gg;
    s2 += gg * gg;
  }
#pragma unroll
  for (int off = 32; off > 0; off >>= 1) s2 += __shfl_down(s2, off);
  __shared__ float ps[4];
  int wave = t >> 6, lane = t & 63;
  if (lane == 0) ps[wave] = s2;
  __syncthreads();
  s2 = ps[0] + ps[1] + ps[2] + ps[3];
  float scale = rsqrtf(s2 * (1.f / DIN) + 1e-5f);
  f32x4 w0 = ((const f32x4*)rms_w)[2 * t];
  f32x4 w1 = ((const f32x4*)rms_w)[2 * t + 1];
  bf16x8 og;
#pragma unroll
  for (int i = 0; i < 4; i++) og[i] = (bf16)(gv[i] * scale * w0[i]);
#pragma unroll
  for (int i = 0; i < 4; i++) og[4 + i] = (bf16)(gv[4 + i] * scale * w1[i]);
  ((bf16x8*)(g + (size_t)row * DIN))[t] = og;
}

extern "C" void kernel_launch(void* const* d_in, const int* in_sizes, int n_in,
                              void* d_out, int out_size, void* d_ws, size_t ws_size,
                              hipStream_t stream) {
  const float* x = (const float*)d_in[0];
  const float* lnw = (const float*)d_in[1];
  const float* lnb = (const float*)d_in[2];
  const float* Win = (const float*)d_in[3];
  const float* cw = (const float*)d_in[4];
  const float* cb = (const float*)d_in[5];
  const float* Alog = (const float*)d_in[6];
  const float* Dpv = (const float*)d_in[7];
  const float* dtb = (const float*)d_in[8];
  const float* rmsw = (const float*)d_in[9];
  const float* Wout = (const float*)d_in[10];
  float* out = (float*)d_out;

  char* ws = (char*)d_ws;
  bf16* u = (bf16*)(ws + 0);                     // [8192][4384] bf16
  bf16* xnb = (bf16*)(ws + 71827456);            // [8192][1024] bf16 (dead after GEMM1)
  bf16* WinT = (bf16*)(ws + 88604672);           // [4608][1024] bf16 (dead after GEMM1)
  bf16* yb = (bf16*)(ws + 71827456);             // [8192][2048] bf16 (reuses xnb+WinT)
  bf16* xsb = (bf16*)(ws + 105381888);           // [8192][2048] bf16 (dead after scan)
  bf16* gb = (bf16*)(ws + 105381888);            // reuses xsb
  float* BC = (float*)(ws + 138936320);          // [8192][32] f32
  float* dtf = (float*)(ws + 139984896);         // [8192][256] f32
  bf16* WoutT = (bf16*)(ws + 148373504);         // [1024][2048] bf16

  transpose_cvt<<<dim3(32, 144), dim3(32, 8), 0, stream>>>(Win, WinT, 1024, DPROJ, NPAD1);
  transpose_cvt<<<dim3(64, 32), dim3(32, 8), 0, stream>>>(Wout, WoutT, DIN, DM, DM);
  ln_kernel<<<MROWS, 256, 0, stream>>>(x, lnw, lnb, xnb);
  gemm1_8p<<<576, 512, 0, stream>>>(xnb, WinT, u);
  conv_prep3<<<(MROWS * 292) / 256, 256, 0, stream>>>(u, cw, cb, dtb, xsb, BC, dtf);
  scan_p1<<<MROWS, 64, 0, stream>>>(xsb, BC, dtf, Alog, u);
  scan_p2<<<128, 64, 0, stream>>>(u);
  scan_p3<<<MROWS, 64, 0, stream>>>(xsb, BC, dtf, Alog, Dpv, u, yb);
  gate_rms<<<MROWS, 256, 0, stream>>>(u, yb, rmsw, gb);
  gemm2_8p<<<256, 512, 0, stream>>>(gb, WoutT, out, x);
}

// Round 9
// 303.405 us; speedup vs baseline: 1.2635x; 1.0269x over previous
//
#include <hip/hip_runtime.h>

typedef __bf16 bf16;
typedef __attribute__((ext_vector_type(8))) __bf16 bf16x8;
typedef __attribute__((ext_vector_type(4))) float f32x4;

#define B_SZ 4
#define SEQ 2048
#define DM 1024
#define DIN 2048
#define NH 256
#define DSTATE 16
#define CONVD 2080
#define DPROJ 4384
#define NPAD1 4608
#define MROWS 8192
#define NC 64
#define LC 32
#define UROWB 8768  // u row stride in bytes (4384 * 2)

__device__ __forceinline__ void gload_lds16(const void* g, void* l) {
  __builtin_amdgcn_global_load_lds(
      (__attribute__((address_space(1))) void*)g,
      (__attribute__((address_space(3))) void*)l, 16, 0, 0);
}

template <int N>
__device__ __forceinline__ void vm_wait() {
  asm volatile("s_waitcnt vmcnt(%0)" ::"n"(N) : "memory");
}
__device__ __forceinline__ void bar() { asm volatile("s_barrier" ::: "memory"); }
__device__ __forceinline__ void lgkm0() {
  asm volatile("s_waitcnt lgkmcnt(0)" ::: "memory");
}

// ---------------- transpose (f32 [K][N] -> bf16 [Npad][K], zero-pad rows >= N)
__global__ void transpose_cvt(const float* __restrict__ W, bf16* __restrict__ WT,
                              int K, int N, int Npad) {
  __shared__ float tile[32][33];
  int k0 = blockIdx.x * 32, n0 = blockIdx.y * 32;
  int tx = threadIdx.x, ty = threadIdx.y;  // (32, 8)
#pragma unroll
  for (int j = 0; j < 4; j++) {
    int k = k0 + ty + 8 * j, n = n0 + tx;
    tile[ty + 8 * j][tx] = (k < K && n < N) ? W[(size_t)k * N + n] : 0.f;
  }
  __syncthreads();
#pragma unroll
  for (int j = 0; j < 4; j++) {
    int n = n0 + ty + 8 * j, k = k0 + tx;
    if (n < Npad && k < K) WT[(size_t)n * K + k] = (bf16)tile[tx][ty + 8 * j];
  }
}

// ---------------- layernorm (f32 in) -> xn bf16
__global__ __launch_bounds__(256) void ln_kernel(const float* __restrict__ x,
                                                 const float* __restrict__ lw,
                                                 const float* __restrict__ lb,
                                                 bf16* __restrict__ xn) {
  int row = blockIdx.x;
  int t = threadIdx.x;
  f32x4 v4 = ((const f32x4*)(x + (size_t)row * DM))[t];
  float v0 = v4[0], v1 = v4[1], v2 = v4[2], v3 = v4[3];
  float s = v0 + v1 + v2 + v3;
  float s2 = v0 * v0 + v1 * v1 + v2 * v2 + v3 * v3;
#pragma unroll
  for (int off = 32; off > 0; off >>= 1) {
    s += __shfl_down(s, off);
    s2 += __shfl_down(s2, off);
  }
  __shared__ float ps[8];
  int wave = t >> 6, lane = t & 63;
  if (lane == 0) { ps[wave] = s; ps[4 + wave] = s2; }
  __syncthreads();
  s = ps[0] + ps[1] + ps[2] + ps[3];
  s2 = ps[4] + ps[5] + ps[6] + ps[7];
  float mean = s * (1.f / DM);
  float var = s2 * (1.f / DM) - mean * mean;
  float rstd = rsqrtf(var + 1e-5f);
  f32x4 wv = ((const f32x4*)lw)[t];
  f32x4 bv = ((const f32x4*)lb)[t];
  bf16 o[4];
  o[0] = (bf16)((v0 - mean) * rstd * wv[0] + bv[0]);
  o[1] = (bf16)((v1 - mean) * rstd * wv[1] + bv[1]);
  o[2] = (bf16)((v2 - mean) * rstd * wv[2] + bv[2]);
  o[3] = (bf16)((v3 - mean) * rstd * wv[3] + bv[3]);
  bf16* dst = xn + (size_t)row * DM + t * 4;
  dst[0] = o[0]; dst[1] = o[1]; dst[2] = o[2]; dst[3] = o[3];
}

// ---------------- GEMM1: 256x256, BK=64, 8 waves (2Mx4N), 8-phase schedule.
// LDS: A[buf][half] 4x16KB at 0..65536; B[buf][half] 4x16KB at 65536..131072.
// Stage->phase map (race-audited): ph1/2: A bf1(o); ph3/4: B bf0(e+2);
// ph5/6: A bf0(e+2); ph7/8: B bf1(o+2). Waits: vmcnt(4) at ph4 & ph8 only.
#define G1PH(RDA, AARR, RDB, BARR, MQ, NQ, P, STAGE, WAIT)                                 \
  {                                                                                        \
    const char* sa_ = lds + (P) * 32768 + wm * 16384;                                      \
    const char* sb_ = lds + 65536 + (P) * 32768 + (wn >> 1) * 16384;                       \
    if (RDA) {                                                                             \
      _Pragma("unroll") for (int mi = 0; mi < 4; mi++) {                                   \
        int lrow = ((MQ) * 4 + mi) * 16 + lr16;                                            \
        AARR[mi][0] = *(const bf16x8*)(sa_ + lrow * 128 + ts0 * 16);                       \
        AARR[mi][1] = *(const bf16x8*)(sa_ + lrow * 128 + ts1 * 16);                       \
      }                                                                                    \
    }                                                                                      \
    if (RDB) {                                                                             \
      _Pragma("unroll") for (int ni = 0; ni < 2; ni++) {                                   \
        int lrow = (wn & 1) * 64 + ((NQ) * 2 + ni) * 16 + lr16;                            \
        BARR[ni][0] = *(const bf16x8*)(sb_ + lrow * 128 + ts0 * 16);                       \
        BARR[ni][1] = *(const bf16x8*)(sb_ + lrow * 128 + ts1 * 16);                       \
      }                                                                                    \
    }                                                                                      \
    STAGE;                                                                                 \
    WAIT;                                                                                  \
    bar();                                                                                 \
    lgkm0();                                                                               \
    __builtin_amdgcn_s_setprio(1);                                                         \
    _Pragma("unroll") for (int mi = 0; mi < 4; mi++)                                       \
      _Pragma("unroll") for (int ni = 0; ni < 2; ni++) {                                   \
        acc[(MQ) * 4 + mi][(NQ) * 2 + ni] = __builtin_amdgcn_mfma_f32_16x16x32_bf16(       \
            AARR[mi][0], BARR[ni][0], acc[(MQ) * 4 + mi][(NQ) * 2 + ni], 0, 0, 0);         \
        acc[(MQ) * 4 + mi][(NQ) * 2 + ni] = __builtin_amdgcn_mfma_f32_16x16x32_bf16(       \
            AARR[mi][1], BARR[ni][1], acc[(MQ) * 4 + mi][(NQ) * 2 + ni], 0, 0, 0);         \
      }                                                                                    \
    __builtin_amdgcn_s_setprio(0);                                                         \
    bar();                                                                                 \
  }

__global__ __launch_bounds__(512, 2) void gemm1_8p(const bf16* __restrict__ A,
                                                   const bf16* __restrict__ BT,
                                                   bf16* __restrict__ C) {
  __shared__ char lds[131072];
  int bid = blockIdx.x;                       // 576 = 32 m-tiles * 18 n-tiles
  int swz = (bid & 7) * 72 + (bid >> 3);      // bijective XCD swizzle (576 % 8 == 0)
  int bm = swz / 18, bn = swz - (swz / 18) * 18;
  int m0 = bm * 256, n0 = bn * 256;
  int t = threadIdx.x, lane = t & 63, wave = t >> 6;
  int wm = wave >> 2, wn = wave & 3;
  int lr16 = lane & 15, kq = lane >> 4;
  int ts0 = kq ^ (lr16 & 7);
  int ts1 = (4 + kq) ^ (lr16 & 7);
  int sw = (lane & 7) ^ (lane >> 3);
  int l8 = lane >> 3;
  const char* Ab = (const char*)A;
  const char* Bb = (const char*)BT;

  // stage A-half h of K-tile kt into buf p (2 gloads/thread = 16 KB halftile)
  auto stA = [&](int kt, int p, int h) {
    char* slot = lds + p * 32768 + h * 16384;
    size_t ko = (size_t)kt * 128 + sw * 16;
#pragma unroll
    for (int g = 0; g < 2; g++) {
      int c = wave * 2 + g;
      gload_lds16(Ab + (size_t)(m0 + h * 128 + c * 8 + l8) * 2048 + ko, slot + c * 1024);
    }
  };
  auto stB = [&](int kt, int p, int h) {
    char* slot = lds + 65536 + p * 32768 + h * 16384;
    size_t ko = (size_t)kt * 128 + sw * 16;
#pragma unroll
    for (int g = 0; g < 2; g++) {
      int c = wave * 2 + g;
      gload_lds16(Bb + (size_t)(n0 + h * 128 + c * 8 + l8) * 2048 + ko, slot + c * 1024);
    }
  };

  f32x4 acc[8][4] = {};
  bf16x8 aL[4][2], aH[4][2], b01[2][2], b23[2][2];

  // prologue: all of bf0(kt0), then B bf1(kt1); allow B-bf1 (4 instr) in flight
  stA(0, 0, 0); stA(0, 0, 1); stB(0, 0, 0); stB(0, 0, 1);
  stB(1, 1, 0); stB(1, 1, 1);
  vm_wait<4>();
  bar();
#pragma unroll 1
  for (int it = 0; it < 8; ++it) {
    int e2 = 2 * it + 2, o1 = 2 * it + 1, o3 = 2 * it + 3;
    bool st = it < 7;
    // ph1: Q(0,0) bf0; reads aL+b01; stage A_h0 bf1(o1)  [slot freed prev ph7]
    G1PH(1, aL, 1, b01, 0, 0, 0, { stA(o1, 1, 0); }, {});
    // ph2: Q(0,1) bf0; reads b23; stage A_h1 bf1(o1)
    G1PH(0, aL, 1, b23, 0, 1, 0, { stA(o1, 1, 1); }, {});
    // ph3: Q(1,0) bf0; reads aH; stage B_h0 bf0(e2)  [B bf0 freed ph2]
    G1PH(1, aH, 0, b01, 1, 0, 0, { if (st) stB(e2, 0, 0); }, {});
    // ph4: Q(1,1) bf0; no reads; stage B_h1 bf0(e2); WAIT -> protects ph5 bf1(o1) reads
    G1PH(0, aH, 0, b23, 1, 1, 0, { if (st) stB(e2, 0, 1); },
         { if (st) vm_wait<4>(); else vm_wait<0>(); });
    // ph5: Q(0,0) bf1; reads aL+b01; stage A_h0 bf0(e2)  [A bf0 freed ph3]
    G1PH(1, aL, 1, b01, 0, 0, 1, { if (st) stA(e2, 0, 0); }, {});
    // ph6: Q(0,1) bf1; reads b23; stage A_h1 bf0(e2)
    G1PH(0, aL, 1, b23, 0, 1, 1, { if (st) stA(e2, 0, 1); }, {});
    // ph7: Q(1,0) bf1; reads aH; stage B_h0 bf1(o3)  [B bf1 freed ph6]
    G1PH(1, aH, 0, b01, 1, 0, 1, { if (st) stB(o3, 1, 0); }, {});
    // ph8: Q(1,1) bf1; no reads; stage B_h1 bf1(o3); WAIT -> protects next ph1 bf0(e2) reads
    G1PH(0, aH, 0, b23, 1, 1, 1, { if (st) stB(o3, 1, 1); },
         { if (st) vm_wait<4>(); });
  }
#pragma unroll
  for (int mq = 0; mq < 2; mq++)
#pragma unroll
    for (int mi = 0; mi < 4; mi++)
#pragma unroll
      for (int ni = 0; ni < 4; ni++) {
        int row = m0 + wm * 128 + (mq * 4 + mi) * 16 + kq * 4;
        int col = n0 + wn * 64 + ni * 16 + lr16;
        f32x4 v = acc[mq * 4 + mi][ni];
        if (col < 4384) {
#pragma unroll
          for (int r = 0; r < 4; r++)
            C[(size_t)(row + r) * DPROJ + col] = (bf16)v[r];
        }
      }
}

// ---------------- GEMM2: 256x128, BK=64, 8 waves, grid 256 (=1/CU), dual-barrier skeleton.
#define G2_PHASE(MQ, P, STAGE, VMW)                                                        \
  {                                                                                        \
    const char* sa_ = lds + ((P) * 2 + (MQ)) * 16384;                                      \
    const char* sb_ = lds + 65536 + (P) * 16384;                                           \
    bf16x8 a_[4][2], b_[2][2];                                                             \
    _Pragma("unroll") for (int mi = 0; mi < 4; mi++) {                                     \
      int lrow = wm * 64 + mi * 16 + lr16;                                                 \
      a_[mi][0] = *(const bf16x8*)(sa_ + lrow * 128 + ts0 * 16);                           \
      a_[mi][1] = *(const bf16x8*)(sa_ + lrow * 128 + ts1 * 16);                           \
    }                                                                                      \
    _Pragma("unroll") for (int ni = 0; ni < 2; ni++) {                                     \
      int lrow = wn * 32 + ni * 16 + lr16;                                                 \
      b_[ni][0] = *(const bf16x8*)(sb_ + lrow * 128 + ts0 * 16);                           \
      b_[ni][1] = *(const bf16x8*)(sb_ + lrow * 128 + ts1 * 16);                           \
    }                                                                                      \
    STAGE;                                                                                 \
    VMW;                                                                                   \
    bar();                                                                                 \
    lgkm0();                                                                               \
    __builtin_amdgcn_s_setprio(1);                                                         \
    _Pragma("unroll") for (int mi = 0; mi < 4; mi++)                                       \
      _Pragma("unroll") for (int ni = 0; ni < 2; ni++) {                                   \
        acc[(MQ) * 4 + mi][ni] = __builtin_amdgcn_mfma_f32_16x16x32_bf16(                  \
            a_[mi][0], b_[ni][0], acc[(MQ) * 4 + mi][ni], 0, 0, 0);                        \
        acc[(MQ) * 4 + mi][ni] = __builtin_amdgcn_mfma_f32_16x16x32_bf16(                  \
            a_[mi][1], b_[ni][1], acc[(MQ) * 4 + mi][ni], 0, 0, 0);                        \
      }                                                                                    \
    __builtin_amdgcn_s_setprio(0);                                                         \
    bar();                                                                                 \
  }

__global__ __launch_bounds__(512, 2) void gemm2_8p(const bf16* __restrict__ A,
                                                   const bf16* __restrict__ BT,
                                                   float* __restrict__ C,
                                                   const float* __restrict__ Xres) {
  __shared__ char lds[98304];
  int bid = blockIdx.x;                  // 256 = 32 m * 8 n
  int swz = (bid & 7) * 32 + (bid >> 3); // bijective (256 % 8 == 0)
  int bm = swz >> 3, bn = swz & 7;
  int m0 = bm * 256, n0 = bn * 128;
  int t = threadIdx.x, lane = t & 63, wave = t >> 6;
  int wm = wave >> 2, wn = wave & 3;
  int lr16 = lane & 15, kq = lane >> 4;
  int ts0 = kq ^ (lr16 & 7);
  int ts1 = (4 + kq) ^ (lr16 & 7);
  int sw = (lane & 7) ^ ((lane >> 3) & 7);
  int l8 = lane >> 3;
  int c0 = 2 * wave, c1 = 2 * wave + 1;
  int lr0 = c0 * 8 + l8, lr1 = c1 * 8 + l8;
  const char* Ab = (const char*)A;
  const char* Bb = (const char*)BT;
  int grA0 = m0 + (lr0 >> 6) * 128 + (lr0 & 63);
  int grA1 = m0 + (lr1 >> 6) * 128 + (lr1 & 63);
  int gcB0 = n0 + lr0, gcB1 = n0 + lr1;  // lr in [0,128)

  auto stA = [&](int kt, int p, int mq) {
    char* slot = lds + (p * 2 + mq) * 16384;
    size_t ko = (size_t)kt * 128 + sw * 16;
    gload_lds16(Ab + (size_t)(grA0 + mq * 64) * 4096 + ko, slot + c0 * 1024);
    gload_lds16(Ab + (size_t)(grA1 + mq * 64) * 4096 + ko, slot + c1 * 1024);
  };
  auto stB = [&](int kt, int p) {
    char* slot = lds + 65536 + p * 16384;
    size_t ko = (size_t)kt * 128 + sw * 16;
    gload_lds16(Bb + (size_t)gcB0 * 4096 + ko, slot + c0 * 1024);
    gload_lds16(Bb + (size_t)gcB1 * 4096 + ko, slot + c1 * 1024);
  };

  f32x4 acc[8][2] = {};
  stA(0, 0, 0); stB(0, 0); stA(0, 0, 1); stA(1, 1, 0);
  vm_wait<4>();
  bar();
#pragma unroll 1
  for (int kt = 0; kt < 32; kt++) {
    int p = kt & 1;
    G2_PHASE(0, p, { if (kt + 1 < 32) { stB(kt + 1, p ^ 1); stA(kt + 1, p ^ 1, 1); } },
             { if (kt < 31) vm_wait<6>(); else vm_wait<0>(); });
    G2_PHASE(1, p, { if (kt + 2 < 32) stA(kt + 2, p, 0); },
             { if (kt < 30) vm_wait<4>(); else if (kt == 30) vm_wait<2>(); });
  }
#pragma unroll
  for (int mq = 0; mq < 2; mq++)
#pragma unroll
    for (int mi = 0; mi < 4; mi++)
#pragma unroll
      for (int ni = 0; ni < 2; ni++) {
        int row = m0 + wm * 128 + mq * 64 + mi * 16 + kq * 4;
        int col = n0 + wn * 32 + ni * 16 + lr16;
        f32x4 v = acc[mq * 4 + mi][ni];
#pragma unroll
        for (int r = 0; r < 4; r++) {
          size_t o = (size_t)(row + r) * DM + col;
          C[o] = Xres[o] + v[r];
        }
      }
}

// ---------------- conv: one thread per 8-channel vector per row
__global__ __launch_bounds__(256) void conv_prep3(const bf16* __restrict__ u,
                                                  const float* __restrict__ cw,
                                                  const float* __restrict__ cb,
                                                  const float* __restrict__ dt_bias,
                                                  bf16* __restrict__ xs,
                                                  float* __restrict__ BC,
                                                  float* __restrict__ dtf) {
  const int JPR = 292;  // 260 conv vec8 + 32 dt vec8
  int idx = blockIdx.x * 256 + threadIdx.x;
  if (idx >= MROWS * JPR) return;
  int row = idx / JPR;
  int j = idx - row * JPR;
  int t = row & (SEQ - 1);
  if (j < 260) {
    int c0 = j * 8;
    float acc[8];
#pragma unroll
    for (int i = 0; i < 8; i++) acc[i] = cb[c0 + i];
    const bf16* ub = u + (size_t)row * DPROJ + DIN + c0;
#pragma unroll
    for (int tap = 0; tap < 4; tap++) {
      int tt = t - 3 + tap;
      if (tt >= 0) {
        bf16x8 uv = *(const bf16x8*)(ub + (ptrdiff_t)(tap - 3) * DPROJ);
        const float* wv = cw + tap * CONVD + c0;
#pragma unroll
        for (int i = 0; i < 8; i++) acc[i] += wv[i] * (float)uv[i];
      }
    }
    if (c0 < DIN) {
      bf16x8 o;
#pragma unroll
      for (int i = 0; i < 8; i++) {
        float sv = acc[i] / (1.f + __expf(-acc[i]));
        o[i] = (bf16)sv;
      }
      *(bf16x8*)(xs + (size_t)row * DIN + c0) = o;
    } else {
      float* bc = BC + (size_t)row * 32 + (c0 - DIN);
#pragma unroll
      for (int i = 0; i < 8; i++) bc[i] = acc[i] / (1.f + __expf(-acc[i]));
    }
  } else {
    int h0 = (j - 260) * 8;
    bf16x8 uv = *(const bf16x8*)(u + (size_t)row * DPROJ + (DPROJ - NH) + h0);
    float* dst = dtf + (size_t)row * NH + h0;
#pragma unroll
    for (int i = 0; i < 8; i++) {
      float xv = (float)uv[i] + dt_bias[h0 + i];
      dst[i] = (xv > 20.f) ? xv : log1pf(__expf(xv));
    }
  }
}

// ---------------- chunked scan, phase 1: local scan from zero -> (S, P) in u's dead tail
__global__ __launch_bounds__(64) void scan_p1(const bf16* __restrict__ xs,
                                              const float* __restrict__ BC,
                                              const float* __restrict__ dtf,
                                              const float* __restrict__ A_log,
                                              bf16* __restrict__ uscr) {
  int c = blockIdx.x & 63, hg = (blockIdx.x >> 6) & 31, b = blockIdx.x >> 11;
  int lane = threadIdx.x, hh = lane >> 3;
  int h = hg * 8 + hh;
  float A = -__expf(A_log[h]);
  float st[16];
#pragma unroll
  for (int n = 0; n < 16; n++) st[n] = 0.f;
  float pcum = 1.f;
  size_t rb = (size_t)b * SEQ + (size_t)c * LC;
  for (int t = 0; t < LC; t++) {
    size_t row = rb + t;
    const float* bcrow = BC + row * 32;
    float dtv = dtf[row * NH + h];
    float x = (float)xs[row * DIN + hg * 64 + lane];
    float dA = __expf(dtv * A);
    pcum *= dA;
    float w = dtv * x;
#pragma unroll
    for (int n = 0; n < 16; n++) st[n] = st[n] * dA + w * bcrow[n];
  }
  char* slot = (char*)uscr + (size_t)blockIdx.x * UROWB + 4096;
  float* S = (float*)slot;
#pragma unroll
  for (int n = 0; n < 16; n++) S[lane * 16 + n] = st[n];
  if ((lane & 7) == 0) ((float*)(slot + 4096))[hh] = pcum;
}

// ---------------- phase 2: sequential combine over chunks (prefetched); S <- incoming H
__global__ __launch_bounds__(64) void scan_p2(bf16* __restrict__ uscr) {
  int bh = blockIdx.x;  // 0..127 = b*32+hg
  int lane = threadIdx.x, hh = lane >> 3;
  float H[16];
#pragma unroll
  for (int n = 0; n < 16; n++) H[n] = 0.f;
  char* base = (char*)uscr + (size_t)bh * NC * UROWB + 4096;
  float sN[16], PN;
  {
    float* S = (float*)base;
#pragma unroll
    for (int n = 0; n < 16; n++) sN[n] = S[lane * 16 + n];
    PN = ((const float*)(base + 4096))[hh];
  }
  for (int c = 0; c < NC; c++) {
    float sC[16], PC = PN;
#pragma unroll
    for (int n = 0; n < 16; n++) sC[n] = sN[n];
    if (c + 1 < NC) {
      char* slot = base + (size_t)(c + 1) * UROWB;
      float* S = (float*)slot;
#pragma unroll
      for (int n = 0; n < 16; n++) sN[n] = S[lane * 16 + n];
      PN = ((const float*)(slot + 4096))[hh];
    }
    float* S0 = (float*)(base + (size_t)c * UROWB);
#pragma unroll
    for (int n = 0; n < 16; n++) {
      float hn = H[n];
      S0[lane * 16 + n] = hn;
      H[n] = PC * hn + sC[n];
    }
  }
}

// ---------------- phase 3: re-scan each chunk from true incoming state, emit y
__global__ __launch_bounds__(64) void scan_p3(const bf16* __restrict__ xs,
                                              const float* __restrict__ BC,
                                              const float* __restrict__ dtf,
                                              const float* __restrict__ A_log,
                                              const float* __restrict__ Dp,
                                              const bf16* __restrict__ uscr,
                                              bf16* __restrict__ y) {
  int c = blockIdx.x & 63, hg = (blockIdx.x >> 6) & 31, b = blockIdx.x >> 11;
  int lane = threadIdx.x, hh = lane >> 3;
  int h = hg * 8 + hh;
  float A = -__expf(A_log[h]);
  float D = Dp[h];
  const char* slot = (const char*)uscr + (size_t)blockIdx.x * UROWB + 4096;
  float st[16];
#pragma unroll
  for (int n = 0; n < 16; n++) st[n] = ((const float*)slot)[lane * 16 + n];
  size_t rb = (size_t)b * SEQ + (size_t)c * LC;
  for (int t = 0; t < LC; t++) {
    size_t row = rb + t;
    const float* bcrow = BC + row * 32;
    float dtv = dtf[row * NH + h];
    float x = (float)xs[row * DIN + hg * 64 + lane];
    float dA = __expf(dtv * A);
    float w = dtv * x;
    float yv = 0.f;
#pragma unroll
    for (int n = 0; n < 16; n++) {
      st[n] = st[n] * dA + w * bcrow[n];
      yv += st[n] * bcrow[16 + n];
    }
    y[row * DIN + hg * 64 + lane] = (bf16)(yv + D * x);
  }
}

// ---------------- gating + rmsnorm -> g bf16
__global__ __launch_bounds__(256) void gate_rms(const bf16* __restrict__ u,
                                                const bf16* __restrict__ y,
                                                const float* __restrict__ rms_w,
                                                bf16* __restrict__ g) {
  int row = blockIdx.x;
  int t = threadIdx.x;
  bf16x8 zv = ((const bf16x8*)(u + (size_t)row * DPROJ))[t];
  bf16x8 yv = ((const bf16x8*)(y + (size_t)row * DIN))[t];
  float gv[8];
  float s2 = 0.f;
#pragma unroll
  for (int i = 0; i < 8; i++) {
    float z = (float)zv[i];
    float yy = (float)yv[i];
    float gg = yy * z / (1.f + __expf(-z));
    gv[i] = gg;
    s2 += gg * gg;
  }
#pragma unroll
  for (int off = 32; off > 0; off >>= 1) s2 += __shfl_down(s2, off);
  __shared__ float ps[4];
  int wave = t >> 6, lane = t & 63;
  if (lane == 0) ps[wave] = s2;
  __syncthreads();
  s2 = ps[0] + ps[1] + ps[2] + ps[3];
  float scale = rsqrtf(s2 * (1.f / DIN) + 1e-5f);
  f32x4 w0 = ((const f32x4*)rms_w)[2 * t];
  f32x4 w1 = ((const f32x4*)rms_w)[2 * t + 1];
  bf16x8 og;
#pragma unroll
  for (int i = 0; i < 4; i++) og[i] = (bf16)(gv[i] * scale * w0[i]);
#pragma unroll
  for (int i = 0; i < 4; i++) og[4 + i] = (bf16)(gv[4 + i] * scale * w1[i]);
  ((bf16x8*)(g + (size_t)row * DIN))[t] = og;
}

extern "C" void kernel_launch(void* const* d_in, const int* in_sizes, int n_in,
                              void* d_out, int out_size, void* d_ws, size_t ws_size,
                              hipStream_t stream) {
  const float* x = (const float*)d_in[0];
  const float* lnw = (const float*)d_in[1];
  const float* lnb = (const float*)d_in[2];
  const float* Win = (const float*)d_in[3];
  const float* cw = (const float*)d_in[4];
  const float* cb = (const float*)d_in[5];
  const float* Alog = (const float*)d_in[6];
  const float* Dpv = (const float*)d_in[7];
  const float* dtb = (const float*)d_in[8];
  const float* rmsw = (const float*)d_in[9];
  const float* Wout = (const float*)d_in[10];
  float* out = (float*)d_out;

  char* ws = (char*)d_ws;
  bf16* u = (bf16*)(ws + 0);                     // [8192][4384] bf16
  bf16* xnb = (bf16*)(ws + 71827456);            // [8192][1024] bf16 (dead after GEMM1)
  bf16* WinT = (bf16*)(ws + 88604672);           // [4608][1024] bf16 (dead after GEMM1)
  bf16* yb = (bf16*)(ws + 71827456);             // [8192][2048] bf16 (reuses xnb+WinT)
  bf16* xsb = (bf16*)(ws + 105381888);           // [8192][2048] bf16 (dead after scan)
  bf16* gb = (bf16*)(ws + 105381888);            // reuses xsb
  float* BC = (float*)(ws + 138936320);          // [8192][32] f32
  float* dtf = (float*)(ws + 139984896);         // [8192][256] f32
  bf16* WoutT = (bf16*)(ws + 148373504);         // [1024][2048] bf16

  transpose_cvt<<<dim3(32, 144), dim3(32, 8), 0, stream>>>(Win, WinT, 1024, DPROJ, NPAD1);
  transpose_cvt<<<dim3(64, 32), dim3(32, 8), 0, stream>>>(Wout, WoutT, DIN, DM, DM);
  ln_kernel<<<MROWS, 256, 0, stream>>>(x, lnw, lnb, xnb);
  gemm1_8p<<<576, 512, 0, stream>>>(xnb, WinT, u);
  conv_prep3<<<(MROWS * 292) / 256, 256, 0, stream>>>(u, cw, cb, dtb, xsb, BC, dtf);
  scan_p1<<<MROWS, 64, 0, stream>>>(xsb, BC, dtf, Alog, u);
  scan_p2<<<128, 64, 0, stream>>>(u);
  scan_p3<<<MROWS, 64, 0, stream>>>(xsb, BC, dtf, Alog, Dpv, u, yb);
  gate_rms<<<MROWS, 256, 0, stream>>>(u, yb, rmsw, gb);
  gemm2_8p<<<256, 512, 0, stream>>>(gb, WoutT, out, x);
}

// Round 10
// 298.597 us; speedup vs baseline: 1.2839x; 1.0161x over previous
//
#include <hip/hip_runtime.h>

typedef __bf16 bf16;
typedef __attribute__((ext_vector_type(8))) __bf16 bf16x8;
typedef __attribute__((ext_vector_type(4))) float f32x4;

#define B_SZ 4
#define SEQ 2048
#define DM 1024
#define DIN 2048
#define NH 256
#define DSTATE 16
#define CONVD 2080
#define DPROJ 4384
#define NPAD1 4608
#define MROWS 8192
#define NC 64
#define LC 32
#define UROWB 8768  // u row stride in bytes (4384 * 2)

__device__ __forceinline__ void gload_lds16(const void* g, void* l) {
  __builtin_amdgcn_global_load_lds(
      (__attribute__((address_space(1))) void*)g,
      (__attribute__((address_space(3))) void*)l, 16, 0, 0);
}

template <int N>
__device__ __forceinline__ void vm_wait() {
  asm volatile("s_waitcnt vmcnt(%0)" ::"n"(N) : "memory");
}
__device__ __forceinline__ void bar() { asm volatile("s_barrier" ::: "memory"); }
__device__ __forceinline__ void lgkm0() {
  asm volatile("s_waitcnt lgkmcnt(0)" ::: "memory");
}

// ---------------- transpose (f32 [K][N] -> bf16 [Npad][K], zero-pad rows >= N)
__global__ void transpose_cvt(const float* __restrict__ W, bf16* __restrict__ WT,
                              int K, int N, int Npad) {
  __shared__ float tile[32][33];
  int k0 = blockIdx.x * 32, n0 = blockIdx.y * 32;
  int tx = threadIdx.x, ty = threadIdx.y;  // (32, 8)
#pragma unroll
  for (int j = 0; j < 4; j++) {
    int k = k0 + ty + 8 * j, n = n0 + tx;
    tile[ty + 8 * j][tx] = (k < K && n < N) ? W[(size_t)k * N + n] : 0.f;
  }
  __syncthreads();
#pragma unroll
  for (int j = 0; j < 4; j++) {
    int n = n0 + ty + 8 * j, k = k0 + tx;
    if (n < Npad && k < K) WT[(size_t)n * K + k] = (bf16)tile[tx][ty + 8 * j];
  }
}

// ---------------- layernorm (f32 in) -> xn bf16
__global__ __launch_bounds__(256) void ln_kernel(const float* __restrict__ x,
                                                 const float* __restrict__ lw,
                                                 const float* __restrict__ lb,
                                                 bf16* __restrict__ xn) {
  int row = blockIdx.x;
  int t = threadIdx.x;
  f32x4 v4 = ((const f32x4*)(x + (size_t)row * DM))[t];
  float v0 = v4[0], v1 = v4[1], v2 = v4[2], v3 = v4[3];
  float s = v0 + v1 + v2 + v3;
  float s2 = v0 * v0 + v1 * v1 + v2 * v2 + v3 * v3;
#pragma unroll
  for (int off = 32; off > 0; off >>= 1) {
    s += __shfl_down(s, off);
    s2 += __shfl_down(s2, off);
  }
  __shared__ float ps[8];
  int wave = t >> 6, lane = t & 63;
  if (lane == 0) { ps[wave] = s; ps[4 + wave] = s2; }
  __syncthreads();
  s = ps[0] + ps[1] + ps[2] + ps[3];
  s2 = ps[4] + ps[5] + ps[6] + ps[7];
  float mean = s * (1.f / DM);
  float var = s2 * (1.f / DM) - mean * mean;
  float rstd = rsqrtf(var + 1e-5f);
  f32x4 wv = ((const f32x4*)lw)[t];
  f32x4 bv = ((const f32x4*)lb)[t];
  bf16 o[4];
  o[0] = (bf16)((v0 - mean) * rstd * wv[0] + bv[0]);
  o[1] = (bf16)((v1 - mean) * rstd * wv[1] + bv[1]);
  o[2] = (bf16)((v2 - mean) * rstd * wv[2] + bv[2]);
  o[3] = (bf16)((v3 - mean) * rstd * wv[3] + bv[3]);
  bf16* dst = xn + (size_t)row * DM + t * 4;
  dst[0] = o[0]; dst[1] = o[1]; dst[2] = o[2]; dst[3] = o[3];
}

// ---------------- GEMM1: 256x192 tile, grid 768 (= exactly 3 blocks/CU), BK=64,
// 8 waves (2M x 4N, wave tile 128x48). 2 phases/K-tile.
// LDS: A 3 bufs x 32KB at 0 (triple-buffered, 2-deep prefetch);
//      B 2 bufs x 24KB at 98304. Total 144 KiB.
// Ledger (steady): enter ph1(kt) with [A(kt+1)]; ph1 issues B(kt+1) then A(kt+2);
// ph2 waits vmcnt(4) -> drains A(kt+1)+B(kt+1), leaves A(kt+2). Race-audited:
// stA(kt+2) overwrites buf holding A(kt-1), last read ph2(kt-1), gap = 1 barrier;
// stB(kt+1) overwrites buf holding B(kt-1), last read ph1(kt-1), gap = 1 phase.
__global__ __launch_bounds__(512, 2) void gemm1_8p(const bf16* __restrict__ A,
                                                   const bf16* __restrict__ BT,
                                                   bf16* __restrict__ C) {
  __shared__ char lds[147456];
  int bid = blockIdx.x;                       // 768 = 32 m-tiles * 24 n-tiles
  int swz = (bid & 7) * 96 + (bid >> 3);      // bijective XCD swizzle (768 % 8 == 0)
  int bm = swz / 24, bn = swz - (swz / 24) * 24;
  int m0 = bm * 256, n0 = bn * 192;
  int t = threadIdx.x, lane = t & 63, wave = t >> 6;
  int wm = wave >> 2, wn = wave & 3;
  int lr16 = lane & 15, kq = lane >> 4;
  int ts0 = kq ^ (lr16 & 7);
  int ts1 = (4 + kq) ^ (lr16 & 7);
  int sw = (lane & 7) ^ (lane >> 3);
  int l8 = lane >> 3;
  const char* Ab = (const char*)A;
  const char* Bb = (const char*)BT;

  // A: 256 rows x 128 B per buf; 4 gloads/thread (chunk c = wave*4+g covers rows c*8..c*8+7)
  auto stA = [&](int kt, int ab) {
    char* slot = lds + ab * 32768;
    size_t ko = (size_t)kt * 128 + sw * 16;
#pragma unroll
    for (int g = 0; g < 4; g++) {
      int c = wave * 4 + g;
      gload_lds16(Ab + (size_t)(m0 + c * 8 + l8) * 2048 + ko, slot + c * 1024);
    }
  };
  // B: 192 rows x 128 B per buf; 3 gloads/thread
  auto stB = [&](int kt, int p) {
    char* slot = lds + 98304 + p * 24576;
    size_t ko = (size_t)kt * 128 + sw * 16;
#pragma unroll
    for (int g = 0; g < 3; g++) {
      int c = wave * 3 + g;
      gload_lds16(Bb + (size_t)(n0 + c * 8 + l8) * 2048 + ko, slot + c * 1024);
    }
  };

  f32x4 acc[8][3] = {};
  bf16x8 a_[4][2], b_[3][2];

  // prologue: A(0,buf0), B(0,buf0), A(1,buf1); drain A0+B0 (leave A1 = 4 in flight)
  stA(0, 0); stB(0, 0); stA(1, 1);
  vm_wait<4>();
  bar();
#pragma unroll 1
  for (int kt = 0; kt < 16; kt++) {
    int ab = kt % 3;
    int p = kt & 1;
    // ---- ph1: read aL (frag-rows 0..3) + all B; issue B(kt+1) then A(kt+2); 24 MFMA mq=0
    {
      const char* sa = lds + ab * 32768;
      const char* sb = lds + 98304 + p * 24576;
#pragma unroll
      for (int mi = 0; mi < 4; mi++) {
        int lrow = wm * 128 + mi * 16 + lr16;
        a_[mi][0] = *(const bf16x8*)(sa + lrow * 128 + ts0 * 16);
        a_[mi][1] = *(const bf16x8*)(sa + lrow * 128 + ts1 * 16);
      }
#pragma unroll
      for (int ni = 0; ni < 3; ni++) {
        int lrow = wn * 48 + ni * 16 + lr16;
        b_[ni][0] = *(const bf16x8*)(sb + lrow * 128 + ts0 * 16);
        b_[ni][1] = *(const bf16x8*)(sb + lrow * 128 + ts1 * 16);
      }
      if (kt < 15) stB(kt + 1, p ^ 1);
      if (kt < 14) stA(kt + 2, (kt + 2) % 3);
      bar();
      lgkm0();
      __builtin_amdgcn_s_setprio(1);
#pragma unroll
      for (int mi = 0; mi < 4; mi++)
#pragma unroll
        for (int ni = 0; ni < 3; ni++) {
          acc[mi][ni] = __builtin_amdgcn_mfma_f32_16x16x32_bf16(a_[mi][0], b_[ni][0], acc[mi][ni], 0, 0, 0);
          acc[mi][ni] = __builtin_amdgcn_mfma_f32_16x16x32_bf16(a_[mi][1], b_[ni][1], acc[mi][ni], 0, 0, 0);
        }
      __builtin_amdgcn_s_setprio(0);
      bar();
    }
    // ---- ph2: read aH (frag-rows 4..7); wait; 24 MFMA mq=1 (B persists in regs)
    {
      const char* sa = lds + ab * 32768;
#pragma unroll
      for (int mi = 0; mi < 4; mi++) {
        int lrow = wm * 128 + 64 + mi * 16 + lr16;
        a_[mi][0] = *(const bf16x8*)(sa + lrow * 128 + ts0 * 16);
        a_[mi][1] = *(const bf16x8*)(sa + lrow * 128 + ts1 * 16);
      }
      if (kt < 14) vm_wait<4>();
      else if (kt == 14) vm_wait<0>();
      bar();
      lgkm0();
      __builtin_amdgcn_s_setprio(1);
#pragma unroll
      for (int mi = 0; mi < 4; mi++)
#pragma unroll
        for (int ni = 0; ni < 3; ni++) {
          acc[4 + mi][ni] = __builtin_amdgcn_mfma_f32_16x16x32_bf16(a_[mi][0], b_[ni][0], acc[4 + mi][ni], 0, 0, 0);
          acc[4 + mi][ni] = __builtin_amdgcn_mfma_f32_16x16x32_bf16(a_[mi][1], b_[ni][1], acc[4 + mi][ni], 0, 0, 0);
        }
      __builtin_amdgcn_s_setprio(0);
      bar();
    }
  }
#pragma unroll
  for (int fr = 0; fr < 8; fr++)
#pragma unroll
    for (int ni = 0; ni < 3; ni++) {
      int row = m0 + wm * 128 + fr * 16 + kq * 4;
      int col = n0 + wn * 48 + ni * 16 + lr16;
      f32x4 v = acc[fr][ni];
      if (col < 4384) {
#pragma unroll
        for (int r = 0; r < 4; r++)
          C[(size_t)(row + r) * DPROJ + col] = (bf16)v[r];
      }
    }
}

// ---------------- GEMM2: 256x128, BK=64, 8 waves, grid 256 (=1/CU), dual-barrier skeleton.
#define G2_PHASE(MQ, P, STAGE, VMW)                                                        \
  {                                                                                        \
    const char* sa_ = lds + ((P) * 2 + (MQ)) * 16384;                                      \
    const char* sb_ = lds + 65536 + (P) * 16384;                                           \
    bf16x8 a_[4][2], b_[2][2];                                                             \
    _Pragma("unroll") for (int mi = 0; mi < 4; mi++) {                                     \
      int lrow = wm * 64 + mi * 16 + lr16;                                                 \
      a_[mi][0] = *(const bf16x8*)(sa_ + lrow * 128 + ts0 * 16);                           \
      a_[mi][1] = *(const bf16x8*)(sa_ + lrow * 128 + ts1 * 16);                           \
    }                                                                                      \
    _Pragma("unroll") for (int ni = 0; ni < 2; ni++) {                                     \
      int lrow = wn * 32 + ni * 16 + lr16;                                                 \
      b_[ni][0] = *(const bf16x8*)(sb_ + lrow * 128 + ts0 * 16);                           \
      b_[ni][1] = *(const bf16x8*)(sb_ + lrow * 128 + ts1 * 16);                           \
    }                                                                                      \
    STAGE;                                                                                 \
    VMW;                                                                                   \
    bar();                                                                                 \
    lgkm0();                                                                               \
    __builtin_amdgcn_s_setprio(1);                                                         \
    _Pragma("unroll") for (int mi = 0; mi < 4; mi++)                                       \
      _Pragma("unroll") for (int ni = 0; ni < 2; ni++) {                                   \
        acc[(MQ) * 4 + mi][ni] = __builtin_amdgcn_mfma_f32_16x16x32_bf16(                  \
            a_[mi][0], b_[ni][0], acc[(MQ) * 4 + mi][ni], 0, 0, 0);                        \
        acc[(MQ) * 4 + mi][ni] = __builtin_amdgcn_mfma_f32_16x16x32_bf16(                  \
            a_[mi][1], b_[ni][1], acc[(MQ) * 4 + mi][ni], 0, 0, 0);                        \
      }                                                                                    \
    __builtin_amdgcn_s_setprio(0);                                                         \
    bar();                                                                                 \
  }

__global__ __launch_bounds__(512, 2) void gemm2_8p(const bf16* __restrict__ A,
                                                   const bf16* __restrict__ BT,
                                                   float* __restrict__ C,
                                                   const float* __restrict__ Xres) {
  __shared__ char lds[98304];
  int bid = blockIdx.x;                  // 256 = 32 m * 8 n
  int swz = (bid & 7) * 32 + (bid >> 3); // bijective (256 % 8 == 0)
  int bm = swz >> 3, bn = swz & 7;
  int m0 = bm * 256, n0 = bn * 128;
  int t = threadIdx.x, lane = t & 63, wave = t >> 6;
  int wm = wave >> 2, wn = wave & 3;
  int lr16 = lane & 15, kq = lane >> 4;
  int ts0 = kq ^ (lr16 & 7);
  int ts1 = (4 + kq) ^ (lr16 & 7);
  int sw = (lane & 7) ^ ((lane >> 3) & 7);
  int l8 = lane >> 3;
  int c0 = 2 * wave, c1 = 2 * wave + 1;
  int lr0 = c0 * 8 + l8, lr1 = c1 * 8 + l8;
  const char* Ab = (const char*)A;
  const char* Bb = (const char*)BT;
  int grA0 = m0 + (lr0 >> 6) * 128 + (lr0 & 63);
  int grA1 = m0 + (lr1 >> 6) * 128 + (lr1 & 63);
  int gcB0 = n0 + lr0, gcB1 = n0 + lr1;  // lr in [0,128)

  auto stA = [&](int kt, int p, int mq) {
    char* slot = lds + (p * 2 + mq) * 16384;
    size_t ko = (size_t)kt * 128 + sw * 16;
    gload_lds16(Ab + (size_t)(grA0 + mq * 64) * 4096 + ko, slot + c0 * 1024);
    gload_lds16(Ab + (size_t)(grA1 + mq * 64) * 4096 + ko, slot + c1 * 1024);
  };
  auto stB = [&](int kt, int p) {
    char* slot = lds + 65536 + p * 16384;
    size_t ko = (size_t)kt * 128 + sw * 16;
    gload_lds16(Bb + (size_t)gcB0 * 4096 + ko, slot + c0 * 1024);
    gload_lds16(Bb + (size_t)gcB1 * 4096 + ko, slot + c1 * 1024);
  };

  f32x4 acc[8][2] = {};
  stA(0, 0, 0); stB(0, 0); stA(0, 0, 1); stA(1, 1, 0);
  vm_wait<4>();
  bar();
#pragma unroll 1
  for (int kt = 0; kt < 32; kt++) {
    int p = kt & 1;
    G2_PHASE(0, p, { if (kt + 1 < 32) { stB(kt + 1, p ^ 1); stA(kt + 1, p ^ 1, 1); } },
             { if (kt < 31) vm_wait<6>(); else vm_wait<0>(); });
    G2_PHASE(1, p, { if (kt + 2 < 32) stA(kt + 2, p, 0); },
             { if (kt < 30) vm_wait<4>(); else if (kt == 30) vm_wait<2>(); });
  }
#pragma unroll
  for (int mq = 0; mq < 2; mq++)
#pragma unroll
    for (int mi = 0; mi < 4; mi++)
#pragma unroll
      for (int ni = 0; ni < 2; ni++) {
        int row = m0 + wm * 128 + mq * 64 + mi * 16 + kq * 4;
        int col = n0 + wn * 32 + ni * 16 + lr16;
        f32x4 v = acc[mq * 4 + mi][ni];
#pragma unroll
        for (int r = 0; r < 4; r++) {
          size_t o = (size_t)(row + r) * DM + col;
          C[o] = Xres[o] + v[r];
        }
      }
}

// ---------------- conv: one thread per 8-channel vector per row
__global__ __launch_bounds__(256) void conv_prep3(const bf16* __restrict__ u,
                                                  const float* __restrict__ cw,
                                                  const float* __restrict__ cb,
                                                  const float* __restrict__ dt_bias,
                                                  bf16* __restrict__ xs,
                                                  float* __restrict__ BC,
                                                  float* __restrict__ dtf) {
  const int JPR = 292;  // 260 conv vec8 + 32 dt vec8
  int idx = blockIdx.x * 256 + threadIdx.x;
  if (idx >= MROWS * JPR) return;
  int row = idx / JPR;
  int j = idx - row * JPR;
  int t = row & (SEQ - 1);
  if (j < 260) {
    int c0 = j * 8;
    float acc[8];
#pragma unroll
    for (int i = 0; i < 8; i++) acc[i] = cb[c0 + i];
    const bf16* ub = u + (size_t)row * DPROJ + DIN + c0;
#pragma unroll
    for (int tap = 0; tap < 4; tap++) {
      int tt = t - 3 + tap;
      if (tt >= 0) {
        bf16x8 uv = *(const bf16x8*)(ub + (ptrdiff_t)(tap - 3) * DPROJ);
        const float* wv = cw + tap * CONVD + c0;
#pragma unroll
        for (int i = 0; i < 8; i++) acc[i] += wv[i] * (float)uv[i];
      }
    }
    if (c0 < DIN) {
      bf16x8 o;
#pragma unroll
      for (int i = 0; i < 8; i++) {
        float sv = acc[i] / (1.f + __expf(-acc[i]));
        o[i] = (bf16)sv;
      }
      *(bf16x8*)(xs + (size_t)row * DIN + c0) = o;
    } else {
      float* bc = BC + (size_t)row * 32 + (c0 - DIN);
#pragma unroll
      for (int i = 0; i < 8; i++) bc[i] = acc[i] / (1.f + __expf(-acc[i]));
    }
  } else {
    int h0 = (j - 260) * 8;
    bf16x8 uv = *(const bf16x8*)(u + (size_t)row * DPROJ + (DPROJ - NH) + h0);
    float* dst = dtf + (size_t)row * NH + h0;
#pragma unroll
    for (int i = 0; i < 8; i++) {
      float xv = (float)uv[i] + dt_bias[h0 + i];
      dst[i] = (xv > 20.f) ? xv : log1pf(__expf(xv));
    }
  }
}

// ---------------- chunked scan, phase 1: local scan from zero -> (S, P) in u's dead tail
__global__ __launch_bounds__(64) void scan_p1(const bf16* __restrict__ xs,
                                              const float* __restrict__ BC,
                                              const float* __restrict__ dtf,
                                              const float* __restrict__ A_log,
                                              bf16* __restrict__ uscr) {
  int c = blockIdx.x & 63, hg = (blockIdx.x >> 6) & 31, b = blockIdx.x >> 11;
  int lane = threadIdx.x, hh = lane >> 3;
  int h = hg * 8 + hh;
  float A = -__expf(A_log[h]);
  float st[16];
#pragma unroll
  for (int n = 0; n < 16; n++) st[n] = 0.f;
  float pcum = 1.f;
  size_t rb = (size_t)b * SEQ + (size_t)c * LC;
  for (int t = 0; t < LC; t++) {
    size_t row = rb + t;
    const float* bcrow = BC + row * 32;
    float dtv = dtf[row * NH + h];
    float x = (float)xs[row * DIN + hg * 64 + lane];
    float dA = __expf(dtv * A);
    pcum *= dA;
    float w = dtv * x;
#pragma unroll
    for (int n = 0; n < 16; n++) st[n] = st[n] * dA + w * bcrow[n];
  }
  char* slot = (char*)uscr + (size_t)blockIdx.x * UROWB + 4096;
  float* S = (float*)slot;
#pragma unroll
  for (int n = 0; n < 16; n++) S[lane * 16 + n] = st[n];
  if ((lane & 7) == 0) ((float*)(slot + 4096))[hh] = pcum;
}

// ---------------- phase 2: sequential combine over chunks (prefetched); S <- incoming H
__global__ __launch_bounds__(64) void scan_p2(bf16* __restrict__ uscr) {
  int bh = blockIdx.x;  // 0..127 = b*32+hg
  int lane = threadIdx.x, hh = lane >> 3;
  float H[16];
#pragma unroll
  for (int n = 0; n < 16; n++) H[n] = 0.f;
  char* base = (char*)uscr + (size_t)bh * NC * UROWB + 4096;
  float sN[16], PN;
  {
    float* S = (float*)base;
#pragma unroll
    for (int n = 0; n < 16; n++) sN[n] = S[lane * 16 + n];
    PN = ((const float*)(base + 4096))[hh];
  }
  for (int c = 0; c < NC; c++) {
    float sC[16], PC = PN;
#pragma unroll
    for (int n = 0; n < 16; n++) sC[n] = sN[n];
    if (c + 1 < NC) {
      char* slot = base + (size_t)(c + 1) * UROWB;
      float* S = (float*)slot;
#pragma unroll
      for (int n = 0; n < 16; n++) sN[n] = S[lane * 16 + n];
      PN = ((const float*)(slot + 4096))[hh];
    }
    float* S0 = (float*)(base + (size_t)c * UROWB);
#pragma unroll
    for (int n = 0; n < 16; n++) {
      float hn = H[n];
      S0[lane * 16 + n] = hn;
      H[n] = PC * hn + sC[n];
    }
  }
}

// ---------------- phase 3: re-scan each chunk from true incoming state, emit y
__global__ __launch_bounds__(64) void scan_p3(const bf16* __restrict__ xs,
                                              const float* __restrict__ BC,
                                              const float* __restrict__ dtf,
                                              const float* __restrict__ A_log,
                                              const float* __restrict__ Dp,
                                              const bf16* __restrict__ uscr,
                                              bf16* __restrict__ y) {
  int c = blockIdx.x & 63, hg = (blockIdx.x >> 6) & 31, b = blockIdx.x >> 11;
  int lane = threadIdx.x, hh = lane >> 3;
  int h = hg * 8 + hh;
  float A = -__expf(A_log[h]);
  float D = Dp[h];
  const char* slot = (const char*)uscr + (size_t)blockIdx.x * UROWB + 4096;
  float st[16];
#pragma unroll
  for (int n = 0; n < 16; n++) st[n] = ((const float*)slot)[lane * 16 + n];
  size_t rb = (size_t)b * SEQ + (size_t)c * LC;
  for (int t = 0; t < LC; t++) {
    size_t row = rb + t;
    const float* bcrow = BC + row * 32;
    float dtv = dtf[row * NH + h];
    float x = (float)xs[row * DIN + hg * 64 + lane];
    float dA = __expf(dtv * A);
    float w = dtv * x;
    float yv = 0.f;
#pragma unroll
    for (int n = 0; n < 16; n++) {
      st[n] = st[n] * dA + w * bcrow[n];
      yv += st[n] * bcrow[16 + n];
    }
    y[row * DIN + hg * 64 + lane] = (bf16)(yv + D * x);
  }
}

// ---------------- gating + rmsnorm -> g bf16
__global__ __launch_bounds__(256) void gate_rms(const bf16* __restrict__ u,
                                                const bf16* __restrict__ y,
                                                const float* __restrict__ rms_w,
                                                bf16* __restrict__ g) {
  int row = blockIdx.x;
  int t = threadIdx.x;
  bf16x8 zv = ((const bf16x8*)(u + (size_t)row * DPROJ))[t];
  bf16x8 yv = ((const bf16x8*)(y + (size_t)row * DIN))[t];
  float gv[8];
  float s2 = 0.f;
#pragma unroll
  for (int i = 0; i < 8; i++) {
    float z = (float)zv[i];
    float yy = (float)yv[i];
    float gg = yy * z / (1.f + __expf(-z));
    gv[i] = gg;
    s2 += gg * gg;
  }
#pragma unroll
  for (int off = 32; off > 0; off >>= 1) s2 += __shfl_down(s2, off);
  __shared__ float ps[4];
  int wave = t >> 6, lane = t & 63;
  if (lane == 0) ps[wave] = s2;
  __syncthreads();
  s2 = ps[0] + ps[1] + ps[2] + ps[3];
  float scale = rsqrtf(s2 * (1.f / DIN) + 1e-5f);
  f32x4 w0 = ((const f32x4*)rms_w)[2 * t];
  f32x4 w1 = ((const f32x4*)rms_w)[2 * t + 1];
  bf16x8 og;
#pragma unroll
  for (int i = 0; i < 4; i++) og[i] = (bf16)(gv[i] * scale * w0[i]);
#pragma unroll
  for (int i = 0; i < 4; i++) og[4 + i] = (bf16)(gv[4 + i] * scale * w1[i]);
  ((bf16x8*)(g + (size_t)row * DIN))[t] = og;
}

extern "C" void kernel_launch(void* const* d_in, const int* in_sizes, int n_in,
                              void* d_out, int out_size, void* d_ws, size_t ws_size,
                              hipStream_t stream) {
  const float* x = (const float*)d_in[0];
  const float* lnw = (const float*)d_in[1];
  const float* lnb = (const float*)d_in[2];
  const float* Win = (const float*)d_in[3];
  const float* cw = (const float*)d_in[4];
  const float* cb = (const float*)d_in[5];
  const float* Alog = (const float*)d_in[6];
  const float* Dpv = (const float*)d_in[7];
  const float* dtb = (const float*)d_in[8];
  const float* rmsw = (const float*)d_in[9];
  const float* Wout = (const float*)d_in[10];
  float* out = (float*)d_out;

  char* ws = (char*)d_ws;
  bf16* u = (bf16*)(ws + 0);                     // [8192][4384] bf16
  bf16* xnb = (bf16*)(ws + 71827456);            // [8192][1024] bf16 (dead after GEMM1)
  bf16* WinT = (bf16*)(ws + 88604672);           // [4608][1024] bf16 (dead after GEMM1)
  bf16* yb = (bf16*)(ws + 71827456);             // [8192][2048] bf16 (reuses xnb+WinT)
  bf16* xsb = (bf16*)(ws + 105381888);           // [8192][2048] bf16 (dead after scan)
  bf16* gb = (bf16*)(ws + 105381888);            // reuses xsb
  float* BC = (float*)(ws + 138936320);          // [8192][32] f32
  float* dtf = (float*)(ws + 139984896);         // [8192][256] f32
  bf16* WoutT = (bf16*)(ws + 148373504);         // [1024][2048] bf16

  transpose_cvt<<<dim3(32, 144), dim3(32, 8), 0, stream>>>(Win, WinT, 1024, DPROJ, NPAD1);
  transpose_cvt<<<dim3(64, 32), dim3(32, 8), 0, stream>>>(Wout, WoutT, DIN, DM, DM);
  ln_kernel<<<MROWS, 256, 0, stream>>>(x, lnw, lnb, xnb);
  gemm1_8p<<<768, 512, 0, stream>>>(xnb, WinT, u);
  conv_prep3<<<(MROWS * 292) / 256, 256, 0, stream>>>(u, cw, cb, dtb, xsb, BC, dtf);
  scan_p1<<<MROWS, 64, 0, stream>>>(xsb, BC, dtf, Alog, u);
  scan_p2<<<128, 64, 0, stream>>>(u);
  scan_p3<<<MROWS, 64, 0, stream>>>(xsb, BC, dtf, Alog, Dpv, u, yb);
  gate_rms<<<MROWS, 256, 0, stream>>>(u, yb, rmsw, gb);
  gemm2_8p<<<256, 512, 0, stream>>>(gb, WoutT, out, x);
}

// Round 11
// 298.148 us; speedup vs baseline: 1.2858x; 1.0015x over previous
//
#include <hip/hip_runtime.h>

typedef __bf16 bf16;
typedef __attribute__((ext_vector_type(8))) __bf16 bf16x8;
typedef __attribute__((ext_vector_type(4))) float f32x4;

#define B_SZ 4
#define SEQ 2048
#define DM 1024
#define DIN 2048
#define NH 256
#define DSTATE 16
#define CONVD 2080
#define DPROJ 4384
#define NPAD1 4608
#define MROWS 8192
#define NC 64
#define LC 32
#define UROWB 8768  // u row stride in bytes (4384 * 2)

__device__ __forceinline__ void gload_lds16(const void* g, void* l) {
  __builtin_amdgcn_global_load_lds(
      (__attribute__((address_space(1))) void*)g,
      (__attribute__((address_space(3))) void*)l, 16, 0, 0);
}

template <int N>
__device__ __forceinline__ void vm_wait() {
  asm volatile("s_waitcnt vmcnt(%0)" ::"n"(N) : "memory");
}
__device__ __forceinline__ void bar() { asm volatile("s_barrier" ::: "memory"); }
__device__ __forceinline__ void lgkm0() {
  asm volatile("s_waitcnt lgkmcnt(0)" ::: "memory");
}

// ---------------- transpose (f32 [K][N] -> bf16 [Npad][K], zero-pad rows >= N)
__global__ void transpose_cvt(const float* __restrict__ W, bf16* __restrict__ WT,
                              int K, int N, int Npad) {
  __shared__ float tile[32][33];
  int k0 = blockIdx.x * 32, n0 = blockIdx.y * 32;
  int tx = threadIdx.x, ty = threadIdx.y;  // (32, 8)
#pragma unroll
  for (int j = 0; j < 4; j++) {
    int k = k0 + ty + 8 * j, n = n0 + tx;
    tile[ty + 8 * j][tx] = (k < K && n < N) ? W[(size_t)k * N + n] : 0.f;
  }
  __syncthreads();
#pragma unroll
  for (int j = 0; j < 4; j++) {
    int n = n0 + ty + 8 * j, k = k0 + tx;
    if (n < Npad && k < K) WT[(size_t)n * K + k] = (bf16)tile[tx][ty + 8 * j];
  }
}

// ---------------- layernorm (f32 in) -> xn bf16
__global__ __launch_bounds__(256) void ln_kernel(const float* __restrict__ x,
                                                 const float* __restrict__ lw,
                                                 const float* __restrict__ lb,
                                                 bf16* __restrict__ xn) {
  int row = blockIdx.x;
  int t = threadIdx.x;
  f32x4 v4 = ((const f32x4*)(x + (size_t)row * DM))[t];
  float v0 = v4[0], v1 = v4[1], v2 = v4[2], v3 = v4[3];
  float s = v0 + v1 + v2 + v3;
  float s2 = v0 * v0 + v1 * v1 + v2 * v2 + v3 * v3;
#pragma unroll
  for (int off = 32; off > 0; off >>= 1) {
    s += __shfl_down(s, off);
    s2 += __shfl_down(s2, off);
  }
  __shared__ float ps[8];
  int wave = t >> 6, lane = t & 63;
  if (lane == 0) { ps[wave] = s; ps[4 + wave] = s2; }
  __syncthreads();
  s = ps[0] + ps[1] + ps[2] + ps[3];
  s2 = ps[4] + ps[5] + ps[6] + ps[7];
  float mean = s * (1.f / DM);
  float var = s2 * (1.f / DM) - mean * mean;
  float rstd = rsqrtf(var + 1e-5f);
  f32x4 wv = ((const f32x4*)lw)[t];
  f32x4 bv = ((const f32x4*)lb)[t];
  bf16 o[4];
  o[0] = (bf16)((v0 - mean) * rstd * wv[0] + bv[0]);
  o[1] = (bf16)((v1 - mean) * rstd * wv[1] + bv[1]);
  o[2] = (bf16)((v2 - mean) * rstd * wv[2] + bv[2]);
  o[3] = (bf16)((v3 - mean) * rstd * wv[3] + bv[3]);
  bf16* dst = xn + (size_t)row * DM + t * 4;
  dst[0] = o[0]; dst[1] = o[1]; dst[2] = o[2]; dst[3] = o[3];
}

// ---------------- GEMM1: 256x192 tile, grid 768 (exactly 3 rounds), BK=64,
// 8 waves (2M x 4N). A double-buffered (2x32KB), B TRIPLE-buffered (3x24KB) = 136 KiB.
// Prefetch cover: A(kt+1) issued ph1(kt), consumed ph1(kt+1) = 2 phases;
// B(kt+2) issued ph1(kt), consumed ph1(kt+2) = 4 phases (covers L3/HBM latency).
// Waits: ph2(kt): vmcnt(3) drains A(kt+1)+B(kt+1), leaves B(kt+2). Tail kt=14: vmcnt(0).
// XCD swizzle: concurrent 32 blocks per XCD = 4m x 8n panel (A 2MB + B 3MB ~ L2-fit).
__global__ __launch_bounds__(512, 2) void gemm1_8p(const bf16* __restrict__ A,
                                                   const bf16* __restrict__ BT,
                                                   bf16* __restrict__ C) {
  __shared__ char lds[139264];
  int bid = blockIdx.x;  // 768 = 32 m-tiles * 24 n-tiles
  int xcd = bid & 7;
  int l = bid >> 3;             // 0..95 per XCD, 32 per round
  int bm = xcd * 4 + ((l >> 3) & 3);
  int bn = (l >> 5) * 8 + (l & 7);
  int m0 = bm * 256, n0 = bn * 192;
  int t = threadIdx.x, lane = t & 63, wave = t >> 6;
  int wm = wave >> 2, wn = wave & 3;
  int lr16 = lane & 15, kq = lane >> 4;
  int ts0 = kq ^ (lr16 & 7);
  int ts1 = (4 + kq) ^ (lr16 & 7);
  int sw = (lane & 7) ^ (lane >> 3);
  int l8 = lane >> 3;
  const char* Ab = (const char*)A;
  const char* Bb = (const char*)BT;

  // A: 256 rows x 128 B per buf (32 KB); 4 gloads/thread
  auto stA = [&](int kt) {
    char* slot = lds + (kt & 1) * 32768;
    size_t ko = (size_t)kt * 128 + sw * 16;
#pragma unroll
    for (int g = 0; g < 4; g++) {
      int c = wave * 4 + g;
      gload_lds16(Ab + (size_t)(m0 + c * 8 + l8) * 2048 + ko, slot + c * 1024);
    }
  };
  // B: 192 rows x 128 B per buf (24 KB); 3 gloads/thread
  auto stB = [&](int kt) {
    char* slot = lds + 65536 + (kt % 3) * 24576;
    size_t ko = (size_t)kt * 128 + sw * 16;
#pragma unroll
    for (int g = 0; g < 3; g++) {
      int c = wave * 3 + g;
      gload_lds16(Bb + (size_t)(n0 + c * 8 + l8) * 2048 + ko, slot + c * 1024);
    }
  };

  f32x4 acc[8][3] = {};
  bf16x8 a_[4][2], b_[3][2];

  // prologue: A(0),B(0),A(1),B(1) = 14 loads; drain first 7 (A0+B0), leave A1,B1
  stA(0); stB(0); stA(1); stB(1);
  vm_wait<7>();
  bar();
#pragma unroll 1
  for (int kt = 0; kt < 16; kt++) {
    // ---- ph1: read aL (frag-rows 0..3) + all B; issue A(kt+1), B(kt+2); 24 MFMA mq=0
    {
      const char* sa = lds + (kt & 1) * 32768;
      const char* sb = lds + 65536 + (kt % 3) * 24576;
#pragma unroll
      for (int mi = 0; mi < 4; mi++) {
        int lrow = wm * 128 + mi * 16 + lr16;
        a_[mi][0] = *(const bf16x8*)(sa + lrow * 128 + ts0 * 16);
        a_[mi][1] = *(const bf16x8*)(sa + lrow * 128 + ts1 * 16);
      }
#pragma unroll
      for (int ni = 0; ni < 3; ni++) {
        int lrow = wn * 48 + ni * 16 + lr16;
        b_[ni][0] = *(const bf16x8*)(sb + lrow * 128 + ts0 * 16);
        b_[ni][1] = *(const bf16x8*)(sb + lrow * 128 + ts1 * 16);
      }
      if (kt >= 1 && kt < 15) stA(kt + 1);
      if (kt < 14) stB(kt + 2);
      bar();
      lgkm0();
      __builtin_amdgcn_s_setprio(1);
#pragma unroll
      for (int mi = 0; mi < 4; mi++)
#pragma unroll
        for (int ni = 0; ni < 3; ni++) {
          acc[mi][ni] = __builtin_amdgcn_mfma_f32_16x16x32_bf16(a_[mi][0], b_[ni][0], acc[mi][ni], 0, 0, 0);
          acc[mi][ni] = __builtin_amdgcn_mfma_f32_16x16x32_bf16(a_[mi][1], b_[ni][1], acc[mi][ni], 0, 0, 0);
        }
      __builtin_amdgcn_s_setprio(0);
      bar();
    }
    // ---- ph2: read aH (frag-rows 4..7); wait drains next tile's A+B; 24 MFMA mq=1
    {
      const char* sa = lds + (kt & 1) * 32768;
#pragma unroll
      for (int mi = 0; mi < 4; mi++) {
        int lrow = wm * 128 + 64 + mi * 16 + lr16;
        a_[mi][0] = *(const bf16x8*)(sa + lrow * 128 + ts0 * 16);
        a_[mi][1] = *(const bf16x8*)(sa + lrow * 128 + ts1 * 16);
      }
      if (kt <= 13) vm_wait<3>();
      else if (kt == 14) vm_wait<0>();
      bar();
      lgkm0();
      __builtin_amdgcn_s_setprio(1);
#pragma unroll
      for (int mi = 0; mi < 4; mi++)
#pragma unroll
        for (int ni = 0; ni < 3; ni++) {
          acc[4 + mi][ni] = __builtin_amdgcn_mfma_f32_16x16x32_bf16(a_[mi][0], b_[ni][0], acc[4 + mi][ni], 0, 0, 0);
          acc[4 + mi][ni] = __builtin_amdgcn_mfma_f32_16x16x32_bf16(a_[mi][1], b_[ni][1], acc[4 + mi][ni], 0, 0, 0);
        }
      __builtin_amdgcn_s_setprio(0);
      bar();
    }
  }
#pragma unroll
  for (int fr = 0; fr < 8; fr++)
#pragma unroll
    for (int ni = 0; ni < 3; ni++) {
      int row = m0 + wm * 128 + fr * 16 + kq * 4;
      int col = n0 + wn * 48 + ni * 16 + lr16;
      f32x4 v = acc[fr][ni];
      if (col < 4384) {
#pragma unroll
        for (int r = 0; r < 4; r++)
          C[(size_t)(row + r) * DPROJ + col] = (bf16)v[r];
      }
    }
}

// ---------------- GEMM2: 256x128, BK=64, 8 waves, grid 256 (=1/CU), dual-barrier skeleton.
#define G2_PHASE(MQ, P, STAGE, VMW)                                                        \
  {                                                                                        \
    const char* sa_ = lds + ((P) * 2 + (MQ)) * 16384;                                      \
    const char* sb_ = lds + 65536 + (P) * 16384;                                           \
    bf16x8 a_[4][2], b_[2][2];                                                             \
    _Pragma("unroll") for (int mi = 0; mi < 4; mi++) {                                     \
      int lrow = wm * 64 + mi * 16 + lr16;                                                 \
      a_[mi][0] = *(const bf16x8*)(sa_ + lrow * 128 + ts0 * 16);                           \
      a_[mi][1] = *(const bf16x8*)(sa_ + lrow * 128 + ts1 * 16);                           \
    }                                                                                      \
    _Pragma("unroll") for (int ni = 0; ni < 2; ni++) {                                     \
      int lrow = wn * 32 + ni * 16 + lr16;                                                 \
      b_[ni][0] = *(const bf16x8*)(sb_ + lrow * 128 + ts0 * 16);                           \
      b_[ni][1] = *(const bf16x8*)(sb_ + lrow * 128 + ts1 * 16);                           \
    }                                                                                      \
    STAGE;                                                                                 \
    VMW;                                                                                   \
    bar();                                                                                 \
    lgkm0();                                                                               \
    __builtin_amdgcn_s_setprio(1);                                                         \
    _Pragma("unroll") for (int mi = 0; mi < 4; mi++)                                       \
      _Pragma("unroll") for (int ni = 0; ni < 2; ni++) {                                   \
        acc[(MQ) * 4 + mi][ni] = __builtin_amdgcn_mfma_f32_16x16x32_bf16(                  \
            a_[mi][0], b_[ni][0], acc[(MQ) * 4 + mi][ni], 0, 0, 0);                        \
        acc[(MQ) * 4 + mi][ni] = __builtin_amdgcn_mfma_f32_16x16x32_bf16(                  \
            a_[mi][1], b_[ni][1], acc[(MQ) * 4 + mi][ni], 0, 0, 0);                        \
      }                                                                                    \
    __builtin_amdgcn_s_setprio(0);                                                         \
    bar();                                                                                 \
  }

__global__ __launch_bounds__(512, 2) void gemm2_8p(const bf16* __restrict__ A,
                                                   const bf16* __restrict__ BT,
                                                   float* __restrict__ C,
                                                   const float* __restrict__ Xres) {
  __shared__ char lds[98304];
  int bid = blockIdx.x;                  // 256 = 32 m * 8 n
  int swz = (bid & 7) * 32 + (bid >> 3); // bijective (256 % 8 == 0)
  int bm = swz >> 3, bn = swz & 7;
  int m0 = bm * 256, n0 = bn * 128;
  int t = threadIdx.x, lane = t & 63, wave = t >> 6;
  int wm = wave >> 2, wn = wave & 3;
  int lr16 = lane & 15, kq = lane >> 4;
  int ts0 = kq ^ (lr16 & 7);
  int ts1 = (4 + kq) ^ (lr16 & 7);
  int sw = (lane & 7) ^ ((lane >> 3) & 7);
  int l8 = lane >> 3;
  int c0 = 2 * wave, c1 = 2 * wave + 1;
  int lr0 = c0 * 8 + l8, lr1 = c1 * 8 + l8;
  const char* Ab = (const char*)A;
  const char* Bb = (const char*)BT;
  int grA0 = m0 + (lr0 >> 6) * 128 + (lr0 & 63);
  int grA1 = m0 + (lr1 >> 6) * 128 + (lr1 & 63);
  int gcB0 = n0 + lr0, gcB1 = n0 + lr1;  // lr in [0,128)

  auto stA = [&](int kt, int p, int mq) {
    char* slot = lds + (p * 2 + mq) * 16384;
    size_t ko = (size_t)kt * 128 + sw * 16;
    gload_lds16(Ab + (size_t)(grA0 + mq * 64) * 4096 + ko, slot + c0 * 1024);
    gload_lds16(Ab + (size_t)(grA1 + mq * 64) * 4096 + ko, slot + c1 * 1024);
  };
  auto stB = [&](int kt, int p) {
    char* slot = lds + 65536 + p * 16384;
    size_t ko = (size_t)kt * 128 + sw * 16;
    gload_lds16(Bb + (size_t)gcB0 * 4096 + ko, slot + c0 * 1024);
    gload_lds16(Bb + (size_t)gcB1 * 4096 + ko, slot + c1 * 1024);
  };

  f32x4 acc[8][2] = {};
  stA(0, 0, 0); stB(0, 0); stA(0, 0, 1); stA(1, 1, 0);
  vm_wait<4>();
  bar();
#pragma unroll 1
  for (int kt = 0; kt < 32; kt++) {
    int p = kt & 1;
    G2_PHASE(0, p, { if (kt + 1 < 32) { stB(kt + 1, p ^ 1); stA(kt + 1, p ^ 1, 1); } },
             { if (kt < 31) vm_wait<6>(); else vm_wait<0>(); });
    G2_PHASE(1, p, { if (kt + 2 < 32) stA(kt + 2, p, 0); },
             { if (kt < 30) vm_wait<4>(); else if (kt == 30) vm_wait<2>(); });
  }
#pragma unroll
  for (int mq = 0; mq < 2; mq++)
#pragma unroll
    for (int mi = 0; mi < 4; mi++)
#pragma unroll
      for (int ni = 0; ni < 2; ni++) {
        int row = m0 + wm * 128 + mq * 64 + mi * 16 + kq * 4;
        int col = n0 + wn * 32 + ni * 16 + lr16;
        f32x4 v = acc[mq * 4 + mi][ni];
#pragma unroll
        for (int r = 0; r < 4; r++) {
          size_t o = (size_t)(row + r) * DM + col;
          C[o] = Xres[o] + v[r];
        }
      }
}

// ---------------- conv: one thread per 8-channel vector per row
__global__ __launch_bounds__(256) void conv_prep3(const bf16* __restrict__ u,
                                                  const float* __restrict__ cw,
                                                  const float* __restrict__ cb,
                                                  const float* __restrict__ dt_bias,
                                                  bf16* __restrict__ xs,
                                                  float* __restrict__ BC,
                                                  float* __restrict__ dtf) {
  const int JPR = 292;  // 260 conv vec8 + 32 dt vec8
  int idx = blockIdx.x * 256 + threadIdx.x;
  if (idx >= MROWS * JPR) return;
  int row = idx / JPR;
  int j = idx - row * JPR;
  int t = row & (SEQ - 1);
  if (j < 260) {
    int c0 = j * 8;
    float acc[8];
#pragma unroll
    for (int i = 0; i < 8; i++) acc[i] = cb[c0 + i];
    const bf16* ub = u + (size_t)row * DPROJ + DIN + c0;
#pragma unroll
    for (int tap = 0; tap < 4; tap++) {
      int tt = t - 3 + tap;
      if (tt >= 0) {
        bf16x8 uv = *(const bf16x8*)(ub + (ptrdiff_t)(tap - 3) * DPROJ);
        const float* wv = cw + tap * CONVD + c0;
#pragma unroll
        for (int i = 0; i < 8; i++) acc[i] += wv[i] * (float)uv[i];
      }
    }
    if (c0 < DIN) {
      bf16x8 o;
#pragma unroll
      for (int i = 0; i < 8; i++) {
        float sv = acc[i] / (1.f + __expf(-acc[i]));
        o[i] = (bf16)sv;
      }
      *(bf16x8*)(xs + (size_t)row * DIN + c0) = o;
    } else {
      float* bc = BC + (size_t)row * 32 + (c0 - DIN);
#pragma unroll
      for (int i = 0; i < 8; i++) bc[i] = acc[i] / (1.f + __expf(-acc[i]));
    }
  } else {
    int h0 = (j - 260) * 8;
    bf16x8 uv = *(const bf16x8*)(u + (size_t)row * DPROJ + (DPROJ - NH) + h0);
    float* dst = dtf + (size_t)row * NH + h0;
#pragma unroll
    for (int i = 0; i < 8; i++) {
      float xv = (float)uv[i] + dt_bias[h0 + i];
      dst[i] = (xv > 20.f) ? xv : log1pf(__expf(xv));
    }
  }
}

// ---------------- chunked scan, phase 1: local scan from zero -> (S, P) in u's dead tail
__global__ __launch_bounds__(64) void scan_p1(const bf16* __restrict__ xs,
                                              const float* __restrict__ BC,
                                              const float* __restrict__ dtf,
                                              const float* __restrict__ A_log,
                                              bf16* __restrict__ uscr) {
  int c = blockIdx.x & 63, hg = (blockIdx.x >> 6) & 31, b = blockIdx.x >> 11;
  int lane = threadIdx.x, hh = lane >> 3;
  int h = hg * 8 + hh;
  float A = -__expf(A_log[h]);
  float st[16];
#pragma unroll
  for (int n = 0; n < 16; n++) st[n] = 0.f;
  float pcum = 1.f;
  size_t rb = (size_t)b * SEQ + (size_t)c * LC;
  for (int t = 0; t < LC; t++) {
    size_t row = rb + t;
    const float* bcrow = BC + row * 32;
    float dtv = dtf[row * NH + h];
    float x = (float)xs[row * DIN + hg * 64 + lane];
    float dA = __expf(dtv * A);
    pcum *= dA;
    float w = dtv * x;
#pragma unroll
    for (int n = 0; n < 16; n++) st[n] = st[n] * dA + w * bcrow[n];
  }
  char* slot = (char*)uscr + (size_t)blockIdx.x * UROWB + 4096;
  float* S = (float*)slot;
#pragma unroll
  for (int n = 0; n < 16; n++) S[lane * 16 + n] = st[n];
  if ((lane & 7) == 0) ((float*)(slot + 4096))[hh] = pcum;
}

// ---------------- phase 2: sequential combine over chunks (prefetched); S <- incoming H
__global__ __launch_bounds__(64) void scan_p2(bf16* __restrict__ uscr) {
  int bh = blockIdx.x;  // 0..127 = b*32+hg
  int lane = threadIdx.x, hh = lane >> 3;
  float H[16];
#pragma unroll
  for (int n = 0; n < 16; n++) H[n] = 0.f;
  char* base = (char*)uscr + (size_t)bh * NC * UROWB + 4096;
  float sN[16], PN;
  {
    float* S = (float*)base;
#pragma unroll
    for (int n = 0; n < 16; n++) sN[n] = S[lane * 16 + n];
    PN = ((const float*)(base + 4096))[hh];
  }
  for (int c = 0; c < NC; c++) {
    float sC[16], PC = PN;
#pragma unroll
    for (int n = 0; n < 16; n++) sC[n] = sN[n];
    if (c + 1 < NC) {
      char* slot = base + (size_t)(c + 1) * UROWB;
      float* S = (float*)slot;
#pragma unroll
      for (int n = 0; n < 16; n++) sN[n] = S[lane * 16 + n];
      PN = ((const float*)(slot + 4096))[hh];
    }
    float* S0 = (float*)(base + (size_t)c * UROWB);
#pragma unroll
    for (int n = 0; n < 16; n++) {
      float hn = H[n];
      S0[lane * 16 + n] = hn;
      H[n] = PC * hn + sC[n];
    }
  }
}

// ---------------- phase 3: re-scan each chunk from true incoming state, emit y
__global__ __launch_bounds__(64) void scan_p3(const bf16* __restrict__ xs,
                                              const float* __restrict__ BC,
                                              const float* __restrict__ dtf,
                                              const float* __restrict__ A_log,
                                              const float* __restrict__ Dp,
                                              const bf16* __restrict__ uscr,
                                              bf16* __restrict__ y) {
  int c = blockIdx.x & 63, hg = (blockIdx.x >> 6) & 31, b = blockIdx.x >> 11;
  int lane = threadIdx.x, hh = lane >> 3;
  int h = hg * 8 + hh;
  float A = -__expf(A_log[h]);
  float D = Dp[h];
  const char* slot = (const char*)uscr + (size_t)blockIdx.x * UROWB + 4096;
  float st[16];
#pragma unroll
  for (int n = 0; n < 16; n++) st[n] = ((const float*)slot)[lane * 16 + n];
  size_t rb = (size_t)b * SEQ + (size_t)c * LC;
  for (int t = 0; t < LC; t++) {
    size_t row = rb + t;
    const float* bcrow = BC + row * 32;
    float dtv = dtf[row * NH + h];
    float x = (float)xs[row * DIN + hg * 64 + lane];
    float dA = __expf(dtv * A);
    float w = dtv * x;
    float yv = 0.f;
#pragma unroll
    for (int n = 0; n < 16; n++) {
      st[n] = st[n] * dA + w * bcrow[n];
      yv += st[n] * bcrow[16 + n];
    }
    y[row * DIN + hg * 64 + lane] = (bf16)(yv + D * x);
  }
}

// ---------------- gating + rmsnorm -> g bf16
__global__ __launch_bounds__(256) void gate_rms(const bf16* __restrict__ u,
                                                const bf16* __restrict__ y,
                                                const float* __restrict__ rms_w,
                                                bf16* __restrict__ g) {
  int row = blockIdx.x;
  int t = threadIdx.x;
  bf16x8 zv = ((const bf16x8*)(u + (size_t)row * DPROJ))[t];
  bf16x8 yv = ((const bf16x8*)(y + (size_t)row * DIN))[t];
  float gv[8];
  float s2 = 0.f;
#pragma unroll
  for (int i = 0; i < 8; i++) {
    float z = (float)zv[i];
    float yy = (float)yv[i];
    float gg = yy * z / (1.f + __expf(-z));
    gv[i] = gg;
    s2 += gg * gg;
  }
#pragma unroll
  for (int off = 32; off > 0; off >>= 1) s2 += __shfl_down(s2, off);
  __shared__ float ps[4];
  int wave = t >> 6, lane = t & 63;
  if (lane == 0) ps[wave] = s2;
  __syncthreads();
  s2 = ps[0] + ps[1] + ps[2] + ps[3];
  float scale = rsqrtf(s2 * (1.f / DIN) + 1e-5f);
  f32x4 w0 = ((const f32x4*)rms_w)[2 * t];
  f32x4 w1 = ((const f32x4*)rms_w)[2 * t + 1];
  bf16x8 og;
#pragma unroll
  for (int i = 0; i < 4; i++) og[i] = (bf16)(gv[i] * scale * w0[i]);
#pragma unroll
  for (int i = 0; i < 4; i++) og[4 + i] = (bf16)(gv[4 + i] * scale * w1[i]);
  ((bf16x8*)(g + (size_t)row * DIN))[t] = og;
}

extern "C" void kernel_launch(void* const* d_in, const int* in_sizes, int n_in,
                              void* d_out, int out_size, void* d_ws, size_t ws_size,
                              hipStream_t stream) {
  const float* x = (const float*)d_in[0];
  const float* lnw = (const float*)d_in[1];
  const float* lnb = (const float*)d_in[2];
  const float* Win = (const float*)d_in[3];
  const float* cw = (const float*)d_in[4];
  const float* cb = (const float*)d_in[5];
  const float* Alog = (const float*)d_in[6];
  const float* Dpv = (const float*)d_in[7];
  const float* dtb = (const float*)d_in[8];
  const float* rmsw = (const float*)d_in[9];
  const float* Wout = (const float*)d_in[10];
  float* out = (float*)d_out;

  char* ws = (char*)d_ws;
  bf16* u = (bf16*)(ws + 0);                     // [8192][4384] bf16
  bf16* xnb = (bf16*)(ws + 71827456);            // [8192][1024] bf16 (dead after GEMM1)
  bf16* WinT = (bf16*)(ws + 88604672);           // [4608][1024] bf16 (dead after GEMM1)
  bf16* yb = (bf16*)(ws + 71827456);             // [8192][2048] bf16 (reuses xnb+WinT)
  bf16* xsb = (bf16*)(ws + 105381888);           // [8192][2048] bf16 (dead after scan)
  bf16* gb = (bf16*)(ws + 105381888);            // reuses xsb
  float* BC = (float*)(ws + 138936320);          // [8192][32] f32
  float* dtf = (float*)(ws + 139984896);         // [8192][256] f32
  bf16* WoutT = (bf16*)(ws + 148373504);         // [1024][2048] bf16

  transpose_cvt<<<dim3(32, 144), dim3(32, 8), 0, stream>>>(Win, WinT, 1024, DPROJ, NPAD1);
  transpose_cvt<<<dim3(64, 32), dim3(32, 8), 0, stream>>>(Wout, WoutT, DIN, DM, DM);
  ln_kernel<<<MROWS, 256, 0, stream>>>(x, lnw, lnb, xnb);
  gemm1_8p<<<768, 512, 0, stream>>>(xnb, WinT, u);
  conv_prep3<<<(MROWS * 292) / 256, 256, 0, stream>>>(u, cw, cb, dtb, xsb, BC, dtf);
  scan_p1<<<MROWS, 64, 0, stream>>>(xsb, BC, dtf, Alog, u);
  scan_p2<<<128, 64, 0, stream>>>(u);
  scan_p3<<<MROWS, 64, 0, stream>>>(xsb, BC, dtf, Alog, Dpv, u, yb);
  gate_rms<<<MROWS, 256, 0, stream>>>(u, yb, rmsw, gb);
  gemm2_8p<<<256, 512, 0, stream>>>(gb, WoutT, out, x);
}

// Round 12
// 296.805 us; speedup vs baseline: 1.2916x; 1.0045x over previous
//
#include <hip/hip_runtime.h>

typedef __bf16 bf16;
typedef __attribute__((ext_vector_type(8))) __bf16 bf16x8;
typedef __attribute__((ext_vector_type(4))) float f32x4;

#define B_SZ 4
#define SEQ 2048
#define DM 1024
#define DIN 2048
#define NH 256
#define DSTATE 16
#define CONVD 2080
#define DPROJ 4384
#define NPAD1 4608
#define MROWS 8192
#define NC 64
#define LC 32
#define UROWB 8768  // u row stride in bytes (4384 * 2)

__device__ __forceinline__ void gload_lds16(const void* g, void* l) {
  __builtin_amdgcn_global_load_lds(
      (__attribute__((address_space(1))) void*)g,
      (__attribute__((address_space(3))) void*)l, 16, 0, 0);
}

template <int N>
__device__ __forceinline__ void vm_wait() {
  asm volatile("s_waitcnt vmcnt(%0)" ::"n"(N) : "memory");
}
__device__ __forceinline__ void bar() { asm volatile("s_barrier" ::: "memory"); }
__device__ __forceinline__ void lgkm0() {
  asm volatile("s_waitcnt lgkmcnt(0)" ::: "memory");
}

// ---------------- transpose (f32 [K][N] -> bf16 [Npad][K], zero-pad rows >= N)
__global__ void transpose_cvt(const float* __restrict__ W, bf16* __restrict__ WT,
                              int K, int N, int Npad) {
  __shared__ float tile[32][33];
  int k0 = blockIdx.x * 32, n0 = blockIdx.y * 32;
  int tx = threadIdx.x, ty = threadIdx.y;  // (32, 8)
#pragma unroll
  for (int j = 0; j < 4; j++) {
    int k = k0 + ty + 8 * j, n = n0 + tx;
    tile[ty + 8 * j][tx] = (k < K && n < N) ? W[(size_t)k * N + n] : 0.f;
  }
  __syncthreads();
#pragma unroll
  for (int j = 0; j < 4; j++) {
    int n = n0 + ty + 8 * j, k = k0 + tx;
    if (n < Npad && k < K) WT[(size_t)n * K + k] = (bf16)tile[tx][ty + 8 * j];
  }
}

// ---------------- layernorm (f32 in) -> xn bf16
__global__ __launch_bounds__(256) void ln_kernel(const float* __restrict__ x,
                                                 const float* __restrict__ lw,
                                                 const float* __restrict__ lb,
                                                 bf16* __restrict__ xn) {
  int row = blockIdx.x;
  int t = threadIdx.x;
  f32x4 v4 = ((const f32x4*)(x + (size_t)row * DM))[t];
  float v0 = v4[0], v1 = v4[1], v2 = v4[2], v3 = v4[3];
  float s = v0 + v1 + v2 + v3;
  float s2 = v0 * v0 + v1 * v1 + v2 * v2 + v3 * v3;
#pragma unroll
  for (int off = 32; off > 0; off >>= 1) {
    s += __shfl_down(s, off);
    s2 += __shfl_down(s2, off);
  }
  __shared__ float ps[8];
  int wave = t >> 6, lane = t & 63;
  if (lane == 0) { ps[wave] = s; ps[4 + wave] = s2; }
  __syncthreads();
  s = ps[0] + ps[1] + ps[2] + ps[3];
  s2 = ps[4] + ps[5] + ps[6] + ps[7];
  float mean = s * (1.f / DM);
  float var = s2 * (1.f / DM) - mean * mean;
  float rstd = rsqrtf(var + 1e-5f);
  f32x4 wv = ((const f32x4*)lw)[t];
  f32x4 bv = ((const f32x4*)lb)[t];
  bf16 o[4];
  o[0] = (bf16)((v0 - mean) * rstd * wv[0] + bv[0]);
  o[1] = (bf16)((v1 - mean) * rstd * wv[1] + bv[1]);
  o[2] = (bf16)((v2 - mean) * rstd * wv[2] + bv[2]);
  o[3] = (bf16)((v3 - mean) * rstd * wv[3] + bv[3]);
  bf16* dst = xn + (size_t)row * DM + t * 4;
  dst[0] = o[0]; dst[1] = o[1]; dst[2] = o[2]; dst[3] = o[3];
}

// ---------------- GEMM1: 256x192 tile, grid 768 (exactly 3 rounds), BK=64,
// 8 waves (2M x 4N). A double-buffered (2x32KB), B triple-buffered (3x24KB) = 136 KiB.
__global__ __launch_bounds__(512, 2) void gemm1_8p(const bf16* __restrict__ A,
                                                   const bf16* __restrict__ BT,
                                                   bf16* __restrict__ C) {
  __shared__ char lds[139264];
  int bid = blockIdx.x;  // 768 = 32 m-tiles * 24 n-tiles
  int xcd = bid & 7;
  int l = bid >> 3;             // 0..95 per XCD, 32 per round
  int bm = xcd * 4 + ((l >> 3) & 3);
  int bn = (l >> 5) * 8 + (l & 7);
  int m0 = bm * 256, n0 = bn * 192;
  int t = threadIdx.x, lane = t & 63, wave = t >> 6;
  int wm = wave >> 2, wn = wave & 3;
  int lr16 = lane & 15, kq = lane >> 4;
  int ts0 = kq ^ (lr16 & 7);
  int ts1 = (4 + kq) ^ (lr16 & 7);
  int sw = (lane & 7) ^ (lane >> 3);
  int l8 = lane >> 3;
  const char* Ab = (const char*)A;
  const char* Bb = (const char*)BT;

  auto stA = [&](int kt) {
    char* slot = lds + (kt & 1) * 32768;
    size_t ko = (size_t)kt * 128 + sw * 16;
#pragma unroll
    for (int g = 0; g < 4; g++) {
      int c = wave * 4 + g;
      gload_lds16(Ab + (size_t)(m0 + c * 8 + l8) * 2048 + ko, slot + c * 1024);
    }
  };
  auto stB = [&](int kt) {
    char* slot = lds + 65536 + (kt % 3) * 24576;
    size_t ko = (size_t)kt * 128 + sw * 16;
#pragma unroll
    for (int g = 0; g < 3; g++) {
      int c = wave * 3 + g;
      gload_lds16(Bb + (size_t)(n0 + c * 8 + l8) * 2048 + ko, slot + c * 1024);
    }
  };

  f32x4 acc[8][3] = {};
  bf16x8 a_[4][2], b_[3][2];

  stA(0); stB(0); stA(1); stB(1);
  vm_wait<7>();
  bar();
#pragma unroll 1
  for (int kt = 0; kt < 16; kt++) {
    {
      const char* sa = lds + (kt & 1) * 32768;
      const char* sb = lds + 65536 + (kt % 3) * 24576;
#pragma unroll
      for (int mi = 0; mi < 4; mi++) {
        int lrow = wm * 128 + mi * 16 + lr16;
        a_[mi][0] = *(const bf16x8*)(sa + lrow * 128 + ts0 * 16);
        a_[mi][1] = *(const bf16x8*)(sa + lrow * 128 + ts1 * 16);
      }
#pragma unroll
      for (int ni = 0; ni < 3; ni++) {
        int lrow = wn * 48 + ni * 16 + lr16;
        b_[ni][0] = *(const bf16x8*)(sb + lrow * 128 + ts0 * 16);
        b_[ni][1] = *(const bf16x8*)(sb + lrow * 128 + ts1 * 16);
      }
      if (kt >= 1 && kt < 15) stA(kt + 1);
      if (kt < 14) stB(kt + 2);
      bar();
      lgkm0();
      __builtin_amdgcn_s_setprio(1);
#pragma unroll
      for (int mi = 0; mi < 4; mi++)
#pragma unroll
        for (int ni = 0; ni < 3; ni++) {
          acc[mi][ni] = __builtin_amdgcn_mfma_f32_16x16x32_bf16(a_[mi][0], b_[ni][0], acc[mi][ni], 0, 0, 0);
          acc[mi][ni] = __builtin_amdgcn_mfma_f32_16x16x32_bf16(a_[mi][1], b_[ni][1], acc[mi][ni], 0, 0, 0);
        }
      __builtin_amdgcn_s_setprio(0);
      bar();
    }
    {
      const char* sa = lds + (kt & 1) * 32768;
#pragma unroll
      for (int mi = 0; mi < 4; mi++) {
        int lrow = wm * 128 + 64 + mi * 16 + lr16;
        a_[mi][0] = *(const bf16x8*)(sa + lrow * 128 + ts0 * 16);
        a_[mi][1] = *(const bf16x8*)(sa + lrow * 128 + ts1 * 16);
      }
      if (kt <= 13) vm_wait<3>();
      else if (kt == 14) vm_wait<0>();
      bar();
      lgkm0();
      __builtin_amdgcn_s_setprio(1);
#pragma unroll
      for (int mi = 0; mi < 4; mi++)
#pragma unroll
        for (int ni = 0; ni < 3; ni++) {
          acc[4 + mi][ni] = __builtin_amdgcn_mfma_f32_16x16x32_bf16(a_[mi][0], b_[ni][0], acc[4 + mi][ni], 0, 0, 0);
          acc[4 + mi][ni] = __builtin_amdgcn_mfma_f32_16x16x32_bf16(a_[mi][1], b_[ni][1], acc[4 + mi][ni], 0, 0, 0);
        }
      __builtin_amdgcn_s_setprio(0);
      bar();
    }
  }
#pragma unroll
  for (int fr = 0; fr < 8; fr++)
#pragma unroll
    for (int ni = 0; ni < 3; ni++) {
      int row = m0 + wm * 128 + fr * 16 + kq * 4;
      int col = n0 + wn * 48 + ni * 16 + lr16;
      f32x4 v = acc[fr][ni];
      if (col < 4384) {
#pragma unroll
        for (int r = 0; r < 4; r++)
          C[(size_t)(row + r) * DPROJ + col] = (bf16)v[r];
      }
    }
}

// ---------------- GEMM2: 128x256 tile, BK=64, 8 waves (2M x 4N, wave 64x64),
// grid 256 = 1 exact round. A+B triple-buffered: A 3x16KB at 0, B 3x32KB at 49152
// = 144 KiB. Ledger: prologue stages tiles 0,1 (12 loads), wait 6; ph1(kt) issues
// tile kt+2 (6 loads); ph2(kt) waits vmcnt(6) draining kt+1, leaving kt+2 in
// flight (kt=30: vmcnt(0) drains tile 31). WAR: buf (kt+2)%3 holds tile kt-1,
// last read ph1/ph2(kt-1), >=1 barrier before issue at ph1(kt). A frags persist
// in regs across both phases; ph1 = A(8 reads)+B01(4)+16 MFMA; ph2 = B23(4)+16.
__global__ __launch_bounds__(512, 2) void gemm2_8p(const bf16* __restrict__ A,
                                                   const bf16* __restrict__ BT,
                                                   float* __restrict__ C,
                                                   const float* __restrict__ Xres) {
  __shared__ char lds[147456];
  int bid = blockIdx.x;                  // 256 = 64 m * 4 n
  int swz = (bid & 7) * 32 + (bid >> 3); // bijective (256 % 8 == 0)
  int bm = swz >> 2, bn = swz & 3;
  int m0 = bm * 128, n0 = bn * 256;
  int t = threadIdx.x, lane = t & 63, wave = t >> 6;
  int wm = wave >> 2, wn = wave & 3;
  int lr16 = lane & 15, kq = lane >> 4;
  int ts0 = kq ^ (lr16 & 7);
  int ts1 = (4 + kq) ^ (lr16 & 7);
  int sw = (lane & 7) ^ (lane >> 3);
  int l8 = lane >> 3;
  const char* Ab = (const char*)A;
  const char* Bb = (const char*)BT;

  // A: 128 rows x 128 B = 16 KB/buf; 2 gloads/thread
  auto stA = [&](int kt) {
    char* slot = lds + (kt % 3) * 16384;
    size_t ko = (size_t)kt * 128 + sw * 16;
#pragma unroll
    for (int g = 0; g < 2; g++) {
      int c = wave * 2 + g;
      gload_lds16(Ab + (size_t)(m0 + c * 8 + l8) * 4096 + ko, slot + c * 1024);
    }
  };
  // B: 256 rows x 128 B = 32 KB/buf; 4 gloads/thread
  auto stB = [&](int kt) {
    char* slot = lds + 49152 + (kt % 3) * 32768;
    size_t ko = (size_t)kt * 128 + sw * 16;
#pragma unroll
    for (int g = 0; g < 4; g++) {
      int c = wave * 4 + g;
      gload_lds16(Bb + (size_t)(n0 + c * 8 + l8) * 4096 + ko, slot + c * 1024);
    }
  };

  f32x4 acc[4][4] = {};
  bf16x8 a_[4][2], b_[2][2];

  // prologue: tiles 0 and 1 (12 loads); drain tile 0 (6), leave tile 1
  stA(0); stB(0); stA(1); stB(1);
  vm_wait<6>();
  bar();
#pragma unroll 1
  for (int kt = 0; kt < 32; kt++) {
    const char* sa = lds + (kt % 3) * 16384;
    const char* sb = lds + 49152 + (kt % 3) * 32768;
    // ---- ph1: read all A (8) + B n0/n1 (4); issue tile kt+2; 16 MFMA
    {
#pragma unroll
      for (int mi = 0; mi < 4; mi++) {
        int lrow = wm * 64 + mi * 16 + lr16;
        a_[mi][0] = *(const bf16x8*)(sa + lrow * 128 + ts0 * 16);
        a_[mi][1] = *(const bf16x8*)(sa + lrow * 128 + ts1 * 16);
      }
#pragma unroll
      for (int ni = 0; ni < 2; ni++) {
        int lrow = wn * 64 + ni * 16 + lr16;
        b_[ni][0] = *(const bf16x8*)(sb + lrow * 128 + ts0 * 16);
        b_[ni][1] = *(const bf16x8*)(sb + lrow * 128 + ts1 * 16);
      }
      if (kt + 2 < 32) { stA(kt + 2); stB(kt + 2); }
      bar();
      lgkm0();
      __builtin_amdgcn_s_setprio(1);
#pragma unroll
      for (int mi = 0; mi < 4; mi++)
#pragma unroll
        for (int ni = 0; ni < 2; ni++) {
          acc[mi][ni] = __builtin_amdgcn_mfma_f32_16x16x32_bf16(a_[mi][0], b_[ni][0], acc[mi][ni], 0, 0, 0);
          acc[mi][ni] = __builtin_amdgcn_mfma_f32_16x16x32_bf16(a_[mi][1], b_[ni][1], acc[mi][ni], 0, 0, 0);
        }
      __builtin_amdgcn_s_setprio(0);
      bar();
    }
    // ---- ph2: read B n2/n3 (4); counted wait for tile kt+1; 16 MFMA
    {
#pragma unroll
      for (int ni = 0; ni < 2; ni++) {
        int lrow = wn * 64 + (2 + ni) * 16 + lr16;
        b_[ni][0] = *(const bf16x8*)(sb + lrow * 128 + ts0 * 16);
        b_[ni][1] = *(const bf16x8*)(sb + lrow * 128 + ts1 * 16);
      }
      if (kt <= 29) vm_wait<6>();
      else if (kt == 30) vm_wait<0>();
      bar();
      lgkm0();
      __builtin_amdgcn_s_setprio(1);
#pragma unroll
      for (int mi = 0; mi < 4; mi++)
#pragma unroll
        for (int ni = 0; ni < 2; ni++) {
          acc[mi][2 + ni] = __builtin_amdgcn_mfma_f32_16x16x32_bf16(a_[mi][0], b_[ni][0], acc[mi][2 + ni], 0, 0, 0);
          acc[mi][2 + ni] = __builtin_amdgcn_mfma_f32_16x16x32_bf16(a_[mi][1], b_[ni][1], acc[mi][2 + ni], 0, 0, 0);
        }
      __builtin_amdgcn_s_setprio(0);
      bar();
    }
  }
#pragma unroll
  for (int mi = 0; mi < 4; mi++)
#pragma unroll
    for (int ni = 0; ni < 4; ni++) {
      int row = m0 + wm * 64 + mi * 16 + kq * 4;
      int col = n0 + wn * 64 + ni * 16 + lr16;
      f32x4 v = acc[mi][ni];
#pragma unroll
      for (int r = 0; r < 4; r++) {
        size_t o = (size_t)(row + r) * DM + col;
        C[o] = Xres[o] + v[r];
      }
    }
}

// ---------------- conv: one thread per 8-channel vector per row
__global__ __launch_bounds__(256) void conv_prep3(const bf16* __restrict__ u,
                                                  const float* __restrict__ cw,
                                                  const float* __restrict__ cb,
                                                  const float* __restrict__ dt_bias,
                                                  bf16* __restrict__ xs,
                                                  float* __restrict__ BC,
                                                  float* __restrict__ dtf) {
  const int JPR = 292;  // 260 conv vec8 + 32 dt vec8
  int idx = blockIdx.x * 256 + threadIdx.x;
  if (idx >= MROWS * JPR) return;
  int row = idx / JPR;
  int j = idx - row * JPR;
  int t = row & (SEQ - 1);
  if (j < 260) {
    int c0 = j * 8;
    float acc[8];
#pragma unroll
    for (int i = 0; i < 8; i++) acc[i] = cb[c0 + i];
    const bf16* ub = u + (size_t)row * DPROJ + DIN + c0;
#pragma unroll
    for (int tap = 0; tap < 4; tap++) {
      int tt = t - 3 + tap;
      if (tt >= 0) {
        bf16x8 uv = *(const bf16x8*)(ub + (ptrdiff_t)(tap - 3) * DPROJ);
        const float* wv = cw + tap * CONVD + c0;
#pragma unroll
        for (int i = 0; i < 8; i++) acc[i] += wv[i] * (float)uv[i];
      }
    }
    if (c0 < DIN) {
      bf16x8 o;
#pragma unroll
      for (int i = 0; i < 8; i++) {
        float sv = acc[i] / (1.f + __expf(-acc[i]));
        o[i] = (bf16)sv;
      }
      *(bf16x8*)(xs + (size_t)row * DIN + c0) = o;
    } else {
      float* bc = BC + (size_t)row * 32 + (c0 - DIN);
#pragma unroll
      for (int i = 0; i < 8; i++) bc[i] = acc[i] / (1.f + __expf(-acc[i]));
    }
  } else {
    int h0 = (j - 260) * 8;
    bf16x8 uv = *(const bf16x8*)(u + (size_t)row * DPROJ + (DPROJ - NH) + h0);
    float* dst = dtf + (size_t)row * NH + h0;
#pragma unroll
    for (int i = 0; i < 8; i++) {
      float xv = (float)uv[i] + dt_bias[h0 + i];
      dst[i] = (xv > 20.f) ? xv : log1pf(__expf(xv));
    }
  }
}

// ---------------- chunked scan, phase 1: local scan from zero -> (S, P) in u's dead tail
__global__ __launch_bounds__(64) void scan_p1(const bf16* __restrict__ xs,
                                              const float* __restrict__ BC,
                                              const float* __restrict__ dtf,
                                              const float* __restrict__ A_log,
                                              bf16* __restrict__ uscr) {
  int c = blockIdx.x & 63, hg = (blockIdx.x >> 6) & 31, b = blockIdx.x >> 11;
  int lane = threadIdx.x, hh = lane >> 3;
  int h = hg * 8 + hh;
  float A = -__expf(A_log[h]);
  float st[16];
#pragma unroll
  for (int n = 0; n < 16; n++) st[n] = 0.f;
  float pcum = 1.f;
  size_t rb = (size_t)b * SEQ + (size_t)c * LC;
  for (int t = 0; t < LC; t++) {
    size_t row = rb + t;
    const float* bcrow = BC + row * 32;
    float dtv = dtf[row * NH + h];
    float x = (float)xs[row * DIN + hg * 64 + lane];
    float dA = __expf(dtv * A);
    pcum *= dA;
    float w = dtv * x;
#pragma unroll
    for (int n = 0; n < 16; n++) st[n] = st[n] * dA + w * bcrow[n];
  }
  char* slot = (char*)uscr + (size_t)blockIdx.x * UROWB + 4096;
  float* S = (float*)slot;
#pragma unroll
  for (int n = 0; n < 16; n++) S[lane * 16 + n] = st[n];
  if ((lane & 7) == 0) ((float*)(slot + 4096))[hh] = pcum;
}

// ---------------- phase 2: sequential combine over chunks (prefetched); S <- incoming H
__global__ __launch_bounds__(64) void scan_p2(bf16* __restrict__ uscr) {
  int bh = blockIdx.x;  // 0..127 = b*32+hg
  int lane = threadIdx.x, hh = lane >> 3;
  float H[16];
#pragma unroll
  for (int n = 0; n < 16; n++) H[n] = 0.f;
  char* base = (char*)uscr + (size_t)bh * NC * UROWB + 4096;
  float sN[16], PN;
  {
    float* S = (float*)base;
#pragma unroll
    for (int n = 0; n < 16; n++) sN[n] = S[lane * 16 + n];
    PN = ((const float*)(base + 4096))[hh];
  }
  for (int c = 0; c < NC; c++) {
    float sC[16], PC = PN;
#pragma unroll
    for (int n = 0; n < 16; n++) sC[n] = sN[n];
    if (c + 1 < NC) {
      char* slot = base + (size_t)(c + 1) * UROWB;
      float* S = (float*)slot;
#pragma unroll
      for (int n = 0; n < 16; n++) sN[n] = S[lane * 16 + n];
      PN = ((const float*)(slot + 4096))[hh];
    }
    float* S0 = (float*)(base + (size_t)c * UROWB);
#pragma unroll
    for (int n = 0; n < 16; n++) {
      float hn = H[n];
      S0[lane * 16 + n] = hn;
      H[n] = PC * hn + sC[n];
    }
  }
}

// ---------------- phase 3: re-scan each chunk from true incoming state, emit y
__global__ __launch_bounds__(64) void scan_p3(const bf16* __restrict__ xs,
                                              const float* __restrict__ BC,
                                              const float* __restrict__ dtf,
                                              const float* __restrict__ A_log,
                                              const float* __restrict__ Dp,
                                              const bf16* __restrict__ uscr,
                                              bf16* __restrict__ y) {
  int c = blockIdx.x & 63, hg = (blockIdx.x >> 6) & 31, b = blockIdx.x >> 11;
  int lane = threadIdx.x, hh = lane >> 3;
  int h = hg * 8 + hh;
  float A = -__expf(A_log[h]);
  float D = Dp[h];
  const char* slot = (const char*)uscr + (size_t)blockIdx.x * UROWB + 4096;
  float st[16];
#pragma unroll
  for (int n = 0; n < 16; n++) st[n] = ((const float*)slot)[lane * 16 + n];
  size_t rb = (size_t)b * SEQ + (size_t)c * LC;
  for (int t = 0; t < LC; t++) {
    size_t row = rb + t;
    const float* bcrow = BC + row * 32;
    float dtv = dtf[row * NH + h];
    float x = (float)xs[row * DIN + hg * 64 + lane];
    float dA = __expf(dtv * A);
    float w = dtv * x;
    float yv = 0.f;
#pragma unroll
    for (int n = 0; n < 16; n++) {
      st[n] = st[n] * dA + w * bcrow[n];
      yv += st[n] * bcrow[16 + n];
    }
    y[row * DIN + hg * 64 + lane] = (bf16)(yv + D * x);
  }
}

// ---------------- gating + rmsnorm -> g bf16
__global__ __launch_bounds__(256) void gate_rms(const bf16* __restrict__ u,
                                                const bf16* __restrict__ y,
                                                const float* __restrict__ rms_w,
                                                bf16* __restrict__ g) {
  int row = blockIdx.x;
  int t = threadIdx.x;
  bf16x8 zv = ((const bf16x8*)(u + (size_t)row * DPROJ))[t];
  bf16x8 yv = ((const bf16x8*)(y + (size_t)row * DIN))[t];
  float gv[8];
  float s2 = 0.f;
#pragma unroll
  for (int i = 0; i < 8; i++) {
    float z = (float)zv[i];
    float yy = (float)yv[i];
    float gg = yy * z / (1.f + __expf(-z));
    gv[i] = gg;
    s2 += gg * gg;
  }
#pragma unroll
  for (int off = 32; off > 0; off >>= 1) s2 += __shfl_down(s2, off);
  __shared__ float ps[4];
  int wave = t >> 6, lane = t & 63;
  if (lane == 0) ps[wave] = s2;
  __syncthreads();
  s2 = ps[0] + ps[1] + ps[2] + ps[3];
  float scale = rsqrtf(s2 * (1.f / DIN) + 1e-5f);
  f32x4 w0 = ((const f32x4*)rms_w)[2 * t];
  f32x4 w1 = ((const f32x4*)rms_w)[2 * t + 1];
  bf16x8 og;
#pragma unroll
  for (int i = 0; i < 4; i++) og[i] = (bf16)(gv[i] * scale * w0[i]);
#pragma unroll
  for (int i = 0; i < 4; i++) og[4 + i] = (bf16)(gv[4 + i] * scale * w1[i]);
  ((bf16x8*)(g + (size_t)row * DIN))[t] = og;
}

extern "C" void kernel_launch(void* const* d_in, const int* in_sizes, int n_in,
                              void* d_out, int out_size, void* d_ws, size_t ws_size,
                              hipStream_t stream) {
  const float* x = (const float*)d_in[0];
  const float* lnw = (const float*)d_in[1];
  const float* lnb = (const float*)d_in[2];
  const float* Win = (const float*)d_in[3];
  const float* cw = (const float*)d_in[4];
  const float* cb = (const float*)d_in[5];
  const float* Alog = (const float*)d_in[6];
  const float* Dpv = (const float*)d_in[7];
  const float* dtb = (const float*)d_in[8];
  const float* rmsw = (const float*)d_in[9];
  const float* Wout = (const float*)d_in[10];
  float* out = (float*)d_out;

  char* ws = (char*)d_ws;
  bf16* u = (bf16*)(ws + 0);                     // [8192][4384] bf16
  bf16* xnb = (bf16*)(ws + 71827456);            // [8192][1024] bf16 (dead after GEMM1)
  bf16* WinT = (bf16*)(ws + 88604672);           // [4608][1024] bf16 (dead after GEMM1)
  bf16* yb = (bf16*)(ws + 71827456);             // [8192][2048] bf16 (reuses xnb+WinT)
  bf16* xsb = (bf16*)(ws + 105381888);           // [8192][2048] bf16 (dead after scan)
  bf16* gb = (bf16*)(ws + 105381888);            // reuses xsb
  float* BC = (float*)(ws + 138936320);          // [8192][32] f32
  float* dtf = (float*)(ws + 139984896);         // [8192][256] f32
  bf16* WoutT = (bf16*)(ws + 148373504);         // [1024][2048] bf16

  transpose_cvt<<<dim3(32, 144), dim3(32, 8), 0, stream>>>(Win, WinT, 1024, DPROJ, NPAD1);
  transpose_cvt<<<dim3(64, 32), dim3(32, 8), 0, stream>>>(Wout, WoutT, DIN, DM, DM);
  ln_kernel<<<MROWS, 256, 0, stream>>>(x, lnw, lnb, xnb);
  gemm1_8p<<<768, 512, 0, stream>>>(xnb, WinT, u);
  conv_prep3<<<(MROWS * 292) / 256, 256, 0, stream>>>(u, cw, cb, dtb, xsb, BC, dtf);
  scan_p1<<<MROWS, 64, 0, stream>>>(xsb, BC, dtf, Alog, u);
  scan_p2<<<128, 64, 0, stream>>>(u);
  scan_p3<<<MROWS, 64, 0, stream>>>(xsb, BC, dtf, Alog, Dpv, u, yb);
  gate_rms<<<MROWS, 256, 0, stream>>>(u, yb, rmsw, gb);
  gemm2_8p<<<256, 512, 0, stream>>>(gb, WoutT, out, x);
}